// Round 8
// baseline (564.257 us; speedup 1.0000x reference)
//
#include <hip/hip_runtime.h>
#include <hip/hip_bf16.h>

#define N_NODES 32768
#define N_EDGES 524288
#define LN_EPS 1e-5f

typedef unsigned short ushort_t;
typedef __attribute__((ext_vector_type(8))) short short8v;
typedef __attribute__((ext_vector_type(4))) float float4v;
typedef __attribute__((ext_vector_type(2))) float float2v;

__device__ __forceinline__ float bf2f(ushort_t u) {
    return __uint_as_float(((unsigned int)u) << 16);
}
__device__ __forceinline__ ushort_t f2bf(float f) {
    unsigned int u = __float_as_uint(f);
    unsigned int r = (u + 0x7FFFu + ((u >> 16) & 1u)) >> 16;
    return (ushort_t)r;
}
__device__ __forceinline__ float lo16(unsigned int x) { return __uint_as_float(x << 16); }
__device__ __forceinline__ float hi16(unsigned int x) { return __uint_as_float(x & 0xFFFF0000u); }

#if __has_builtin(__builtin_amdgcn_exp2f)
#define EXP2(x) __builtin_amdgcn_exp2f(x)
#else
#define EXP2(x) exp2f(x)
#endif

// compact f32 conv region: only params consumed as f32 (biases, LN, input-proj weights)
#define OFF_WNODE 0
#define OFF_BNODE 5632
#define OFF_WPOS  5760
#define OFF_BPOS  6784
#define OFF_WEDGE 6912
#define OFF_BEDGE 7040
#define OFF_BLIN  7168
#define OFF_G1    7552
#define OFF_BE1   7936
#define OFF_BF1   8320
#define OFF_BF2   9088
#define OFF_G2    9472
#define OFF_BE2   9856
#define CONV_TOTAL 10240

// swizzled-B record bases (records of 512 ushorts = 64 lanes x 8 bf16)
#define REC_QKV(i)  ((i) * 96)          // 24 ct x 4 kb
#define REC_WLIN(i) (288 + (i) * 32)    // 8 ct x 4 kb
#define REC_WF1(i)  (384 + (i) * 64)    // 16 ct x 4 kb
#define REC_WF2(i)  (576 + (i) * 64)    // 8 ct x 8 kb
#define REC_WNP     768                 // input-proj [Wn;Wp;0] 8 ct x 2 kb
#define REC_TOTAL   784

#define LDS_STRIDE 264   // ushorts per LDS row (256 + 8 pad)
#define LDS_FSTRIDE 132  // floats per LDS row (same byte footprint)

// ---------------- dtype detection: bf16 data has exponent-like bits at [15:8] ---------
__global__ void detect_kernel(const unsigned int* __restrict__ wn, int* __restrict__ flag) {
    __shared__ int s[256];
    int t = threadIdx.x;
    int cnt = 0;
    for (int i = t; i < 2816; i += 256) {
        unsigned int b = (wn[i] >> 8) & 0x7F;
        cnt += (b >= 0x3A && b <= 0x40) ? 1 : 0;
    }
    s[t] = cnt;
    __syncthreads();
    for (int off = 128; off > 0; off >>= 1) {
        if (t < off) s[t] += s[t + off];
        __syncthreads();
    }
    if (t == 0) *flag = (s[0] > 1408) ? 1 : 0;   // 1 = bf16, 0 = f32
}

// ---------------- canonicalize small param buffers to f32 scratch ---------------------
// Also zeros the degree histogram (replaces a hipMemsetAsync dispatch node).
struct ConvArgs { const void* src[13]; };

__global__ void convert_kernel(ConvArgs a, const int* __restrict__ flag,
                               float* __restrict__ dst, int* __restrict__ deg) {
    int gid = blockIdx.x * 256 + threadIdx.x;
    for (int i = gid; i < N_NODES; i += CONV_TOTAL) deg[i] = 0;   // fused deg-zero
    if (gid >= CONV_TOTAL) return;
    const int off[14] = {OFF_WNODE, OFF_BNODE, OFF_WPOS, OFF_BPOS, OFF_WEDGE, OFF_BEDGE,
                         OFF_BLIN, OFF_G1, OFF_BE1, OFF_BF1, OFF_BF2, OFF_G2, OFF_BE2,
                         CONV_TOTAL};
    int s = 0;
#pragma unroll
    for (int i = 1; i < 13; ++i) s += (gid >= off[i]) ? 1 : 0;
    int local = gid - off[s];
    if (*flag)
        dst[gid] = bf2f(((const ushort_t*)a.src[s])[local]);
    else
        dst[gid] = ((const float*)a.src[s])[local];
}

// ---------------- swizzle GEMM weights into MFMA B-fragment records (raw sources) -----
// record(ct,kb): lane l holds W[kb*32 + (l>>4)*8 + j][ct*16 + (l&15)], j=0..7
// blocks 192..194 compute u/c1 (fused uc); blocks 195..198 build input-proj records.
__global__ void swz_kernel(const void* __restrict__ Wq, const void* __restrict__ Wk,
                           const void* __restrict__ Wv, const void* __restrict__ Wlin,
                           const void* __restrict__ Wf1, const void* __restrict__ Wf2,
                           const void* __restrict__ We, const void* __restrict__ wedge,
                           const void* __restrict__ bedge,
                           const void* __restrict__ Wn_, const void* __restrict__ Wp_,
                           const int* __restrict__ flag,
                           ushort_t* __restrict__ swz,
                           float* __restrict__ u, float* __restrict__ c1) {
    const bool isbf = (*flag != 0);
    if (blockIdx.x >= 195) {
        // input-proj B records: W[k][n], k = 0..43 Wn, 44..51 Wp, 52..63 zero pad
        int idx = (blockIdx.x - 195) * 256 + threadIdx.x;   // 0..1023
        int rec16 = idx >> 6;                               // 0..15
        int lane = idx & 63;
        int ct = rec16 >> 1, kb = rec16 & 1;
        int col = lane & 15, quad = lane >> 4;
        int n = ct * 16 + col;
        ushort_t v[8];
#pragma unroll
        for (int j = 0; j < 8; ++j) {
            int k = kb * 32 + quad * 8 + j;
            if (isbf) {
                v[j] = (k < 44) ? ((const ushort_t*)Wn_)[k * 128 + n]
                     : ((k < 52) ? ((const ushort_t*)Wp_)[(k - 44) * 128 + n]
                                 : (ushort_t)0);
            } else {
                float f = (k < 44) ? ((const float*)Wn_)[k * 128 + n]
                        : ((k < 52) ? ((const float*)Wp_)[(k - 44) * 128 + n] : 0.f);
                v[j] = f2bf(f);
            }
        }
        ushort_t* o = swz + (size_t)(REC_WNP + rec16) * 512 + lane * 8;
#pragma unroll
        for (int j = 0; j < 8; ++j) o[j] = v[j];
        return;
    }
    if (blockIdx.x >= 192) {
        // fused uc: pre-scaled by (1/sqrt(dk))*log2(e); agg works in log2 domain
        int l = blockIdx.x - 192;
        int d = threadIdx.x;
        if (d >= 128) return;
        float uu = 0.f, cc = 0.f;
        if (isbf) {
            const ushort_t* Wl = (const ushort_t*)We + (size_t)l * 16384;
            const ushort_t* we_ = (const ushort_t*)wedge;
            const ushort_t* be_ = (const ushort_t*)bedge;
#pragma unroll 4
            for (int k = 0; k < 128; ++k) {
                float w = bf2f(Wl[k * 128 + d]);
                uu = fmaf(bf2f(we_[k]), w, uu);
                cc = fmaf(bf2f(be_[k]), w, cc);
            }
        } else {
            const float* Wl = (const float*)We + (size_t)l * 16384;
            const float* we_ = (const float*)wedge;
            const float* be_ = (const float*)bedge;
#pragma unroll 4
            for (int k = 0; k < 128; ++k) {
                float w = Wl[k * 128 + d];
                uu = fmaf(we_[k], w, uu);
                cc = fmaf(be_[k], w, cc);
            }
        }
        const float scale = 0.17677669529663687f * 1.4426950408889634f;  // isq * log2(e)
        u[l * 128 + d] = uu * scale;
        c1[l * 128 + d] = (1.f + cc) * scale;
        return;
    }
    int gid = blockIdx.x * 256 + threadIdx.x;
    int lane = gid & 63;
    int rec = gid >> 6;
    int col = lane & 15, quad = lane >> 4;
    const void* src;
    size_t base;
    int ct, kb, OC;
    if (rec < 288) {                       // QKV: 3 layers x 24ct x 4kb
        int layer = rec / 96, r2 = rec % 96;
        ct = r2 >> 2; kb = r2 & 3;
        int seg = ct >> 3;                 // 0=Wq 1=Wk 2=Wv
        src = (seg == 0) ? Wq : ((seg == 1) ? Wk : Wv);
        base = (size_t)layer * 16384; OC = 128; ct &= 7;
    } else if (rec < 384) {                // W_lin
        int r = rec - 288, layer = r / 32, r2 = r % 32;
        ct = r2 >> 2; kb = r2 & 3;
        src = Wlin; base = (size_t)layer * 16384; OC = 128;
    } else if (rec < 576) {                // Wf1 (OC=256)
        int r = rec - 384, layer = r / 64, r2 = r % 64;
        ct = r2 >> 2; kb = r2 & 3;
        src = Wf1; base = (size_t)layer * 32768; OC = 256;
    } else {                               // Wf2 (K=256)
        int r = rec - 576, layer = r / 64, r2 = r % 64;
        ct = r2 >> 3; kb = r2 & 7;
        src = Wf2; base = (size_t)layer * 32768; OC = 128;
    }
    int n = ct * 16 + col;
    ushort_t v[8];
    if (isbf) {
        const ushort_t* s16 = (const ushort_t*)src + base;
#pragma unroll
        for (int j = 0; j < 8; ++j) v[j] = s16[(size_t)(kb * 32 + quad * 8 + j) * OC + n];
    } else {
        const float* s32 = (const float*)src + base;
#pragma unroll
        for (int j = 0; j < 8; ++j) v[j] = f2bf(s32[(size_t)(kb * 32 + quad * 8 + j) * OC + n]);
    }
    ushort_t* o = swz + (size_t)rec * 512 + lane * 8;
#pragma unroll
    for (int j = 0; j < 8; ++j) o[j] = v[j];
}

// ---------------- input projection via MFMA: h = [feats|lap|0] @ [Wn;Wp;0] + biases ---
// Grid N/64 blocks x 256 thr (4 waves); A tile staged bf16 in LDS; B from swz records.
// Fused degree histogram (4 strided passes). Outputs h f32 + hb bf16.
__global__ __launch_bounds__(256) void ip_gemm(
    const void* __restrict__ feats, const void* __restrict__ lap,
    const float* __restrict__ conv, const int* __restrict__ flag,
    const int* __restrict__ dstidx, int* __restrict__ deg,
    const ushort_t* __restrict__ Bswz,   // = swz + REC_WNP*512
    float* __restrict__ h, ushort_t* __restrict__ hb) {
    __shared__ __align__(16) ushort_t As[64 * 72];   // 64 rows x K=64, stride 72
    const int tid = threadIdx.x;

    // fused histogram: 512*256 threads x 4 edges
    for (int e = blockIdx.x * 256 + tid; e < N_EDGES; e += (N_NODES / 64) * 256)
        atomicAdd(&deg[dstidx[e]], 1);

    const bool isbf = (*flag != 0);
    const int r = tid >> 2;          // 0..63 (tile row)
    const int t4 = tid & 3;          // 16-col chunk
    const int m0g = blockIdx.x * 64;
    {
        const int row = m0g + r;
        ushort_t tmp[16];
        if (isbf) {
            const ushort_t* frow = (const ushort_t*)feats + (size_t)row * 44;
            const ushort_t* prow = (const ushort_t*)lap + (size_t)row * 8;
#pragma unroll
            for (int j = 0; j < 16; ++j) {
                int k = t4 * 16 + j;
                tmp[j] = (k < 44) ? frow[k]
                       : ((k < 52) ? prow[k - 44] : (ushort_t)0);
            }
        } else {
            const float* frow = (const float*)feats + (size_t)row * 44;
            const float* prow = (const float*)lap + (size_t)row * 8;
#pragma unroll
            for (int j = 0; j < 16; ++j) {
                int k = t4 * 16 + j;
                float v = (k < 44) ? frow[k] : ((k < 52) ? prow[k - 44] : 0.f);
                tmp[j] = f2bf(v);
            }
        }
#pragma unroll
        for (int j = 0; j < 16; ++j) As[r * 72 + t4 * 16 + j] = tmp[j];
    }
    __syncthreads();

    const int wv = tid >> 6, lane = tid & 63;
    const int col = lane & 15, quad = lane >> 4;
    const int m0 = wv * 16;
    short8v a0 = *(const short8v*)&As[(m0 + col) * 72 + quad * 8];
    short8v a1 = *(const short8v*)&As[(m0 + col) * 72 + 32 + quad * 8];

    float4v acc[8];
#pragma unroll
    for (int ct = 0; ct < 8; ++ct) {
        short8v b0 = *(const short8v*)(Bswz + (size_t)(ct * 2 + 0) * 512 + lane * 8);
        short8v b1 = *(const short8v*)(Bswz + (size_t)(ct * 2 + 1) * 512 + lane * 8);
        float4v a = (float4v){0.f, 0.f, 0.f, 0.f};
        a = __builtin_amdgcn_mfma_f32_16x16x32_bf16(a0, b0, a, 0, 0, 0);
        a = __builtin_amdgcn_mfma_f32_16x16x32_bf16(a1, b1, a, 0, 0, 0);
        acc[ct] = a;
    }

    const int rowb = m0g + m0 + quad * 4;
#pragma unroll
    for (int ct = 0; ct < 8; ++ct) {
        int j = ct * 16 + col;
        float bias = conv[OFF_BNODE + j] + conv[OFF_BPOS + j];
#pragma unroll
        for (int rr = 0; rr < 4; ++rr) {
            float o = acc[ct][rr] + bias;
            h[(size_t)(rowb + rr) * 128 + j] = o;
            hb[(size_t)(rowb + rr) * 128 + j] = f2bf(o);
        }
    }
}

// ---------------- CSR build ------------------------------------------------------------
// Also zeros macc (replaces a hipMemsetAsync dispatch node; mean_part runs much later).
__global__ void scan_kernel(const int* __restrict__ deg, int* __restrict__ rowstart,
                            int* __restrict__ cursor, float* __restrict__ macc) {
    __shared__ int lds[1024];
    int t = threadIdx.x;
    if (t < 128) macc[t] = 0.f;                 // fused macc-zero
    int base = t * 32;
    int v[32];
    int csum = 0;
#pragma unroll
    for (int j = 0; j < 8; ++j) {               // coalesced int4 loads
        int4 x = *(const int4*)(deg + base + j * 4);
        v[j * 4 + 0] = x.x; v[j * 4 + 1] = x.y;
        v[j * 4 + 2] = x.z; v[j * 4 + 3] = x.w;
        csum += x.x + x.y + x.z + x.w;
    }
    lds[t] = csum;
    __syncthreads();
    for (int off = 1; off < 1024; off <<= 1) {
        int x = (t >= off) ? lds[t - off] : 0;
        __syncthreads();
        lds[t] += x;
        __syncthreads();
    }
    int excl = lds[t] - csum;
    int running = excl;
#pragma unroll
    for (int j = 0; j < 8; ++j) {
        int4 w;
        w.x = running; running += v[j * 4 + 0];
        w.y = running; running += v[j * 4 + 1];
        w.z = running; running += v[j * 4 + 2];
        w.w = running; running += v[j * 4 + 3];
        *(int4*)(rowstart + base + j * 4) = w;
        *(int4*)(cursor + base + j * 4) = w;
    }
    if (t == 1023) rowstart[N_NODES] = running;
}

__global__ void scatter_kernel(const int* __restrict__ src, const int* __restrict__ dst,
                               const void* __restrict__ ef, const int* __restrict__ flag,
                               int* __restrict__ cursor,
                               unsigned int* __restrict__ edges) {
    int e = blockIdx.x * 256 + threadIdx.x;
    if (e < N_EDGES) {
        ushort_t efb = (*flag != 0) ? ((const ushort_t*)ef)[e]
                                    : f2bf(((const float*)ef)[e]);
        int d = dst[e];
        int p = atomicAdd(&cursor[d], 1);
        edges[p] = (unsigned int)src[e] | ((unsigned int)efb << 16);
    }
}

// ---------------- MFMA GEMM (QKV): seg 0 -> Q bf16 [N,128];
//                  segs 1/2 -> K/V packed fp8-e4m3 into KV [N,256B]
//                  (per 8-dim block b: bytes 16b..16b+7 = K dims, +8..+15 = V dims).
// Block: 256 thr = 4 waves; wave = 16 rows x 128 cols; grid = (M/64, 3 segs).
template <int KB>
__global__ __launch_bounds__(256) void qkv_gemm(
    const ushort_t* __restrict__ A,
    const ushort_t* __restrict__ Bswz,
    ushort_t* __restrict__ outQ,
    unsigned char* __restrict__ outKV) {
    const int K = KB * 32;
    const int tid = threadIdx.x;
    const int wv = tid >> 6, lane = tid & 63;
    const int col = lane & 15, quad = lane >> 4;
    const int m0 = blockIdx.x * 64 + wv * 16;
    const int ct0 = blockIdx.y * 8;

    float4v acc[8];
#pragma unroll
    for (int ct = 0; ct < 8; ++ct) acc[ct] = (float4v){0.f, 0.f, 0.f, 0.f};

    const ushort_t* Ap = A + (size_t)(m0 + col) * K + quad * 8;
    const ushort_t* Bp = Bswz + (size_t)ct0 * KB * 512 + lane * 8;

#pragma unroll
    for (int kb = 0; kb < KB; ++kb) {
        short8v a = *(const short8v*)(Ap + kb * 32);
#pragma unroll
        for (int ct = 0; ct < 8; ++ct) {
            short8v b = *(const short8v*)(Bp + (size_t)(ct * KB + kb) * 512);
            acc[ct] = __builtin_amdgcn_mfma_f32_16x16x32_bf16(a, b, acc[ct], 0, 0, 0);
        }
    }

    const int rowb = m0 + quad * 4;
    const int seg = blockIdx.y;
    if (seg == 0) {
#pragma unroll
        for (int ct = 0; ct < 8; ++ct) {
            int j = ct * 16 + col;
#pragma unroll
            for (int r = 0; r < 4; ++r)
                outQ[(size_t)(rowb + r) * 128 + j] = f2bf(acc[ct][r]);
        }
    } else {
        const int vofs = (seg == 2) ? 8 : 0;
#pragma unroll
        for (int ct = 0; ct < 8; ++ct) {
            int j = ct * 16 + col;
            int off = ((j >> 3) * 16) + (j & 7) + vofs;
#pragma unroll
            for (int r = 0; r < 4; ++r) {
                float a = acc[ct][r];
                float b = __shfl_xor(a, 1, 64);   // partner col (j^1) same ct,r
                if ((col & 1) == 0) {
                    unsigned short pk = (unsigned short)
                        __builtin_amdgcn_cvt_pk_fp8_f32(a, b, 0, false);
                    *(ushort_t*)(outKV + (size_t)(rowb + r) * 256 + off) = pk;
                }
            }
        }
    }
}

// ---------------- fused layer tail: hout = LN2(h' + relu(h'@Wf1+b)@Wf2+b2),
//                  h' = LN1(hin + HOUT@WL+bl). One wave per 16-row tile.
// OVERLAPPED-TILE grid: m0 = blockIdx.x*8, grid N/8-1 -> each row computed twice
// (bit-identical, benign duplicate stores). Doubles resident waves (latency-bound
// kernel at grid-limited 8 waves/CU). Requires hin!=hout, HOUT separate (no RAW).
__global__ __launch_bounds__(64, 2) void ffn_kernel(
    const ushort_t* __restrict__ HOUT,   // [N,128] bf16 (attention out, read-only)
    const ushort_t* __restrict__ BWL,    // swz W_lin  (8ct x 4kb)
    const ushort_t* __restrict__ BF1,    // swz Wf1    (16ct x 4kb)
    const ushort_t* __restrict__ BF2,    // swz Wf2    (8ct x 8kb)
    const float* __restrict__ bl,
    const float* __restrict__ g1v, const float* __restrict__ be1v,
    const float* __restrict__ bf1v,
    const float* __restrict__ bf2v,
    const float* __restrict__ g2v, const float* __restrict__ be2v,
    const float* __restrict__ hin,       // [N,128] f32 residual in (read-only)
    float* __restrict__ hout,            // [N,128] f32 out (ping-pong)
    ushort_t* __restrict__ hb) {         // [N,128] bf16 out (ping-pong)
    __shared__ __align__(16) char ldsraw[16 * 528];   // 8448 B, dual-view
    ushort_t* ldsu = (ushort_t*)ldsraw;  // stride LDS_STRIDE (264)
    float* ldsf = (float*)ldsraw;        // stride LDS_FSTRIDE (132)
    const int lane = threadIdx.x & 63;
    const int col = lane & 15, quad = lane >> 4;
    const int m0 = blockIdx.x * 8;           // overlapped tiles (see header)
    const int rowb = m0 + quad * 4;          // global row base (C-layout)
    const int lrowc = quad * 4;              // LDS row base for C-layout stores
    const int lrowa = col;                   // LDS row for A-fragment reads

    // ---- GEMM1: HOUT @ W_lin ----
    float4v acc[8];
#pragma unroll
    for (int ct = 0; ct < 8; ++ct) acc[ct] = (float4v){0.f, 0.f, 0.f, 0.f};
    const ushort_t* Ap = HOUT + (size_t)(m0 + col) * 128 + quad * 8;
#pragma unroll
    for (int kb = 0; kb < 4; ++kb) {
        short8v a = *(const short8v*)(Ap + kb * 32);
#pragma unroll
        for (int ct = 0; ct < 8; ++ct) {
            short8v b = *(const short8v*)(BWL + (size_t)(ct * 4 + kb) * 512 + lane * 8);
            acc[ct] = __builtin_amdgcn_mfma_f32_16x16x32_bf16(a, b, acc[ct], 0, 0, 0);
        }
    }

    // ---- LN1 (+bias, +residual hin) -> val (h', kept in registers) ----
    float val[8][4], s[4] = {0.f, 0.f, 0.f, 0.f}, ss[4] = {0.f, 0.f, 0.f, 0.f};
#pragma unroll
    for (int ct = 0; ct < 8; ++ct) {
        float bi = bl[ct * 16 + col];
#pragma unroll
        for (int r = 0; r < 4; ++r) {
            float v = acc[ct][r] + bi + hin[(size_t)(rowb + r) * 128 + ct * 16 + col];
            val[ct][r] = v;
            s[r] += v;
            ss[r] += v * v;
        }
    }
#pragma unroll
    for (int mask = 1; mask < 16; mask <<= 1) {
#pragma unroll
        for (int r = 0; r < 4; ++r) {
            s[r] += __shfl_xor(s[r], mask, 64);
            ss[r] += __shfl_xor(ss[r], mask, 64);
        }
    }
#pragma unroll
    for (int r = 0; r < 4; ++r) {
        float mean = s[r] * (1.f / 128.f);
        float var = ss[r] * (1.f / 128.f) - mean * mean;
        s[r] = mean;
        ss[r] = rsqrtf(var + LN_EPS);
    }
#pragma unroll
    for (int ct = 0; ct < 8; ++ct) {
        float gg = g1v[ct * 16 + col], bb = be1v[ct * 16 + col];
#pragma unroll
        for (int r = 0; r < 4; ++r) {
            float o = (val[ct][r] - s[r]) * ss[r] * gg + bb;
            val[ct][r] = o;                                      // residual for LN2
            ldsu[(lrowc + r) * LDS_STRIDE + ct * 16 + col] = f2bf(o);
        }
    }
    __syncthreads();

    // ---- A-fragments of h' from LDS ----
    short8v af[4];
#pragma unroll
    for (int kb = 0; kb < 4; ++kb)
        af[kb] = *(const short8v*)&ldsu[lrowa * LDS_STRIDE + kb * 32 + quad * 8];

    // ---- GEMM2: h' @ Wf1 (OC=256) ----
    float4v acc2[16];
#pragma unroll
    for (int ct = 0; ct < 16; ++ct) acc2[ct] = (float4v){0.f, 0.f, 0.f, 0.f};
#pragma unroll
    for (int kb = 0; kb < 4; ++kb) {
#pragma unroll
        for (int ct = 0; ct < 16; ++ct) {
            short8v b = *(const short8v*)(BF1 + (size_t)(ct * 4 + kb) * 512 + lane * 8);
            acc2[ct] = __builtin_amdgcn_mfma_f32_16x16x32_bf16(af[kb], b, acc2[ct], 0, 0, 0);
        }
    }
    __syncthreads();

    // ---- T = relu(acc2 + bf1) -> LDS ----
#pragma unroll
    for (int ct = 0; ct < 16; ++ct) {
        float bi = bf1v[ct * 16 + col];
#pragma unroll
        for (int r = 0; r < 4; ++r) {
            float v = fmaxf(acc2[ct][r] + bi, 0.f);
            ldsu[(lrowc + r) * LDS_STRIDE + ct * 16 + col] = f2bf(v);
        }
    }
    __syncthreads();

    // ---- GEMM3: T @ Wf2 (K=256) ----
    float4v acc3[8];
#pragma unroll
    for (int ct = 0; ct < 8; ++ct) acc3[ct] = (float4v){0.f, 0.f, 0.f, 0.f};
#pragma unroll
    for (int kb = 0; kb < 8; ++kb) {
        short8v a = *(const short8v*)&ldsu[lrowa * LDS_STRIDE + kb * 32 + quad * 8];
#pragma unroll
        for (int ct = 0; ct < 8; ++ct) {
            short8v b = *(const short8v*)(BF2 + (size_t)(ct * 8 + kb) * 512 + lane * 8);
            acc3[ct] = __builtin_amdgcn_mfma_f32_16x16x32_bf16(a, b, acc3[ct], 0, 0, 0);
        }
    }

    // ---- LN2 (+bias, +residual h') ----
    float s2[4] = {0.f, 0.f, 0.f, 0.f}, ss2[4] = {0.f, 0.f, 0.f, 0.f};
#pragma unroll
    for (int ct = 0; ct < 8; ++ct) {
        float bi = bf2v[ct * 16 + col];
#pragma unroll
        for (int r = 0; r < 4; ++r) {
            float v = acc3[ct][r] + bi + val[ct][r];
            val[ct][r] = v;
            s2[r] += v;
            ss2[r] += v * v;
        }
    }
#pragma unroll
    for (int mask = 1; mask < 16; mask <<= 1) {
#pragma unroll
        for (int r = 0; r < 4; ++r) {
            s2[r] += __shfl_xor(s2[r], mask, 64);
            ss2[r] += __shfl_xor(ss2[r], mask, 64);
        }
    }
#pragma unroll
    for (int r = 0; r < 4; ++r) {
        float mean = s2[r] * (1.f / 128.f);
        float var = ss2[r] * (1.f / 128.f) - mean * mean;
        s2[r] = mean;
        ss2[r] = rsqrtf(var + LN_EPS);
    }
    __syncthreads();   // T fully consumed; reuse LDS as f32 staging
#pragma unroll
    for (int ct = 0; ct < 8; ++ct) {
        float gg = g2v[ct * 16 + col], bb = be2v[ct * 16 + col];
#pragma unroll
        for (int r = 0; r < 4; ++r) {
            float o = (val[ct][r] - s2[r]) * ss2[r] * gg + bb;
            ldsf[(lrowc + r) * LDS_FSTRIDE + ct * 16 + col] = o;
        }
    }
    __syncthreads();

    // ---- coalesced stores: hout as float4, hb as uint4 (8 bf16) ----
#pragma unroll
    for (int j = 0; j < 8; ++j) {
        int p = lane + j * 64;        // 0..511
        int row = p >> 5;
        int c4 = p & 31;
        float4 vv = *(const float4*)&ldsf[row * LDS_FSTRIDE + c4 * 4];
        *(float4*)&hout[(size_t)(m0 + row) * 128 + c4 * 4] = vv;
    }
#pragma unroll
    for (int j = 0; j < 4; ++j) {
        int p = lane + j * 64;        // 0..255
        int row = p >> 4;
        int c8 = p & 15;
        float4 va = *(const float4*)&ldsf[row * LDS_FSTRIDE + c8 * 8];
        float4 vb = *(const float4*)&ldsf[row * LDS_FSTRIDE + c8 * 8 + 4];
        uint4 ou;
        ou.x = (unsigned)f2bf(va.x) | ((unsigned)f2bf(va.y) << 16);
        ou.y = (unsigned)f2bf(va.z) | ((unsigned)f2bf(va.w) << 16);
        ou.z = (unsigned)f2bf(vb.x) | ((unsigned)f2bf(vb.y) << 16);
        ou.w = (unsigned)f2bf(vb.z) | ((unsigned)f2bf(vb.w) << 16);
        *(uint4*)&hb[(size_t)(m0 + row) * 128 + c8 * 8] = ou;
    }
}

// ---------------- attention aggregation --------------------------------------------
// One WAVE per dst node. 4 edge-groups x 16 lanes; lane covers 8 dims (sub = lane&15).
// Q bf16 [N,128]; K/V fp8-e4m3 packed [N,256B] -> ONE uint4 gather per edge per lane.
// Main loop batched 4-DEEP: avg degree 16 -> nfull ~4, so one batch covers a typical
// node's entire main loop -> one exposed gather latency instead of two.
// Log2-domain lazy-max online softmax (u/c1 pre-scaled by isq*log2e).
__global__ __launch_bounds__(64) void agg_kernel(
    const ushort_t* __restrict__ Q, const unsigned char* __restrict__ KV,
    const int* __restrict__ rowstart, const unsigned int* __restrict__ edges,
    const float* __restrict__ u, const float* __restrict__ c1,
    ushort_t* __restrict__ hout) {
    const int lane = threadIdx.x & 63;
    const int v = blockIdx.x;
    const int sub = lane & 15;
    const int grp = lane >> 4;

    // Q dims 8sub..+7 (uint4 = 8 bf16)
    uint4 qu = *(const uint4*)(Q + (size_t)v * 128 + sub * 8);
    float q0 = lo16(qu.x), q1 = hi16(qu.x), q2 = lo16(qu.y), q3 = hi16(qu.y);
    float q4 = lo16(qu.z), q5 = hi16(qu.z), q6 = lo16(qu.w), q7 = hi16(qu.w);
    float4 uva = *(const float4*)(u + sub * 8);
    float4 uvb = *(const float4*)(u + sub * 8 + 4);
    float4 cva = *(const float4*)(c1 + sub * 8);
    float4 cvb = *(const float4*)(c1 + sub * 8 + 4);

    float m = -1.0e38f;
    float sA[8] = {0.f, 0.f, 0.f, 0.f, 0.f, 0.f, 0.f, 0.f};
    float o[8] = {0.f, 0.f, 0.f, 0.f, 0.f, 0.f, 0.f, 0.f};

    const int start = rowstart[v];
    const int deg = rowstart[v + 1] - start;
    const int nfull = deg >> 2;
    const unsigned int* ep = edges + start + grp;

// compute body consuming a pre-loaded edge word + KV vector
#define AGG_COMPUTE(PE, KVv, MASKED, VALID)                                      \
    {                                                                            \
        float ef_ = __uint_as_float((PE) & 0xFFFF0000u);                         \
        float2v k01 = __builtin_amdgcn_cvt_pk_f32_fp8((KVv).x, false);           \
        float2v k23 = __builtin_amdgcn_cvt_pk_f32_fp8((KVv).x, true);            \
        float2v k45 = __builtin_amdgcn_cvt_pk_f32_fp8((KVv).y, false);           \
        float2v k67 = __builtin_amdgcn_cvt_pk_f32_fp8((KVv).y, true);            \
        float p_ = k01[0] * q0;                                                  \
        p_ = fmaf(k01[1], q1, p_);                                               \
        p_ = fmaf(k23[0], q2, p_);                                               \
        p_ = fmaf(k23[1], q3, p_);                                               \
        p_ = fmaf(k45[0], q4, p_);                                               \
        p_ = fmaf(k45[1], q5, p_);                                               \
        p_ = fmaf(k67[0], q6, p_);                                               \
        p_ = fmaf(k67[1], q7, p_);                                               \
        p_ += __shfl_xor(p_, 1, 64);                                             \
        p_ += __shfl_xor(p_, 2, 64);                                             \
        float x0 = p_ * fmaf(ef_, uva.x, cva.x);                                 \
        float x1 = p_ * fmaf(ef_, uva.y, cva.y);                                 \
        float x2 = p_ * fmaf(ef_, uva.z, cva.z);                                 \
        float x3 = p_ * fmaf(ef_, uva.w, cva.w);                                 \
        float x4 = p_ * fmaf(ef_, uvb.x, cvb.x);                                 \
        float x5 = p_ * fmaf(ef_, uvb.y, cvb.y);                                 \
        float x6 = p_ * fmaf(ef_, uvb.z, cvb.z);                                 \
        float x7 = p_ * fmaf(ef_, uvb.w, cvb.w);                                 \
        if (MASKED) {                                                            \
            x0 = (VALID) ? x0 : -1.0e38f; x1 = (VALID) ? x1 : -1.0e38f;          \
            x2 = (VALID) ? x2 : -1.0e38f; x3 = (VALID) ? x3 : -1.0e38f;          \
            x4 = (VALID) ? x4 : -1.0e38f; x5 = (VALID) ? x5 : -1.0e38f;          \
            x6 = (VALID) ? x6 : -1.0e38f; x7 = (VALID) ? x7 : -1.0e38f;          \
        }                                                                        \
        float xm = fmaxf(fmaxf(fmaxf(x0, x1), fmaxf(x2, x3)),                    \
                         fmaxf(fmaxf(x4, x5), fmaxf(x6, x7)));                   \
        if (xm > m) {                                                            \
            float nm = xm + 6.0f;                                                \
            float sc = EXP2(m - nm);                                             \
            sA[0] *= sc; sA[1] *= sc; sA[2] *= sc; sA[3] *= sc;                  \
            sA[4] *= sc; sA[5] *= sc; sA[6] *= sc; sA[7] *= sc;                  \
            o[0] *= sc; o[1] *= sc; o[2] *= sc; o[3] *= sc;                      \
            o[4] *= sc; o[5] *= sc; o[6] *= sc; o[7] *= sc;                      \
            m = nm;                                                              \
        }                                                                        \
        float e0 = EXP2(x0 - m), e1 = EXP2(x1 - m);                              \
        float e2 = EXP2(x2 - m), e3 = EXP2(x3 - m);                              \
        float e4 = EXP2(x4 - m), e5 = EXP2(x5 - m);                              \
        float e6 = EXP2(x6 - m), e7 = EXP2(x7 - m);                              \
        sA[0] += e0; sA[1] += e1; sA[2] += e2; sA[3] += e3;                      \
        sA[4] += e4; sA[5] += e5; sA[6] += e6; sA[7] += e7;                      \
        float2v v01 = __builtin_amdgcn_cvt_pk_f32_fp8((KVv).z, false);           \
        float2v v23 = __builtin_amdgcn_cvt_pk_f32_fp8((KVv).z, true);            \
        float2v v45 = __builtin_amdgcn_cvt_pk_f32_fp8((KVv).w, false);           \
        float2v v67 = __builtin_amdgcn_cvt_pk_f32_fp8((KVv).w, true);            \
        o[0] = fmaf(v01[0], e0, o[0]);                                           \
        o[1] = fmaf(v01[1], e1, o[1]);                                           \
        o[2] = fmaf(v23[0], e2, o[2]);                                           \
        o[3] = fmaf(v23[1], e3, o[3]);                                           \
        o[4] = fmaf(v45[0], e4, o[4]);                                           \
        o[5] = fmaf(v45[1], e5, o[5]);                                           \
        o[6] = fmaf(v67[0], e6, o[6]);                                           \
        o[7] = fmaf(v67[1], e7, o[7]);                                           \
    }

    int it = 0;
    for (; it + 4 <= nfull; it += 4) {
        // batch: issue all 4 edge words + all 4 KV gathers before any compute
        unsigned int pe0 = ep[4 * it];
        unsigned int pe1 = ep[4 * it + 4];
        unsigned int pe2 = ep[4 * it + 8];
        unsigned int pe3 = ep[4 * it + 12];
        uint4 kv0 = *(const uint4*)(KV + (size_t)(pe0 & 0xFFFFu) * 256 + sub * 16);
        uint4 kv1 = *(const uint4*)(KV + (size_t)(pe1 & 0xFFFFu) * 256 + sub * 16);
        uint4 kv2 = *(const uint4*)(KV + (size_t)(pe2 & 0xFFFFu) * 256 + sub * 16);
        uint4 kv3 = *(const uint4*)(KV + (size_t)(pe3 & 0xFFFFu) * 256 + sub * 16);
        AGG_COMPUTE(pe0, kv0, false, true)
        AGG_COMPUTE(pe1, kv1, false, true)
        AGG_COMPUTE(pe2, kv2, false, true)
        AGG_COMPUTE(pe3, kv3, false, true)
    }
    if (it + 2 <= nfull) {
        unsigned int pe0 = ep[4 * it];
        unsigned int pe1 = ep[4 * it + 4];
        uint4 kv0 = *(const uint4*)(KV + (size_t)(pe0 & 0xFFFFu) * 256 + sub * 16);
        uint4 kv1 = *(const uint4*)(KV + (size_t)(pe1 & 0xFFFFu) * 256 + sub * 16);
        AGG_COMPUTE(pe0, kv0, false, true)
        AGG_COMPUTE(pe1, kv1, false, true)
        it += 2;
    }
    if (it < nfull) {
        unsigned int pe0 = ep[4 * it];
        uint4 kv0 = *(const uint4*)(KV + (size_t)(pe0 & 0xFFFFu) * 256 + sub * 16);
        AGG_COMPUTE(pe0, kv0, false, true)
    }
    const int rem = deg & 3;
    if (rem) {
        bool valid = grp < rem;
        unsigned int pe = valid ? ep[4 * nfull] : edges[start];
        uint4 kv = *(const uint4*)(KV + (size_t)(pe & 0xFFFFu) * 256 + sub * 16);
        AGG_COMPUTE(pe, kv, true, valid)
    }
#undef AGG_COMPUTE

    // merge the 4 edge-groups (partners lane^16, lane^32 hold the same dims)
#pragma unroll
    for (int mask = 16; mask <= 32; mask <<= 1) {
        float mo = __shfl_xor(m, mask, 64);
        float mm = fmaxf(m, mo);
        float sca = EXP2(m - mm);
        float scb = EXP2(mo - mm);
#pragma unroll
        for (int j = 0; j < 8; ++j) {
            float t = __shfl_xor(sA[j], mask, 64);
            sA[j] = sA[j] * sca + t * scb;
            t = __shfl_xor(o[j], mask, 64);
            o[j] = o[j] * sca + t * scb;
        }
        m = mm;
    }

    if (grp == 0) {
        // ref: h_out = num / max(Z, 1e-6); ours scaled by 2^m; 1e-37 NaN guard
        float zc = 1e-6f * EXP2(-m);
        uint4 ou;
        unsigned int w0, w1;
        float z;
        z = fmaxf(fmaxf(sA[0], zc), 1e-37f); w0 = f2bf(o[0] / z);
        z = fmaxf(fmaxf(sA[1], zc), 1e-37f); w1 = f2bf(o[1] / z);
        ou.x = w0 | (w1 << 16);
        z = fmaxf(fmaxf(sA[2], zc), 1e-37f); w0 = f2bf(o[2] / z);
        z = fmaxf(fmaxf(sA[3], zc), 1e-37f); w1 = f2bf(o[3] / z);
        ou.y = w0 | (w1 << 16);
        z = fmaxf(fmaxf(sA[4], zc), 1e-37f); w0 = f2bf(o[4] / z);
        z = fmaxf(fmaxf(sA[5], zc), 1e-37f); w1 = f2bf(o[5] / z);
        ou.z = w0 | (w1 << 16);
        z = fmaxf(fmaxf(sA[6], zc), 1e-37f); w0 = f2bf(o[6] / z);
        z = fmaxf(fmaxf(sA[7], zc), 1e-37f); w1 = f2bf(o[7] / z);
        ou.w = w0 | (w1 << 16);
        *(uint4*)(hout + (size_t)v * 128 + sub * 8) = ou;
    }
}

// ---------------- mean over nodes ------------------------------------------------------
__global__ void mean_part_kernel(const float* __restrict__ h, float* __restrict__ macc) {
    __shared__ float s[256];
    int t = threadIdx.x;
    int col = t & 127;
    int half = t >> 7;
    int r0 = blockIdx.x * 256;
    float acc = 0.f;
    for (int r = half; r < 256; r += 2) acc += h[(size_t)(r0 + r) * 128 + col];
    s[t] = acc;
    __syncthreads();
    if (t < 128) atomicAdd(&macc[t], s[t] + s[t + 128]);
}

// ---------------- finalize -------------------------------------------------------------
__global__ void finalize_kernel(const float* __restrict__ macc, void* __restrict__ out,
                                const int* __restrict__ flag) {
    int t = threadIdx.x;
    float v = macc[t] * (1.f / (float)N_NODES);
    if (*flag)
        ((ushort_t*)out)[t] = f2bf(v);
    else
        ((float*)out)[t] = v;
}

// ---------------------------------------------------------------------------------------
extern "C" void kernel_launch(void* const* d_in, const int* in_sizes, int n_in,
                              void* d_out, int out_size, void* d_ws, size_t ws_size,
                              hipStream_t stream) {
    const int* src = (const int*)d_in[3];
    const int* dst = (const int*)d_in[4];

    char* w = (char*)d_ws;
    const size_t MB = 1u << 20;
    float* hA       = (float*)(w);               // 16 MB [N,128] f32 (ping)
    float* hB       = (float*)(w + 16 * MB);     // 16 MB [N,128] f32 (pong)
    ushort_t* hbA   = (ushort_t*)(w + 32 * MB);  //  8 MB [N,128] bf16 (ping, qkv A-in)
    ushort_t* hbB   = (ushort_t*)(w + 40 * MB);  //  8 MB [N,128] bf16 (pong)
    ushort_t* HOUT  = (ushort_t*)(w + 48 * MB);  //  8 MB [N,128] bf16 (agg out)
    ushort_t* Qh    = (ushort_t*)(w + 56 * MB);  //  8 MB [N,128] bf16
    unsigned char* KVf8 = (unsigned char*)(w + 64 * MB);  // 8 MB [N,256B] fp8 K|V packed
    char* aux       = w + 72 * MB;
    int* deg        = (int*)(aux);               // 128 KB
    int* rowstart   = (int*)(aux + 0x40000);     // 128 KB + 4
    int* cursor     = (int*)(aux + 0x80000);     // 128 KB
    unsigned int* edges = (unsigned int*)(aux + 0xC0000);          // 2 MB
    float* ubuf     = (float*)(aux + 0xC0000 + 2 * MB);            // 3*128 f32
    float* cbuf     = ubuf + 3 * 128;
    float* macc     = cbuf + 3 * 128;            // 128 f32
    int* flag       = (int*)(macc + 128);
    float* conv     = (float*)(aux + 0xC0000 + 2 * MB + 4096);     // 40 KB f32
    ushort_t* swz   = (ushort_t*)((char*)conv + CONV_TOTAL * 4);   // 784 KB bf16

    detect_kernel<<<1, 256, 0, stream>>>((const unsigned int*)d_in[5], flag);

    ConvArgs ca;
    ca.src[0] = d_in[5];    // W_node
    ca.src[1] = d_in[6];    // b_node
    ca.src[2] = d_in[7];    // W_pos
    ca.src[3] = d_in[8];    // b_pos
    ca.src[4] = d_in[9];    // W_edge
    ca.src[5] = d_in[10];   // b_edge
    ca.src[6] = d_in[16];   // b_lin
    ca.src[7] = d_in[17];   // g1
    ca.src[8] = d_in[18];   // be1
    ca.src[9] = d_in[20];   // bf1
    ca.src[10] = d_in[22];  // bf2
    ca.src[11] = d_in[23];  // g2
    ca.src[12] = d_in[24];  // be2
    // convert also zeros deg (replaces hipMemsetAsync node)
    convert_kernel<<<(CONV_TOTAL + 255) / 256, 256, 0, stream>>>(ca, flag, conv, deg);

    // swz (192 blocks) + fused uc (3 blocks) + input-proj records (4 blocks)
    swz_kernel<<<192 + 3 + 4, 256, 0, stream>>>(
        d_in[11], d_in[12], d_in[13], d_in[15], d_in[19], d_in[21],
        d_in[14], d_in[9], d_in[10], d_in[5], d_in[7], flag, swz, ubuf, cbuf);

    // input projection via MFMA + fused degree histogram
    ip_gemm<<<N_NODES / 64, 256, 0, stream>>>(d_in[0], d_in[1], conv, flag, dst, deg,
                                              swz + (size_t)REC_WNP * 512, hA, hbA);
    // scan also zeros macc (replaces hipMemsetAsync node)
    scan_kernel<<<1, 1024, 0, stream>>>(deg, rowstart, cursor, macc);
    scatter_kernel<<<N_EDGES / 256, 256, 0, stream>>>(src, dst, d_in[2], flag, cursor,
                                                      edges);

    for (int i = 0; i < 3; ++i) {
        const ushort_t* swzQKV = swz + (size_t)REC_QKV(i) * 512;
        const ushort_t* swzWL  = swz + (size_t)REC_WLIN(i) * 512;
        const ushort_t* swzF1  = swz + (size_t)REC_WF1(i) * 512;
        const ushort_t* swzF2  = swz + (size_t)REC_WF2(i) * 512;
        // ping-pong: layer i reads hin/Ain, writes hout/Aout (never in-place ->
        // enables ffn's overlapped-tile grid)
        const float* hin   = (i & 1) ? hB : hA;
        float* hout        = (i & 1) ? hA : hB;
        const ushort_t* Ain = (i & 1) ? hbB : hbA;
        ushort_t* Aout      = (i & 1) ? hbA : hbB;

        // Q bf16 + K/V fp8 packed (3-segment, 4-wave blocks)
        qkv_gemm<4><<<dim3(N_NODES / 64, 3), 256, 0, stream>>>(Ain, swzQKV, Qh, KVf8);

        // attention -> HOUT [N,128] bf16 (4-deep batched gather main loop)
        agg_kernel<<<N_NODES, 64, 0, stream>>>(Qh, KVf8, rowstart, edges,
                                               ubuf + i * 128, cbuf + i * 128, HOUT);

        // fused layer tail, overlapped 16-row tiles at 8-row stride (grid N/8-1)
        ffn_kernel<<<N_NODES / 8 - 1, 64, 0, stream>>>(
            HOUT, swzWL, swzF1, swzF2,
            conv + OFF_BLIN + i * 128, conv + OFF_G1 + i * 128, conv + OFF_BE1 + i * 128,
            conv + OFF_BF1 + i * 256,
            conv + OFF_BF2 + i * 128, conv + OFF_G2 + i * 128, conv + OFF_BE2 + i * 128,
            hin, hout, Aout);
    }

    // final h lives in hB (layers 0,2 write hB; layer 1 writes hA)
    mean_part_kernel<<<N_NODES / 256, 256, 0, stream>>>(hB, macc);
    finalize_kernel<<<1, 128, 0, stream>>>(macc, d_out, flag);
}

// Round 9
// 444.444 us; speedup vs baseline: 1.2696x; 1.2696x over previous
//
#include <hip/hip_runtime.h>
#include <hip/hip_bf16.h>

#define N_NODES 32768
#define N_EDGES 524288
#define LN_EPS 1e-5f

typedef unsigned short ushort_t;
typedef __attribute__((ext_vector_type(8))) short short8v;
typedef __attribute__((ext_vector_type(4))) float float4v;
typedef __attribute__((ext_vector_type(2))) float float2v;

__device__ __forceinline__ float bf2f(ushort_t u) {
    return __uint_as_float(((unsigned int)u) << 16);
}
__device__ __forceinline__ ushort_t f2bf(float f) {
    unsigned int u = __float_as_uint(f);
    unsigned int r = (u + 0x7FFFu + ((u >> 16) & 1u)) >> 16;
    return (ushort_t)r;
}
__device__ __forceinline__ float lo16(unsigned int x) { return __uint_as_float(x << 16); }
__device__ __forceinline__ float hi16(unsigned int x) { return __uint_as_float(x & 0xFFFF0000u); }

#if __has_builtin(__builtin_amdgcn_exp2f)
#define EXP2(x) __builtin_amdgcn_exp2f(x)
#else
#define EXP2(x) exp2f(x)
#endif

// compact f32 conv region: only params consumed as f32 (biases, LN, input-proj weights)
#define OFF_WNODE 0
#define OFF_BNODE 5632
#define OFF_WPOS  5760
#define OFF_BPOS  6784
#define OFF_WEDGE 6912
#define OFF_BEDGE 7040
#define OFF_BLIN  7168
#define OFF_G1    7552
#define OFF_BE1   7936
#define OFF_BF1   8320
#define OFF_BF2   9088
#define OFF_G2    9472
#define OFF_BE2   9856
#define CONV_TOTAL 10240

// swizzled-B record bases (records of 512 ushorts = 64 lanes x 8 bf16)
#define REC_QKV(i)  ((i) * 96)          // 24 ct x 4 kb
#define REC_WLIN(i) (288 + (i) * 32)    // 8 ct x 4 kb
#define REC_WF1(i)  (384 + (i) * 64)    // 16 ct x 4 kb
#define REC_WF2(i)  (576 + (i) * 64)    // 8 ct x 8 kb
#define REC_WNP     768                 // input-proj [Wn;Wp;0] 8 ct x 2 kb
#define REC_TOTAL   784

#define LDS_STRIDE 264   // ushorts per LDS row (256 + 8 pad)
#define LDS_FSTRIDE 132  // floats per LDS row (same byte footprint)

// ---------------- dtype detection: bf16 data has exponent-like bits at [15:8] ---------
__global__ void detect_kernel(const unsigned int* __restrict__ wn, int* __restrict__ flag) {
    __shared__ int s[256];
    int t = threadIdx.x;
    int cnt = 0;
    for (int i = t; i < 2816; i += 256) {
        unsigned int b = (wn[i] >> 8) & 0x7F;
        cnt += (b >= 0x3A && b <= 0x40) ? 1 : 0;
    }
    s[t] = cnt;
    __syncthreads();
    for (int off = 128; off > 0; off >>= 1) {
        if (t < off) s[t] += s[t + off];
        __syncthreads();
    }
    if (t == 0) *flag = (s[0] > 1408) ? 1 : 0;   // 1 = bf16, 0 = f32
}

// ---------------- canonicalize small param buffers to f32 scratch ---------------------
// Also zeros the degree histogram (replaces a hipMemsetAsync dispatch node).
struct ConvArgs { const void* src[13]; };

__global__ void convert_kernel(ConvArgs a, const int* __restrict__ flag,
                               float* __restrict__ dst, int* __restrict__ deg) {
    int gid = blockIdx.x * 256 + threadIdx.x;
    for (int i = gid; i < N_NODES; i += CONV_TOTAL) deg[i] = 0;   // fused deg-zero
    if (gid >= CONV_TOTAL) return;
    const int off[14] = {OFF_WNODE, OFF_BNODE, OFF_WPOS, OFF_BPOS, OFF_WEDGE, OFF_BEDGE,
                         OFF_BLIN, OFF_G1, OFF_BE1, OFF_BF1, OFF_BF2, OFF_G2, OFF_BE2,
                         CONV_TOTAL};
    int s = 0;
#pragma unroll
    for (int i = 1; i < 13; ++i) s += (gid >= off[i]) ? 1 : 0;
    int local = gid - off[s];
    if (*flag)
        dst[gid] = bf2f(((const ushort_t*)a.src[s])[local]);
    else
        dst[gid] = ((const float*)a.src[s])[local];
}

// ---------------- swizzle GEMM weights into MFMA B-fragment records (raw sources) -----
// record(ct,kb): lane l holds W[kb*32 + (l>>4)*8 + j][ct*16 + (l&15)], j=0..7
// blocks 192..194 compute u/c1 (fused uc); blocks 195..198 build input-proj records.
__global__ void swz_kernel(const void* __restrict__ Wq, const void* __restrict__ Wk,
                           const void* __restrict__ Wv, const void* __restrict__ Wlin,
                           const void* __restrict__ Wf1, const void* __restrict__ Wf2,
                           const void* __restrict__ We, const void* __restrict__ wedge,
                           const void* __restrict__ bedge,
                           const void* __restrict__ Wn_, const void* __restrict__ Wp_,
                           const int* __restrict__ flag,
                           ushort_t* __restrict__ swz,
                           float* __restrict__ u, float* __restrict__ c1) {
    const bool isbf = (*flag != 0);
    if (blockIdx.x >= 195) {
        // input-proj B records: W[k][n], k = 0..43 Wn, 44..51 Wp, 52..63 zero pad
        int idx = (blockIdx.x - 195) * 256 + threadIdx.x;   // 0..1023
        int rec16 = idx >> 6;                               // 0..15
        int lane = idx & 63;
        int ct = rec16 >> 1, kb = rec16 & 1;
        int col = lane & 15, quad = lane >> 4;
        int n = ct * 16 + col;
        ushort_t v[8];
#pragma unroll
        for (int j = 0; j < 8; ++j) {
            int k = kb * 32 + quad * 8 + j;
            if (isbf) {
                v[j] = (k < 44) ? ((const ushort_t*)Wn_)[k * 128 + n]
                     : ((k < 52) ? ((const ushort_t*)Wp_)[(k - 44) * 128 + n]
                                 : (ushort_t)0);
            } else {
                float f = (k < 44) ? ((const float*)Wn_)[k * 128 + n]
                        : ((k < 52) ? ((const float*)Wp_)[(k - 44) * 128 + n] : 0.f);
                v[j] = f2bf(f);
            }
        }
        ushort_t* o = swz + (size_t)(REC_WNP + rec16) * 512 + lane * 8;
#pragma unroll
        for (int j = 0; j < 8; ++j) o[j] = v[j];
        return;
    }
    if (blockIdx.x >= 192) {
        // fused uc: pre-scaled by (1/sqrt(dk))*log2(e); agg works in log2 domain
        int l = blockIdx.x - 192;
        int d = threadIdx.x;
        if (d >= 128) return;
        float uu = 0.f, cc = 0.f;
        if (isbf) {
            const ushort_t* Wl = (const ushort_t*)We + (size_t)l * 16384;
            const ushort_t* we_ = (const ushort_t*)wedge;
            const ushort_t* be_ = (const ushort_t*)bedge;
#pragma unroll 4
            for (int k = 0; k < 128; ++k) {
                float w = bf2f(Wl[k * 128 + d]);
                uu = fmaf(bf2f(we_[k]), w, uu);
                cc = fmaf(bf2f(be_[k]), w, cc);
            }
        } else {
            const float* Wl = (const float*)We + (size_t)l * 16384;
            const float* we_ = (const float*)wedge;
            const float* be_ = (const float*)bedge;
#pragma unroll 4
            for (int k = 0; k < 128; ++k) {
                float w = Wl[k * 128 + d];
                uu = fmaf(we_[k], w, uu);
                cc = fmaf(be_[k], w, cc);
            }
        }
        const float scale = 0.17677669529663687f * 1.4426950408889634f;  // isq * log2(e)
        u[l * 128 + d] = uu * scale;
        c1[l * 128 + d] = (1.f + cc) * scale;
        return;
    }
    int gid = blockIdx.x * 256 + threadIdx.x;
    int lane = gid & 63;
    int rec = gid >> 6;
    int col = lane & 15, quad = lane >> 4;
    const void* src;
    size_t base;
    int ct, kb, OC;
    if (rec < 288) {                       // QKV: 3 layers x 24ct x 4kb
        int layer = rec / 96, r2 = rec % 96;
        ct = r2 >> 2; kb = r2 & 3;
        int seg = ct >> 3;                 // 0=Wq 1=Wk 2=Wv
        src = (seg == 0) ? Wq : ((seg == 1) ? Wk : Wv);
        base = (size_t)layer * 16384; OC = 128; ct &= 7;
    } else if (rec < 384) {                // W_lin
        int r = rec - 288, layer = r / 32, r2 = r % 32;
        ct = r2 >> 2; kb = r2 & 3;
        src = Wlin; base = (size_t)layer * 16384; OC = 128;
    } else if (rec < 576) {                // Wf1 (OC=256)
        int r = rec - 384, layer = r / 64, r2 = r % 64;
        ct = r2 >> 2; kb = r2 & 3;
        src = Wf1; base = (size_t)layer * 32768; OC = 256;
    } else {                               // Wf2 (K=256)
        int r = rec - 576, layer = r / 64, r2 = r % 64;
        ct = r2 >> 3; kb = r2 & 7;
        src = Wf2; base = (size_t)layer * 32768; OC = 128;
    }
    int n = ct * 16 + col;
    ushort_t v[8];
    if (isbf) {
        const ushort_t* s16 = (const ushort_t*)src + base;
#pragma unroll
        for (int j = 0; j < 8; ++j) v[j] = s16[(size_t)(kb * 32 + quad * 8 + j) * OC + n];
    } else {
        const float* s32 = (const float*)src + base;
#pragma unroll
        for (int j = 0; j < 8; ++j) v[j] = f2bf(s32[(size_t)(kb * 32 + quad * 8 + j) * OC + n]);
    }
    ushort_t* o = swz + (size_t)rec * 512 + lane * 8;
#pragma unroll
    for (int j = 0; j < 8; ++j) o[j] = v[j];
}

// ---------------- input projection via MFMA: h = [feats|lap|0] @ [Wn;Wp;0] + biases ---
// Grid N/64 blocks x 256 thr (4 waves); A tile staged bf16 in LDS; B from swz records.
// Fused degree histogram (4 strided passes). Outputs h f32 + hb bf16.
__global__ __launch_bounds__(256) void ip_gemm(
    const void* __restrict__ feats, const void* __restrict__ lap,
    const float* __restrict__ conv, const int* __restrict__ flag,
    const int* __restrict__ dstidx, int* __restrict__ deg,
    const ushort_t* __restrict__ Bswz,   // = swz + REC_WNP*512
    float* __restrict__ h, ushort_t* __restrict__ hb) {
    __shared__ __align__(16) ushort_t As[64 * 72];   // 64 rows x K=64, stride 72
    const int tid = threadIdx.x;

    // fused histogram: 512*256 threads x 4 edges
    for (int e = blockIdx.x * 256 + tid; e < N_EDGES; e += (N_NODES / 64) * 256)
        atomicAdd(&deg[dstidx[e]], 1);

    const bool isbf = (*flag != 0);
    const int r = tid >> 2;          // 0..63 (tile row)
    const int t4 = tid & 3;          // 16-col chunk
    const int m0g = blockIdx.x * 64;
    {
        const int row = m0g + r;
        ushort_t tmp[16];
        if (isbf) {
            const ushort_t* frow = (const ushort_t*)feats + (size_t)row * 44;
            const ushort_t* prow = (const ushort_t*)lap + (size_t)row * 8;
#pragma unroll
            for (int j = 0; j < 16; ++j) {
                int k = t4 * 16 + j;
                tmp[j] = (k < 44) ? frow[k]
                       : ((k < 52) ? prow[k - 44] : (ushort_t)0);
            }
        } else {
            const float* frow = (const float*)feats + (size_t)row * 44;
            const float* prow = (const float*)lap + (size_t)row * 8;
#pragma unroll
            for (int j = 0; j < 16; ++j) {
                int k = t4 * 16 + j;
                float v = (k < 44) ? frow[k] : ((k < 52) ? prow[k - 44] : 0.f);
                tmp[j] = f2bf(v);
            }
        }
#pragma unroll
        for (int j = 0; j < 16; ++j) As[r * 72 + t4 * 16 + j] = tmp[j];
    }
    __syncthreads();

    const int wv = tid >> 6, lane = tid & 63;
    const int col = lane & 15, quad = lane >> 4;
    const int m0 = wv * 16;
    short8v a0 = *(const short8v*)&As[(m0 + col) * 72 + quad * 8];
    short8v a1 = *(const short8v*)&As[(m0 + col) * 72 + 32 + quad * 8];

    float4v acc[8];
#pragma unroll
    for (int ct = 0; ct < 8; ++ct) {
        short8v b0 = *(const short8v*)(Bswz + (size_t)(ct * 2 + 0) * 512 + lane * 8);
        short8v b1 = *(const short8v*)(Bswz + (size_t)(ct * 2 + 1) * 512 + lane * 8);
        float4v a = (float4v){0.f, 0.f, 0.f, 0.f};
        a = __builtin_amdgcn_mfma_f32_16x16x32_bf16(a0, b0, a, 0, 0, 0);
        a = __builtin_amdgcn_mfma_f32_16x16x32_bf16(a1, b1, a, 0, 0, 0);
        acc[ct] = a;
    }

    const int rowb = m0g + m0 + quad * 4;
#pragma unroll
    for (int ct = 0; ct < 8; ++ct) {
        int j = ct * 16 + col;
        float bias = conv[OFF_BNODE + j] + conv[OFF_BPOS + j];
#pragma unroll
        for (int rr = 0; rr < 4; ++rr) {
            float o = acc[ct][rr] + bias;
            h[(size_t)(rowb + rr) * 128 + j] = o;
            hb[(size_t)(rowb + rr) * 128 + j] = f2bf(o);
        }
    }
}

// ---------------- CSR build ------------------------------------------------------------
// Also zeros macc (replaces a hipMemsetAsync dispatch node; mean_part runs much later).
__global__ void scan_kernel(const int* __restrict__ deg, int* __restrict__ rowstart,
                            int* __restrict__ cursor, float* __restrict__ macc) {
    __shared__ int lds[1024];
    int t = threadIdx.x;
    if (t < 128) macc[t] = 0.f;                 // fused macc-zero
    int base = t * 32;
    int v[32];
    int csum = 0;
#pragma unroll
    for (int j = 0; j < 8; ++j) {               // coalesced int4 loads
        int4 x = *(const int4*)(deg + base + j * 4);
        v[j * 4 + 0] = x.x; v[j * 4 + 1] = x.y;
        v[j * 4 + 2] = x.z; v[j * 4 + 3] = x.w;
        csum += x.x + x.y + x.z + x.w;
    }
    lds[t] = csum;
    __syncthreads();
    for (int off = 1; off < 1024; off <<= 1) {
        int x = (t >= off) ? lds[t - off] : 0;
        __syncthreads();
        lds[t] += x;
        __syncthreads();
    }
    int excl = lds[t] - csum;
    int running = excl;
#pragma unroll
    for (int j = 0; j < 8; ++j) {
        int4 w;
        w.x = running; running += v[j * 4 + 0];
        w.y = running; running += v[j * 4 + 1];
        w.z = running; running += v[j * 4 + 2];
        w.w = running; running += v[j * 4 + 3];
        *(int4*)(rowstart + base + j * 4) = w;
        *(int4*)(cursor + base + j * 4) = w;
    }
    if (t == 1023) rowstart[N_NODES] = running;
}

__global__ void scatter_kernel(const int* __restrict__ src, const int* __restrict__ dst,
                               const void* __restrict__ ef, const int* __restrict__ flag,
                               int* __restrict__ cursor,
                               unsigned int* __restrict__ edges) {
    int e = blockIdx.x * 256 + threadIdx.x;
    if (e < N_EDGES) {
        ushort_t efb = (*flag != 0) ? ((const ushort_t*)ef)[e]
                                    : f2bf(((const float*)ef)[e]);
        int d = dst[e];
        int p = atomicAdd(&cursor[d], 1);
        edges[p] = (unsigned int)src[e] | ((unsigned int)efb << 16);
    }
}

// ---------------- MFMA GEMM (QKV): seg 0 -> Q bf16 [N,128];
//                  segs 1/2 -> K/V packed fp8-e4m3 into KV [N,256B]
//                  (per 8-dim block b: bytes 16b..16b+7 = K dims, +8..+15 = V dims).
// Block: 256 thr = 4 waves; wave = 16 rows x 128 cols; grid = (M/64, 3 segs).
template <int KB>
__global__ __launch_bounds__(256) void qkv_gemm(
    const ushort_t* __restrict__ A,
    const ushort_t* __restrict__ Bswz,
    ushort_t* __restrict__ outQ,
    unsigned char* __restrict__ outKV) {
    const int K = KB * 32;
    const int tid = threadIdx.x;
    const int wv = tid >> 6, lane = tid & 63;
    const int col = lane & 15, quad = lane >> 4;
    const int m0 = blockIdx.x * 64 + wv * 16;
    const int ct0 = blockIdx.y * 8;

    float4v acc[8];
#pragma unroll
    for (int ct = 0; ct < 8; ++ct) acc[ct] = (float4v){0.f, 0.f, 0.f, 0.f};

    const ushort_t* Ap = A + (size_t)(m0 + col) * K + quad * 8;
    const ushort_t* Bp = Bswz + (size_t)ct0 * KB * 512 + lane * 8;

#pragma unroll
    for (int kb = 0; kb < KB; ++kb) {
        short8v a = *(const short8v*)(Ap + kb * 32);
#pragma unroll
        for (int ct = 0; ct < 8; ++ct) {
            short8v b = *(const short8v*)(Bp + (size_t)(ct * KB + kb) * 512);
            acc[ct] = __builtin_amdgcn_mfma_f32_16x16x32_bf16(a, b, acc[ct], 0, 0, 0);
        }
    }

    const int rowb = m0 + quad * 4;
    const int seg = blockIdx.y;
    if (seg == 0) {
#pragma unroll
        for (int ct = 0; ct < 8; ++ct) {
            int j = ct * 16 + col;
#pragma unroll
            for (int r = 0; r < 4; ++r)
                outQ[(size_t)(rowb + r) * 128 + j] = f2bf(acc[ct][r]);
        }
    } else {
        const int vofs = (seg == 2) ? 8 : 0;
#pragma unroll
        for (int ct = 0; ct < 8; ++ct) {
            int j = ct * 16 + col;
            int off = ((j >> 3) * 16) + (j & 7) + vofs;
#pragma unroll
            for (int r = 0; r < 4; ++r) {
                float a = acc[ct][r];
                float b = __shfl_xor(a, 1, 64);   // partner col (j^1) same ct,r
                if ((col & 1) == 0) {
                    unsigned short pk = (unsigned short)
                        __builtin_amdgcn_cvt_pk_fp8_f32(a, b, 0, false);
                    *(ushort_t*)(outKV + (size_t)(rowb + r) * 256 + off) = pk;
                }
            }
        }
    }
}

// ---------------- fused layer tail: h = LN2(h' + relu(h'@Wf1+b)@Wf2+b2),
//                  h' = LN1(h + HOUT@WL+bl). TWO waves per 16-row tile (grid N/16,
//                  128 thr): wave wv owns half the output columns of each GEMM; LN
//                  row-stats completed via a 64-float LDS exchange. Same total work
//                  as the 1-wave version, 2x resident waves (grid-limited kernel).
__global__ __launch_bounds__(128, 2) void ffn_kernel(
    const ushort_t* __restrict__ HOUT,   // [N,128] bf16 (= hb, attention out)
    const ushort_t* __restrict__ BWL,    // swz W_lin  (8ct x 4kb)
    const ushort_t* __restrict__ BF1,    // swz Wf1    (16ct x 4kb)
    const ushort_t* __restrict__ BF2,    // swz Wf2    (8ct x 8kb)
    const float* __restrict__ bl,
    const float* __restrict__ g1v, const float* __restrict__ be1v,
    const float* __restrict__ bf1v,
    const float* __restrict__ bf2v,
    const float* __restrict__ g2v, const float* __restrict__ be2v,
    float* __restrict__ h,               // [N,128] f32 in-out (residual -> final)
    ushort_t* __restrict__ hb) {         // [N,128] bf16 out
    __shared__ __align__(16) char ldsraw[16 * 528];   // 8448 B, dual-view
    __shared__ float lnx[2][16][2];      // cross-wave LN partials [wave][row][sum,sumsq]
    ushort_t* ldsu = (ushort_t*)ldsraw;  // stride LDS_STRIDE (264)
    float* ldsf = (float*)ldsraw;        // stride LDS_FSTRIDE (132)
    const int tid = threadIdx.x;
    const int wv = tid >> 6;             // 0..1 (column-half owner)
    const int lane = tid & 63;
    const int col = lane & 15, quad = lane >> 4;
    const int m0 = blockIdx.x * 16;
    const int rowb = m0 + quad * 4;          // global row base (C-layout)
    const int lrowc = quad * 4;              // LDS row base for C-layout stores
    const int lrowa = col;                   // LDS row for A-fragment reads
    const int ct0 = wv * 4;                  // GEMM1/GEMM3 ct base (4 of 8)

    // ---- GEMM1: HOUT @ W_lin (this wave: cts ct0..ct0+3) ----
    float4v acc[4];
#pragma unroll
    for (int c = 0; c < 4; ++c) acc[c] = (float4v){0.f, 0.f, 0.f, 0.f};
    const ushort_t* Ap = HOUT + (size_t)(m0 + col) * 128 + quad * 8;
#pragma unroll
    for (int kb = 0; kb < 4; ++kb) {
        short8v a = *(const short8v*)(Ap + kb * 32);
#pragma unroll
        for (int c = 0; c < 4; ++c) {
            short8v b = *(const short8v*)(BWL + (size_t)((ct0 + c) * 4 + kb) * 512 + lane * 8);
            acc[c] = __builtin_amdgcn_mfma_f32_16x16x32_bf16(a, b, acc[c], 0, 0, 0);
        }
    }

    // ---- LN1 (+bias, +residual h): wave-partial stats then cross-wave exchange ----
    float val[4][4], s[4] = {0.f, 0.f, 0.f, 0.f}, ss[4] = {0.f, 0.f, 0.f, 0.f};
#pragma unroll
    for (int c = 0; c < 4; ++c) {
        float bi = bl[(ct0 + c) * 16 + col];
#pragma unroll
        for (int r = 0; r < 4; ++r) {
            float v = acc[c][r] + bi + h[(size_t)(rowb + r) * 128 + (ct0 + c) * 16 + col];
            val[c][r] = v;
            s[r] += v;
            ss[r] += v * v;
        }
    }
#pragma unroll
    for (int mask = 1; mask < 16; mask <<= 1) {
#pragma unroll
        for (int r = 0; r < 4; ++r) {
            s[r] += __shfl_xor(s[r], mask, 64);
            ss[r] += __shfl_xor(ss[r], mask, 64);
        }
    }
    if (col == 0) {
#pragma unroll
        for (int r = 0; r < 4; ++r) {
            lnx[wv][lrowc + r][0] = s[r];
            lnx[wv][lrowc + r][1] = ss[r];
        }
    }
    __syncthreads();
#pragma unroll
    for (int r = 0; r < 4; ++r) {
        float fs = lnx[0][lrowc + r][0] + lnx[1][lrowc + r][0];
        float fss = lnx[0][lrowc + r][1] + lnx[1][lrowc + r][1];
        float mean = fs * (1.f / 128.f);
        float var = fss * (1.f / 128.f) - mean * mean;
        s[r] = mean;
        ss[r] = rsqrtf(var + LN_EPS);
    }
#pragma unroll
    for (int c = 0; c < 4; ++c) {
        float gg = g1v[(ct0 + c) * 16 + col], bb = be1v[(ct0 + c) * 16 + col];
#pragma unroll
        for (int r = 0; r < 4; ++r) {
            float o = (val[c][r] - s[r]) * ss[r] * gg + bb;
            val[c][r] = o;                                       // residual for LN2
            ldsu[(lrowc + r) * LDS_STRIDE + (ct0 + c) * 16 + col] = f2bf(o);
        }
    }
    __syncthreads();

    // ---- A-fragments of h' from LDS (full K) ----
    short8v af[4];
#pragma unroll
    for (int kb = 0; kb < 4; ++kb)
        af[kb] = *(const short8v*)&ldsu[lrowa * LDS_STRIDE + kb * 32 + quad * 8];

    // ---- GEMM2: h' @ Wf1 (OC=256; this wave: cts wv*8..wv*8+7) ----
    float4v acc2[8];
#pragma unroll
    for (int c = 0; c < 8; ++c) acc2[c] = (float4v){0.f, 0.f, 0.f, 0.f};
#pragma unroll
    for (int kb = 0; kb < 4; ++kb) {
#pragma unroll
        for (int c = 0; c < 8; ++c) {
            short8v b = *(const short8v*)(BF1 + (size_t)((wv * 8 + c) * 4 + kb) * 512 + lane * 8);
            acc2[c] = __builtin_amdgcn_mfma_f32_16x16x32_bf16(af[kb], b, acc2[c], 0, 0, 0);
        }
    }
    __syncthreads();

    // ---- T = relu(acc2 + bf1) -> LDS (this wave's 8 cts) ----
#pragma unroll
    for (int c = 0; c < 8; ++c) {
        float bi = bf1v[(wv * 8 + c) * 16 + col];
#pragma unroll
        for (int r = 0; r < 4; ++r) {
            float v = fmaxf(acc2[c][r] + bi, 0.f);
            ldsu[(lrowc + r) * LDS_STRIDE + (wv * 8 + c) * 16 + col] = f2bf(v);
        }
    }
    __syncthreads();

    // ---- GEMM3: T @ Wf2 (K=256; this wave: cts ct0..ct0+3) ----
    float4v acc3[4];
#pragma unroll
    for (int c = 0; c < 4; ++c) acc3[c] = (float4v){0.f, 0.f, 0.f, 0.f};
#pragma unroll
    for (int kb = 0; kb < 8; ++kb) {
        short8v a = *(const short8v*)&ldsu[lrowa * LDS_STRIDE + kb * 32 + quad * 8];
#pragma unroll
        for (int c = 0; c < 4; ++c) {
            short8v b = *(const short8v*)(BF2 + (size_t)((ct0 + c) * 8 + kb) * 512 + lane * 8);
            acc3[c] = __builtin_amdgcn_mfma_f32_16x16x32_bf16(a, b, acc3[c], 0, 0, 0);
        }
    }

    // ---- LN2 (+bias, +residual h'): partial stats + cross-wave exchange ----
    float s2[4] = {0.f, 0.f, 0.f, 0.f}, ss2[4] = {0.f, 0.f, 0.f, 0.f};
#pragma unroll
    for (int c = 0; c < 4; ++c) {
        float bi = bf2v[(ct0 + c) * 16 + col];
#pragma unroll
        for (int r = 0; r < 4; ++r) {
            float v = acc3[c][r] + bi + val[c][r];
            val[c][r] = v;
            s2[r] += v;
            ss2[r] += v * v;
        }
    }
#pragma unroll
    for (int mask = 1; mask < 16; mask <<= 1) {
#pragma unroll
        for (int r = 0; r < 4; ++r) {
            s2[r] += __shfl_xor(s2[r], mask, 64);
            ss2[r] += __shfl_xor(ss2[r], mask, 64);
        }
    }
    __syncthreads();   // GEMM3 reads of ldsu done; lnx free for reuse
    if (col == 0) {
#pragma unroll
        for (int r = 0; r < 4; ++r) {
            lnx[wv][lrowc + r][0] = s2[r];
            lnx[wv][lrowc + r][1] = ss2[r];
        }
    }
    __syncthreads();
#pragma unroll
    for (int r = 0; r < 4; ++r) {
        float fs = lnx[0][lrowc + r][0] + lnx[1][lrowc + r][0];
        float fss = lnx[0][lrowc + r][1] + lnx[1][lrowc + r][1];
        float mean = fs * (1.f / 128.f);
        float var = fss * (1.f / 128.f) - mean * mean;
        s2[r] = mean;
        ss2[r] = rsqrtf(var + LN_EPS);
    }
#pragma unroll
    for (int c = 0; c < 4; ++c) {
        float gg = g2v[(ct0 + c) * 16 + col], bb = be2v[(ct0 + c) * 16 + col];
#pragma unroll
        for (int r = 0; r < 4; ++r) {
            float o = (val[c][r] - s2[r]) * ss2[r] * gg + bb;
            ldsf[(lrowc + r) * LDS_FSTRIDE + (ct0 + c) * 16 + col] = o;
        }
    }
    __syncthreads();

    // ---- coalesced stores (128 threads): h as float4, hb as uint4 (8 bf16) ----
#pragma unroll
    for (int j = 0; j < 4; ++j) {
        int p = tid + j * 128;        // 0..511
        int row = p >> 5;
        int c4 = p & 31;
        float4 vv = *(const float4*)&ldsf[row * LDS_FSTRIDE + c4 * 4];
        *(float4*)&h[(size_t)(m0 + row) * 128 + c4 * 4] = vv;
    }
#pragma unroll
    for (int j = 0; j < 2; ++j) {
        int p = tid + j * 128;        // 0..255
        int row = p >> 4;
        int c8 = p & 15;
        float4 va = *(const float4*)&ldsf[row * LDS_FSTRIDE + c8 * 8];
        float4 vb = *(const float4*)&ldsf[row * LDS_FSTRIDE + c8 * 8 + 4];
        uint4 ou;
        ou.x = (unsigned)f2bf(va.x) | ((unsigned)f2bf(va.y) << 16);
        ou.y = (unsigned)f2bf(va.z) | ((unsigned)f2bf(va.w) << 16);
        ou.z = (unsigned)f2bf(vb.x) | ((unsigned)f2bf(vb.y) << 16);
        ou.w = (unsigned)f2bf(vb.z) | ((unsigned)f2bf(vb.w) << 16);
        *(uint4*)&hb[(size_t)(m0 + row) * 128 + c8 * 8] = ou;
    }
}

// ---------------- attention aggregation --------------------------------------------
// One WAVE per dst node. 4 edge-groups x 16 lanes; lane covers 8 dims (sub = lane&15).
// Q bf16 [N,128]; K/V fp8-e4m3 packed [N,256B] -> ONE uint4 gather per edge per lane.
// Main loop batched 4-DEEP: avg degree 16 -> nfull ~4, so one batch covers a typical
// node's entire main loop -> one exposed gather latency instead of two.
// Log2-domain lazy-max online softmax (u/c1 pre-scaled by isq*log2e).
__global__ __launch_bounds__(64) void agg_kernel(
    const ushort_t* __restrict__ Q, const unsigned char* __restrict__ KV,
    const int* __restrict__ rowstart, const unsigned int* __restrict__ edges,
    const float* __restrict__ u, const float* __restrict__ c1,
    ushort_t* __restrict__ hout) {
    const int lane = threadIdx.x & 63;
    const int v = blockIdx.x;
    const int sub = lane & 15;
    const int grp = lane >> 4;

    // Q dims 8sub..+7 (uint4 = 8 bf16)
    uint4 qu = *(const uint4*)(Q + (size_t)v * 128 + sub * 8);
    float q0 = lo16(qu.x), q1 = hi16(qu.x), q2 = lo16(qu.y), q3 = hi16(qu.y);
    float q4 = lo16(qu.z), q5 = hi16(qu.z), q6 = lo16(qu.w), q7 = hi16(qu.w);
    float4 uva = *(const float4*)(u + sub * 8);
    float4 uvb = *(const float4*)(u + sub * 8 + 4);
    float4 cva = *(const float4*)(c1 + sub * 8);
    float4 cvb = *(const float4*)(c1 + sub * 8 + 4);

    float m = -1.0e38f;
    float sA[8] = {0.f, 0.f, 0.f, 0.f, 0.f, 0.f, 0.f, 0.f};
    float o[8] = {0.f, 0.f, 0.f, 0.f, 0.f, 0.f, 0.f, 0.f};

    const int start = rowstart[v];
    const int deg = rowstart[v + 1] - start;
    const int nfull = deg >> 2;
    const unsigned int* ep = edges + start + grp;

// compute body consuming a pre-loaded edge word + KV vector
#define AGG_COMPUTE(PE, KVv, MASKED, VALID)                                      \
    {                                                                            \
        float ef_ = __uint_as_float((PE) & 0xFFFF0000u);                         \
        float2v k01 = __builtin_amdgcn_cvt_pk_f32_fp8((KVv).x, false);           \
        float2v k23 = __builtin_amdgcn_cvt_pk_f32_fp8((KVv).x, true);            \
        float2v k45 = __builtin_amdgcn_cvt_pk_f32_fp8((KVv).y, false);           \
        float2v k67 = __builtin_amdgcn_cvt_pk_f32_fp8((KVv).y, true);            \
        float p_ = k01[0] * q0;                                                  \
        p_ = fmaf(k01[1], q1, p_);                                               \
        p_ = fmaf(k23[0], q2, p_);                                               \
        p_ = fmaf(k23[1], q3, p_);                                               \
        p_ = fmaf(k45[0], q4, p_);                                               \
        p_ = fmaf(k45[1], q5, p_);                                               \
        p_ = fmaf(k67[0], q6, p_);                                               \
        p_ = fmaf(k67[1], q7, p_);                                               \
        p_ += __shfl_xor(p_, 1, 64);                                             \
        p_ += __shfl_xor(p_, 2, 64);                                             \
        float x0 = p_ * fmaf(ef_, uva.x, cva.x);                                 \
        float x1 = p_ * fmaf(ef_, uva.y, cva.y);                                 \
        float x2 = p_ * fmaf(ef_, uva.z, cva.z);                                 \
        float x3 = p_ * fmaf(ef_, uva.w, cva.w);                                 \
        float x4 = p_ * fmaf(ef_, uvb.x, cvb.x);                                 \
        float x5 = p_ * fmaf(ef_, uvb.y, cvb.y);                                 \
        float x6 = p_ * fmaf(ef_, uvb.z, cvb.z);                                 \
        float x7 = p_ * fmaf(ef_, uvb.w, cvb.w);                                 \
        if (MASKED) {                                                            \
            x0 = (VALID) ? x0 : -1.0e38f; x1 = (VALID) ? x1 : -1.0e38f;          \
            x2 = (VALID) ? x2 : -1.0e38f; x3 = (VALID) ? x3 : -1.0e38f;          \
            x4 = (VALID) ? x4 : -1.0e38f; x5 = (VALID) ? x5 : -1.0e38f;          \
            x6 = (VALID) ? x6 : -1.0e38f; x7 = (VALID) ? x7 : -1.0e38f;          \
        }                                                                        \
        float xm = fmaxf(fmaxf(fmaxf(x0, x1), fmaxf(x2, x3)),                    \
                         fmaxf(fmaxf(x4, x5), fmaxf(x6, x7)));                   \
        if (xm > m) {                                                            \
            float nm = xm + 6.0f;                                                \
            float sc = EXP2(m - nm);                                             \
            sA[0] *= sc; sA[1] *= sc; sA[2] *= sc; sA[3] *= sc;                  \
            sA[4] *= sc; sA[5] *= sc; sA[6] *= sc; sA[7] *= sc;                  \
            o[0] *= sc; o[1] *= sc; o[2] *= sc; o[3] *= sc;                      \
            o[4] *= sc; o[5] *= sc; o[6] *= sc; o[7] *= sc;                      \
            m = nm;                                                              \
        }                                                                        \
        float e0 = EXP2(x0 - m), e1 = EXP2(x1 - m);                              \
        float e2 = EXP2(x2 - m), e3 = EXP2(x3 - m);                              \
        float e4 = EXP2(x4 - m), e5 = EXP2(x5 - m);                              \
        float e6 = EXP2(x6 - m), e7 = EXP2(x7 - m);                              \
        sA[0] += e0; sA[1] += e1; sA[2] += e2; sA[3] += e3;                      \
        sA[4] += e4; sA[5] += e5; sA[6] += e6; sA[7] += e7;                      \
        float2v v01 = __builtin_amdgcn_cvt_pk_f32_fp8((KVv).z, false);           \
        float2v v23 = __builtin_amdgcn_cvt_pk_f32_fp8((KVv).z, true);            \
        float2v v45 = __builtin_amdgcn_cvt_pk_f32_fp8((KVv).w, false);           \
        float2v v67 = __builtin_amdgcn_cvt_pk_f32_fp8((KVv).w, true);            \
        o[0] = fmaf(v01[0], e0, o[0]);                                           \
        o[1] = fmaf(v01[1], e1, o[1]);                                           \
        o[2] = fmaf(v23[0], e2, o[2]);                                           \
        o[3] = fmaf(v23[1], e3, o[3]);                                           \
        o[4] = fmaf(v45[0], e4, o[4]);                                           \
        o[5] = fmaf(v45[1], e5, o[5]);                                           \
        o[6] = fmaf(v67[0], e6, o[6]);                                           \
        o[7] = fmaf(v67[1], e7, o[7]);                                           \
    }

    int it = 0;
    for (; it + 4 <= nfull; it += 4) {
        // batch: issue all 4 edge words + all 4 KV gathers before any compute
        unsigned int pe0 = ep[4 * it];
        unsigned int pe1 = ep[4 * it + 4];
        unsigned int pe2 = ep[4 * it + 8];
        unsigned int pe3 = ep[4 * it + 12];
        uint4 kv0 = *(const uint4*)(KV + (size_t)(pe0 & 0xFFFFu) * 256 + sub * 16);
        uint4 kv1 = *(const uint4*)(KV + (size_t)(pe1 & 0xFFFFu) * 256 + sub * 16);
        uint4 kv2 = *(const uint4*)(KV + (size_t)(pe2 & 0xFFFFu) * 256 + sub * 16);
        uint4 kv3 = *(const uint4*)(KV + (size_t)(pe3 & 0xFFFFu) * 256 + sub * 16);
        AGG_COMPUTE(pe0, kv0, false, true)
        AGG_COMPUTE(pe1, kv1, false, true)
        AGG_COMPUTE(pe2, kv2, false, true)
        AGG_COMPUTE(pe3, kv3, false, true)
    }
    if (it + 2 <= nfull) {
        unsigned int pe0 = ep[4 * it];
        unsigned int pe1 = ep[4 * it + 4];
        uint4 kv0 = *(const uint4*)(KV + (size_t)(pe0 & 0xFFFFu) * 256 + sub * 16);
        uint4 kv1 = *(const uint4*)(KV + (size_t)(pe1 & 0xFFFFu) * 256 + sub * 16);
        AGG_COMPUTE(pe0, kv0, false, true)
        AGG_COMPUTE(pe1, kv1, false, true)
        it += 2;
    }
    if (it < nfull) {
        unsigned int pe0 = ep[4 * it];
        uint4 kv0 = *(const uint4*)(KV + (size_t)(pe0 & 0xFFFFu) * 256 + sub * 16);
        AGG_COMPUTE(pe0, kv0, false, true)
    }
    const int rem = deg & 3;
    if (rem) {
        bool valid = grp < rem;
        unsigned int pe = valid ? ep[4 * nfull] : edges[start];
        uint4 kv = *(const uint4*)(KV + (size_t)(pe & 0xFFFFu) * 256 + sub * 16);
        AGG_COMPUTE(pe, kv, true, valid)
    }
#undef AGG_COMPUTE

    // merge the 4 edge-groups (partners lane^16, lane^32 hold the same dims)
#pragma unroll
    for (int mask = 16; mask <= 32; mask <<= 1) {
        float mo = __shfl_xor(m, mask, 64);
        float mm = fmaxf(m, mo);
        float sca = EXP2(m - mm);
        float scb = EXP2(mo - mm);
#pragma unroll
        for (int j = 0; j < 8; ++j) {
            float t = __shfl_xor(sA[j], mask, 64);
            sA[j] = sA[j] * sca + t * scb;
            t = __shfl_xor(o[j], mask, 64);
            o[j] = o[j] * sca + t * scb;
        }
        m = mm;
    }

    if (grp == 0) {
        // ref: h_out = num / max(Z, 1e-6); ours scaled by 2^m; 1e-37 NaN guard
        float zc = 1e-6f * EXP2(-m);
        uint4 ou;
        unsigned int w0, w1;
        float z;
        z = fmaxf(fmaxf(sA[0], zc), 1e-37f); w0 = f2bf(o[0] / z);
        z = fmaxf(fmaxf(sA[1], zc), 1e-37f); w1 = f2bf(o[1] / z);
        ou.x = w0 | (w1 << 16);
        z = fmaxf(fmaxf(sA[2], zc), 1e-37f); w0 = f2bf(o[2] / z);
        z = fmaxf(fmaxf(sA[3], zc), 1e-37f); w1 = f2bf(o[3] / z);
        ou.y = w0 | (w1 << 16);
        z = fmaxf(fmaxf(sA[4], zc), 1e-37f); w0 = f2bf(o[4] / z);
        z = fmaxf(fmaxf(sA[5], zc), 1e-37f); w1 = f2bf(o[5] / z);
        ou.z = w0 | (w1 << 16);
        z = fmaxf(fmaxf(sA[6], zc), 1e-37f); w0 = f2bf(o[6] / z);
        z = fmaxf(fmaxf(sA[7], zc), 1e-37f); w1 = f2bf(o[7] / z);
        ou.w = w0 | (w1 << 16);
        *(uint4*)(hout + (size_t)v * 128 + sub * 8) = ou;
    }
}

// ---------------- mean over nodes ------------------------------------------------------
__global__ void mean_part_kernel(const float* __restrict__ h, float* __restrict__ macc) {
    __shared__ float s[256];
    int t = threadIdx.x;
    int col = t & 127;
    int half = t >> 7;
    int r0 = blockIdx.x * 256;
    float acc = 0.f;
    for (int r = half; r < 256; r += 2) acc += h[(size_t)(r0 + r) * 128 + col];
    s[t] = acc;
    __syncthreads();
    if (t < 128) atomicAdd(&macc[t], s[t] + s[t + 128]);
}

// ---------------- finalize -------------------------------------------------------------
__global__ void finalize_kernel(const float* __restrict__ macc, void* __restrict__ out,
                                const int* __restrict__ flag) {
    int t = threadIdx.x;
    float v = macc[t] * (1.f / (float)N_NODES);
    if (*flag)
        ((ushort_t*)out)[t] = f2bf(v);
    else
        ((float*)out)[t] = v;
}

// ---------------------------------------------------------------------------------------
extern "C" void kernel_launch(void* const* d_in, const int* in_sizes, int n_in,
                              void* d_out, int out_size, void* d_ws, size_t ws_size,
                              hipStream_t stream) {
    const int* src = (const int*)d_in[3];
    const int* dst = (const int*)d_in[4];

    char* w = (char*)d_ws;
    const size_t MB = 1u << 20;
    float* h        = (float*)(w);               // 16 MB [N,128] f32
    ushort_t* hb    = (ushort_t*)(w + 16 * MB);  //  8 MB [N,128] bf16 (also = HOUT)
    ushort_t* Qh    = (ushort_t*)(w + 24 * MB);  //  8 MB [N,128] bf16
    unsigned char* KVf8 = (unsigned char*)(w + 32 * MB);  // 8 MB [N,256B] fp8 K|V packed
    char* aux       = w + 48 * MB;
    int* deg        = (int*)(aux);               // 128 KB
    int* rowstart   = (int*)(aux + 0x40000);     // 128 KB + 4
    int* cursor     = (int*)(aux + 0x80000);     // 128 KB
    unsigned int* edges = (unsigned int*)(aux + 0xC0000);          // 2 MB
    float* ubuf     = (float*)(aux + 0xC0000 + 2 * MB);            // 3*128 f32
    float* cbuf     = ubuf + 3 * 128;
    float* macc     = cbuf + 3 * 128;            // 128 f32
    int* flag       = (int*)(macc + 128);
    float* conv     = (float*)(aux + 0xC0000 + 2 * MB + 4096);     // 40 KB f32
    ushort_t* swz   = (ushort_t*)((char*)conv + CONV_TOTAL * 4);   // 784 KB bf16

    detect_kernel<<<1, 256, 0, stream>>>((const unsigned int*)d_in[5], flag);

    ConvArgs ca;
    ca.src[0] = d_in[5];    // W_node
    ca.src[1] = d_in[6];    // b_node
    ca.src[2] = d_in[7];    // W_pos
    ca.src[3] = d_in[8];    // b_pos
    ca.src[4] = d_in[9];    // W_edge
    ca.src[5] = d_in[10];   // b_edge
    ca.src[6] = d_in[16];   // b_lin
    ca.src[7] = d_in[17];   // g1
    ca.src[8] = d_in[18];   // be1
    ca.src[9] = d_in[20];   // bf1
    ca.src[10] = d_in[22];  // bf2
    ca.src[11] = d_in[23];  // g2
    ca.src[12] = d_in[24];  // be2
    // convert also zeros deg (replaces hipMemsetAsync node)
    convert_kernel<<<(CONV_TOTAL + 255) / 256, 256, 0, stream>>>(ca, flag, conv, deg);

    // swz (192 blocks) + fused uc (3 blocks) + input-proj records (4 blocks)
    swz_kernel<<<192 + 3 + 4, 256, 0, stream>>>(
        d_in[11], d_in[12], d_in[13], d_in[15], d_in[19], d_in[21],
        d_in[14], d_in[9], d_in[10], d_in[5], d_in[7], flag, swz, ubuf, cbuf);

    // input projection via MFMA + fused degree histogram
    ip_gemm<<<N_NODES / 64, 256, 0, stream>>>(d_in[0], d_in[1], conv, flag, dst, deg,
                                              swz + (size_t)REC_WNP * 512, h, hb);
    // scan also zeros macc (replaces hipMemsetAsync node)
    scan_kernel<<<1, 1024, 0, stream>>>(deg, rowstart, cursor, macc);
    scatter_kernel<<<N_EDGES / 256, 256, 0, stream>>>(src, dst, d_in[2], flag, cursor,
                                                      edges);

    for (int i = 0; i < 3; ++i) {
        const ushort_t* swzQKV = swz + (size_t)REC_QKV(i) * 512;
        const ushort_t* swzWL  = swz + (size_t)REC_WLIN(i) * 512;
        const ushort_t* swzF1  = swz + (size_t)REC_WF1(i) * 512;
        const ushort_t* swzF2  = swz + (size_t)REC_WF2(i) * 512;

        // Q bf16 + K/V fp8 packed (3-segment, 4-wave blocks)
        qkv_gemm<4><<<dim3(N_NODES / 64, 3), 256, 0, stream>>>(hb, swzQKV, Qh, KVf8);

        // attention -> hb (= HOUT) [N,128] bf16 (4-deep batched gather main loop)
        agg_kernel<<<N_NODES, 64, 0, stream>>>(Qh, KVf8, rowstart, edges,
                                               ubuf + i * 128, cbuf + i * 128, hb);

        // fused layer tail, TWO waves per 16-row tile (grid 2048 x 128 thr)
        ffn_kernel<<<N_NODES / 16, 128, 0, stream>>>(
            hb, swzWL, swzF1, swzF2,
            conv + OFF_BLIN + i * 128, conv + OFF_G1 + i * 128, conv + OFF_BE1 + i * 128,
            conv + OFF_BF1 + i * 256,
            conv + OFF_BF2 + i * 128, conv + OFF_G2 + i * 128, conv + OFF_BE2 + i * 128,
            h, hb);
    }

    mean_part_kernel<<<N_NODES / 256, 256, 0, stream>>>(h, macc);
    finalize_kernel<<<1, 128, 0, stream>>>(macc, d_out, flag);
}

// Round 10
// 439.055 us; speedup vs baseline: 1.2852x; 1.0123x over previous
//
#include <hip/hip_runtime.h>
#include <hip/hip_bf16.h>

#define N_NODES 32768
#define N_EDGES 524288
#define LN_EPS 1e-5f

typedef unsigned short ushort_t;
typedef __attribute__((ext_vector_type(8))) short short8v;
typedef __attribute__((ext_vector_type(4))) float float4v;
typedef __attribute__((ext_vector_type(2))) float float2v;

__device__ __forceinline__ float bf2f(ushort_t u) {
    return __uint_as_float(((unsigned int)u) << 16);
}
__device__ __forceinline__ ushort_t f2bf(float f) {
    unsigned int u = __float_as_uint(f);
    unsigned int r = (u + 0x7FFFu + ((u >> 16) & 1u)) >> 16;
    return (ushort_t)r;
}
__device__ __forceinline__ float lo16(unsigned int x) { return __uint_as_float(x << 16); }
__device__ __forceinline__ float hi16(unsigned int x) { return __uint_as_float(x & 0xFFFF0000u); }

#if __has_builtin(__builtin_amdgcn_exp2f)
#define EXP2(x) __builtin_amdgcn_exp2f(x)
#else
#define EXP2(x) exp2f(x)
#endif

// compact f32 conv region: only params consumed as f32 (biases, LN, input-proj weights)
#define OFF_WNODE 0
#define OFF_BNODE 5632
#define OFF_WPOS  5760
#define OFF_BPOS  6784
#define OFF_WEDGE 6912
#define OFF_BEDGE 7040
#define OFF_BLIN  7168
#define OFF_G1    7552
#define OFF_BE1   7936
#define OFF_BF1   8320
#define OFF_BF2   9088
#define OFF_G2    9472
#define OFF_BE2   9856
#define CONV_TOTAL 10240

// swizzled-B record bases (records of 512 ushorts = 64 lanes x 8 bf16)
#define REC_QKV(i)  ((i) * 96)          // 24 ct x 4 kb
#define REC_WLIN(i) (288 + (i) * 32)    // 8 ct x 4 kb
#define REC_WF1(i)  (384 + (i) * 64)    // 16 ct x 4 kb
#define REC_WF2(i)  (576 + (i) * 64)    // 8 ct x 8 kb
#define REC_WNP     768                 // input-proj [Wn;Wp;0] 8 ct x 2 kb
#define REC_TOTAL   784

#define LDS_STRIDE 264   // ushorts per LDS row (256 + 8 pad)
#define LDS_FSTRIDE 132  // floats per LDS row (same byte footprint)

// ---------------- dtype detection: bf16 data has exponent-like bits at [15:8] ---------
__global__ void detect_kernel(const unsigned int* __restrict__ wn, int* __restrict__ flag) {
    __shared__ int s[256];
    int t = threadIdx.x;
    int cnt = 0;
    for (int i = t; i < 2816; i += 256) {
        unsigned int b = (wn[i] >> 8) & 0x7F;
        cnt += (b >= 0x3A && b <= 0x40) ? 1 : 0;
    }
    s[t] = cnt;
    __syncthreads();
    for (int off = 128; off > 0; off >>= 1) {
        if (t < off) s[t] += s[t + off];
        __syncthreads();
    }
    if (t == 0) *flag = (s[0] > 1408) ? 1 : 0;   // 1 = bf16, 0 = f32
}

// ---------------- canonicalize small param buffers to f32 scratch ---------------------
// Also zeros the degree histogram (replaces a hipMemsetAsync dispatch node).
struct ConvArgs { const void* src[13]; };

__global__ void convert_kernel(ConvArgs a, const int* __restrict__ flag,
                               float* __restrict__ dst, int* __restrict__ deg) {
    int gid = blockIdx.x * 256 + threadIdx.x;
    for (int i = gid; i < N_NODES; i += CONV_TOTAL) deg[i] = 0;   // fused deg-zero
    if (gid >= CONV_TOTAL) return;
    const int off[14] = {OFF_WNODE, OFF_BNODE, OFF_WPOS, OFF_BPOS, OFF_WEDGE, OFF_BEDGE,
                         OFF_BLIN, OFF_G1, OFF_BE1, OFF_BF1, OFF_BF2, OFF_G2, OFF_BE2,
                         CONV_TOTAL};
    int s = 0;
#pragma unroll
    for (int i = 1; i < 13; ++i) s += (gid >= off[i]) ? 1 : 0;
    int local = gid - off[s];
    if (*flag)
        dst[gid] = bf2f(((const ushort_t*)a.src[s])[local]);
    else
        dst[gid] = ((const float*)a.src[s])[local];
}

// ---------------- swizzle GEMM weights into MFMA B-fragment records (raw sources) -----
// record(ct,kb): lane l holds W[kb*32 + (l>>4)*8 + j][ct*16 + (l&15)], j=0..7
// blocks 192..194 compute u/c1 (fused uc); blocks 195..198 build input-proj records.
__global__ void swz_kernel(const void* __restrict__ Wq, const void* __restrict__ Wk,
                           const void* __restrict__ Wv, const void* __restrict__ Wlin,
                           const void* __restrict__ Wf1, const void* __restrict__ Wf2,
                           const void* __restrict__ We, const void* __restrict__ wedge,
                           const void* __restrict__ bedge,
                           const void* __restrict__ Wn_, const void* __restrict__ Wp_,
                           const int* __restrict__ flag,
                           ushort_t* __restrict__ swz,
                           float* __restrict__ u, float* __restrict__ c1) {
    const bool isbf = (*flag != 0);
    if (blockIdx.x >= 195) {
        // input-proj B records: W[k][n], k = 0..43 Wn, 44..51 Wp, 52..63 zero pad
        int idx = (blockIdx.x - 195) * 256 + threadIdx.x;   // 0..1023
        int rec16 = idx >> 6;                               // 0..15
        int lane = idx & 63;
        int ct = rec16 >> 1, kb = rec16 & 1;
        int col = lane & 15, quad = lane >> 4;
        int n = ct * 16 + col;
        ushort_t v[8];
#pragma unroll
        for (int j = 0; j < 8; ++j) {
            int k = kb * 32 + quad * 8 + j;
            if (isbf) {
                v[j] = (k < 44) ? ((const ushort_t*)Wn_)[k * 128 + n]
                     : ((k < 52) ? ((const ushort_t*)Wp_)[(k - 44) * 128 + n]
                                 : (ushort_t)0);
            } else {
                float f = (k < 44) ? ((const float*)Wn_)[k * 128 + n]
                        : ((k < 52) ? ((const float*)Wp_)[(k - 44) * 128 + n] : 0.f);
                v[j] = f2bf(f);
            }
        }
        ushort_t* o = swz + (size_t)(REC_WNP + rec16) * 512 + lane * 8;
#pragma unroll
        for (int j = 0; j < 8; ++j) o[j] = v[j];
        return;
    }
    if (blockIdx.x >= 192) {
        // fused uc: pre-scaled by (1/sqrt(dk))*log2(e); agg works in log2 domain
        int l = blockIdx.x - 192;
        int d = threadIdx.x;
        if (d >= 128) return;
        float uu = 0.f, cc = 0.f;
        if (isbf) {
            const ushort_t* Wl = (const ushort_t*)We + (size_t)l * 16384;
            const ushort_t* we_ = (const ushort_t*)wedge;
            const ushort_t* be_ = (const ushort_t*)bedge;
#pragma unroll 4
            for (int k = 0; k < 128; ++k) {
                float w = bf2f(Wl[k * 128 + d]);
                uu = fmaf(bf2f(we_[k]), w, uu);
                cc = fmaf(bf2f(be_[k]), w, cc);
            }
        } else {
            const float* Wl = (const float*)We + (size_t)l * 16384;
            const float* we_ = (const float*)wedge;
            const float* be_ = (const float*)bedge;
#pragma unroll 4
            for (int k = 0; k < 128; ++k) {
                float w = Wl[k * 128 + d];
                uu = fmaf(we_[k], w, uu);
                cc = fmaf(be_[k], w, cc);
            }
        }
        const float scale = 0.17677669529663687f * 1.4426950408889634f;  // isq * log2(e)
        u[l * 128 + d] = uu * scale;
        c1[l * 128 + d] = (1.f + cc) * scale;
        return;
    }
    int gid = blockIdx.x * 256 + threadIdx.x;
    int lane = gid & 63;
    int rec = gid >> 6;
    int col = lane & 15, quad = lane >> 4;
    const void* src;
    size_t base;
    int ct, kb, OC;
    if (rec < 288) {                       // QKV: 3 layers x 24ct x 4kb
        int layer = rec / 96, r2 = rec % 96;
        ct = r2 >> 2; kb = r2 & 3;
        int seg = ct >> 3;                 // 0=Wq 1=Wk 2=Wv
        src = (seg == 0) ? Wq : ((seg == 1) ? Wk : Wv);
        base = (size_t)layer * 16384; OC = 128; ct &= 7;
    } else if (rec < 384) {                // W_lin
        int r = rec - 288, layer = r / 32, r2 = r % 32;
        ct = r2 >> 2; kb = r2 & 3;
        src = Wlin; base = (size_t)layer * 16384; OC = 128;
    } else if (rec < 576) {                // Wf1 (OC=256)
        int r = rec - 384, layer = r / 64, r2 = r % 64;
        ct = r2 >> 2; kb = r2 & 3;
        src = Wf1; base = (size_t)layer * 32768; OC = 256;
    } else {                               // Wf2 (K=256)
        int r = rec - 576, layer = r / 64, r2 = r % 64;
        ct = r2 >> 3; kb = r2 & 7;
        src = Wf2; base = (size_t)layer * 32768; OC = 128;
    }
    int n = ct * 16 + col;
    ushort_t v[8];
    if (isbf) {
        const ushort_t* s16 = (const ushort_t*)src + base;
#pragma unroll
        for (int j = 0; j < 8; ++j) v[j] = s16[(size_t)(kb * 32 + quad * 8 + j) * OC + n];
    } else {
        const float* s32 = (const float*)src + base;
#pragma unroll
        for (int j = 0; j < 8; ++j) v[j] = f2bf(s32[(size_t)(kb * 32 + quad * 8 + j) * OC + n]);
    }
    ushort_t* o = swz + (size_t)rec * 512 + lane * 8;
#pragma unroll
    for (int j = 0; j < 8; ++j) o[j] = v[j];
}

// ---------------- input projection via MFMA: h = [feats|lap|0] @ [Wn;Wp;0] + biases ---
// Grid N/64 blocks x 256 thr (4 waves); A tile staged bf16 in LDS; B from swz records.
// Fused degree histogram (4 strided passes). Outputs h f32 + hb bf16.
__global__ __launch_bounds__(256) void ip_gemm(
    const void* __restrict__ feats, const void* __restrict__ lap,
    const float* __restrict__ conv, const int* __restrict__ flag,
    const int* __restrict__ dstidx, int* __restrict__ deg,
    const ushort_t* __restrict__ Bswz,   // = swz + REC_WNP*512
    float* __restrict__ h, ushort_t* __restrict__ hb) {
    __shared__ __align__(16) ushort_t As[64 * 72];   // 64 rows x K=64, stride 72
    const int tid = threadIdx.x;

    // fused histogram: 512*256 threads x 4 edges
    for (int e = blockIdx.x * 256 + tid; e < N_EDGES; e += (N_NODES / 64) * 256)
        atomicAdd(&deg[dstidx[e]], 1);

    const bool isbf = (*flag != 0);
    const int r = tid >> 2;          // 0..63 (tile row)
    const int t4 = tid & 3;          // 16-col chunk
    const int m0g = blockIdx.x * 64;
    {
        const int row = m0g + r;
        ushort_t tmp[16];
        if (isbf) {
            const ushort_t* frow = (const ushort_t*)feats + (size_t)row * 44;
            const ushort_t* prow = (const ushort_t*)lap + (size_t)row * 8;
#pragma unroll
            for (int j = 0; j < 16; ++j) {
                int k = t4 * 16 + j;
                tmp[j] = (k < 44) ? frow[k]
                       : ((k < 52) ? prow[k - 44] : (ushort_t)0);
            }
        } else {
            const float* frow = (const float*)feats + (size_t)row * 44;
            const float* prow = (const float*)lap + (size_t)row * 8;
#pragma unroll
            for (int j = 0; j < 16; ++j) {
                int k = t4 * 16 + j;
                float v = (k < 44) ? frow[k] : ((k < 52) ? prow[k - 44] : 0.f);
                tmp[j] = f2bf(v);
            }
        }
#pragma unroll
        for (int j = 0; j < 16; ++j) As[r * 72 + t4 * 16 + j] = tmp[j];
    }
    __syncthreads();

    const int wv = tid >> 6, lane = tid & 63;
    const int col = lane & 15, quad = lane >> 4;
    const int m0 = wv * 16;
    short8v a0 = *(const short8v*)&As[(m0 + col) * 72 + quad * 8];
    short8v a1 = *(const short8v*)&As[(m0 + col) * 72 + 32 + quad * 8];

    float4v acc[8];
#pragma unroll
    for (int ct = 0; ct < 8; ++ct) {
        short8v b0 = *(const short8v*)(Bswz + (size_t)(ct * 2 + 0) * 512 + lane * 8);
        short8v b1 = *(const short8v*)(Bswz + (size_t)(ct * 2 + 1) * 512 + lane * 8);
        float4v a = (float4v){0.f, 0.f, 0.f, 0.f};
        a = __builtin_amdgcn_mfma_f32_16x16x32_bf16(a0, b0, a, 0, 0, 0);
        a = __builtin_amdgcn_mfma_f32_16x16x32_bf16(a1, b1, a, 0, 0, 0);
        acc[ct] = a;
    }

    const int rowb = m0g + m0 + quad * 4;
#pragma unroll
    for (int ct = 0; ct < 8; ++ct) {
        int j = ct * 16 + col;
        float bias = conv[OFF_BNODE + j] + conv[OFF_BPOS + j];
#pragma unroll
        for (int rr = 0; rr < 4; ++rr) {
            float o = acc[ct][rr] + bias;
            h[(size_t)(rowb + rr) * 128 + j] = o;
            hb[(size_t)(rowb + rr) * 128 + j] = f2bf(o);
        }
    }
}

// ---------------- CSR build ------------------------------------------------------------
// Also zeros macc (replaces a hipMemsetAsync dispatch node; mean_part runs much later).
__global__ void scan_kernel(const int* __restrict__ deg, int* __restrict__ rowstart,
                            int* __restrict__ cursor, float* __restrict__ macc) {
    __shared__ int lds[1024];
    int t = threadIdx.x;
    if (t < 128) macc[t] = 0.f;                 // fused macc-zero
    int base = t * 32;
    int v[32];
    int csum = 0;
#pragma unroll
    for (int j = 0; j < 8; ++j) {               // coalesced int4 loads
        int4 x = *(const int4*)(deg + base + j * 4);
        v[j * 4 + 0] = x.x; v[j * 4 + 1] = x.y;
        v[j * 4 + 2] = x.z; v[j * 4 + 3] = x.w;
        csum += x.x + x.y + x.z + x.w;
    }
    lds[t] = csum;
    __syncthreads();
    for (int off = 1; off < 1024; off <<= 1) {
        int x = (t >= off) ? lds[t - off] : 0;
        __syncthreads();
        lds[t] += x;
        __syncthreads();
    }
    int excl = lds[t] - csum;
    int running = excl;
#pragma unroll
    for (int j = 0; j < 8; ++j) {
        int4 w;
        w.x = running; running += v[j * 4 + 0];
        w.y = running; running += v[j * 4 + 1];
        w.z = running; running += v[j * 4 + 2];
        w.w = running; running += v[j * 4 + 3];
        *(int4*)(rowstart + base + j * 4) = w;
        *(int4*)(cursor + base + j * 4) = w;
    }
    if (t == 1023) rowstart[N_NODES] = running;
}

__global__ void scatter_kernel(const int* __restrict__ src, const int* __restrict__ dst,
                               const void* __restrict__ ef, const int* __restrict__ flag,
                               int* __restrict__ cursor,
                               unsigned int* __restrict__ edges) {
    int e = blockIdx.x * 256 + threadIdx.x;
    if (e < N_EDGES) {
        ushort_t efb = (*flag != 0) ? ((const ushort_t*)ef)[e]
                                    : f2bf(((const float*)ef)[e]);
        int d = dst[e];
        int p = atomicAdd(&cursor[d], 1);
        edges[p] = (unsigned int)src[e] | ((unsigned int)efb << 16);
    }
}

// ---------------- MFMA GEMM (QKV): seg 0 -> Q bf16 [N,128];
//                  segs 1/2 -> K/V packed fp8-e4m3 into KV [N,256B]
//                  (per 8-dim block b: bytes 16b..16b+7 = K dims, +8..+15 = V dims).
// Block: 256 thr = 4 waves; wave = 16 rows x 128 cols; grid = (M/64, 3 segs).
template <int KB>
__global__ __launch_bounds__(256) void qkv_gemm(
    const ushort_t* __restrict__ A,
    const ushort_t* __restrict__ Bswz,
    ushort_t* __restrict__ outQ,
    unsigned char* __restrict__ outKV) {
    const int K = KB * 32;
    const int tid = threadIdx.x;
    const int wv = tid >> 6, lane = tid & 63;
    const int col = lane & 15, quad = lane >> 4;
    const int m0 = blockIdx.x * 64 + wv * 16;
    const int ct0 = blockIdx.y * 8;

    float4v acc[8];
#pragma unroll
    for (int ct = 0; ct < 8; ++ct) acc[ct] = (float4v){0.f, 0.f, 0.f, 0.f};

    const ushort_t* Ap = A + (size_t)(m0 + col) * K + quad * 8;
    const ushort_t* Bp = Bswz + (size_t)ct0 * KB * 512 + lane * 8;

#pragma unroll
    for (int kb = 0; kb < KB; ++kb) {
        short8v a = *(const short8v*)(Ap + kb * 32);
#pragma unroll
        for (int ct = 0; ct < 8; ++ct) {
            short8v b = *(const short8v*)(Bp + (size_t)(ct * KB + kb) * 512);
            acc[ct] = __builtin_amdgcn_mfma_f32_16x16x32_bf16(a, b, acc[ct], 0, 0, 0);
        }
    }

    const int rowb = m0 + quad * 4;
    const int seg = blockIdx.y;
    if (seg == 0) {
#pragma unroll
        for (int ct = 0; ct < 8; ++ct) {
            int j = ct * 16 + col;
#pragma unroll
            for (int r = 0; r < 4; ++r)
                outQ[(size_t)(rowb + r) * 128 + j] = f2bf(acc[ct][r]);
        }
    } else {
        const int vofs = (seg == 2) ? 8 : 0;
#pragma unroll
        for (int ct = 0; ct < 8; ++ct) {
            int j = ct * 16 + col;
            int off = ((j >> 3) * 16) + (j & 7) + vofs;
#pragma unroll
            for (int r = 0; r < 4; ++r) {
                float a = acc[ct][r];
                float b = __shfl_xor(a, 1, 64);   // partner col (j^1) same ct,r
                if ((col & 1) == 0) {
                    unsigned short pk = (unsigned short)
                        __builtin_amdgcn_cvt_pk_fp8_f32(a, b, 0, false);
                    *(ushort_t*)(outKV + (size_t)(rowb + r) * 256 + off) = pk;
                }
            }
        }
    }
}

// ---------------- fused layer tail: h = LN2(h' + relu(h'@Wf1+b)@Wf2+b2),
//                  h' = LN1(h + HOUT@WL+bl). FOUR waves per 16-row tile (grid N/16,
//                  256 thr): wave wv owns a quarter of the output columns of each
//                  GEMM; LN row-stats completed via a 4-way LDS exchange. Same total
//                  work as the 1-wave version, 4x resident waves (grid-limited).
__global__ __launch_bounds__(256, 2) void ffn_kernel(
    const ushort_t* __restrict__ HOUT,   // [N,128] bf16 (= hb, attention out)
    const ushort_t* __restrict__ BWL,    // swz W_lin  (8ct x 4kb)
    const ushort_t* __restrict__ BF1,    // swz Wf1    (16ct x 4kb)
    const ushort_t* __restrict__ BF2,    // swz Wf2    (8ct x 8kb)
    const float* __restrict__ bl,
    const float* __restrict__ g1v, const float* __restrict__ be1v,
    const float* __restrict__ bf1v,
    const float* __restrict__ bf2v,
    const float* __restrict__ g2v, const float* __restrict__ be2v,
    float* __restrict__ h,               // [N,128] f32 in-out (residual -> final)
    ushort_t* __restrict__ hb) {         // [N,128] bf16 out
    __shared__ __align__(16) char ldsraw[16 * 528];   // 8448 B, dual-view
    __shared__ float lnx[4][16][2];      // cross-wave LN partials [wave][row][sum,sumsq]
    ushort_t* ldsu = (ushort_t*)ldsraw;  // stride LDS_STRIDE (264)
    float* ldsf = (float*)ldsraw;        // stride LDS_FSTRIDE (132)
    const int tid = threadIdx.x;
    const int wv = tid >> 6;             // 0..3 (column-quarter owner)
    const int lane = tid & 63;
    const int col = lane & 15, quad = lane >> 4;
    const int m0 = blockIdx.x * 16;
    const int rowb = m0 + quad * 4;          // global row base (C-layout)
    const int lrowc = quad * 4;              // LDS row base for C-layout stores
    const int lrowa = col;                   // LDS row for A-fragment reads
    const int ct0 = wv * 2;                  // GEMM1/GEMM3 ct base (2 of 8)

    // ---- GEMM1: HOUT @ W_lin (this wave: cts ct0..ct0+1) ----
    float4v acc[2];
#pragma unroll
    for (int c = 0; c < 2; ++c) acc[c] = (float4v){0.f, 0.f, 0.f, 0.f};
    const ushort_t* Ap = HOUT + (size_t)(m0 + col) * 128 + quad * 8;
#pragma unroll
    for (int kb = 0; kb < 4; ++kb) {
        short8v a = *(const short8v*)(Ap + kb * 32);
#pragma unroll
        for (int c = 0; c < 2; ++c) {
            short8v b = *(const short8v*)(BWL + (size_t)((ct0 + c) * 4 + kb) * 512 + lane * 8);
            acc[c] = __builtin_amdgcn_mfma_f32_16x16x32_bf16(a, b, acc[c], 0, 0, 0);
        }
    }

    // ---- LN1 (+bias, +residual h): wave-partial stats then 4-way LDS exchange ----
    float val[2][4], s[4] = {0.f, 0.f, 0.f, 0.f}, ss[4] = {0.f, 0.f, 0.f, 0.f};
#pragma unroll
    for (int c = 0; c < 2; ++c) {
        float bi = bl[(ct0 + c) * 16 + col];
#pragma unroll
        for (int r = 0; r < 4; ++r) {
            float v = acc[c][r] + bi + h[(size_t)(rowb + r) * 128 + (ct0 + c) * 16 + col];
            val[c][r] = v;
            s[r] += v;
            ss[r] += v * v;
        }
    }
#pragma unroll
    for (int mask = 1; mask < 16; mask <<= 1) {
#pragma unroll
        for (int r = 0; r < 4; ++r) {
            s[r] += __shfl_xor(s[r], mask, 64);
            ss[r] += __shfl_xor(ss[r], mask, 64);
        }
    }
    if (col == 0) {
#pragma unroll
        for (int r = 0; r < 4; ++r) {
            lnx[wv][lrowc + r][0] = s[r];
            lnx[wv][lrowc + r][1] = ss[r];
        }
    }
    __syncthreads();
#pragma unroll
    for (int r = 0; r < 4; ++r) {
        float fs = (lnx[0][lrowc + r][0] + lnx[1][lrowc + r][0]) +
                   (lnx[2][lrowc + r][0] + lnx[3][lrowc + r][0]);
        float fss = (lnx[0][lrowc + r][1] + lnx[1][lrowc + r][1]) +
                    (lnx[2][lrowc + r][1] + lnx[3][lrowc + r][1]);
        float mean = fs * (1.f / 128.f);
        float var = fss * (1.f / 128.f) - mean * mean;
        s[r] = mean;
        ss[r] = rsqrtf(var + LN_EPS);
    }
#pragma unroll
    for (int c = 0; c < 2; ++c) {
        float gg = g1v[(ct0 + c) * 16 + col], bb = be1v[(ct0 + c) * 16 + col];
#pragma unroll
        for (int r = 0; r < 4; ++r) {
            float o = (val[c][r] - s[r]) * ss[r] * gg + bb;
            val[c][r] = o;                                       // residual for LN2
            ldsu[(lrowc + r) * LDS_STRIDE + (ct0 + c) * 16 + col] = f2bf(o);
        }
    }
    __syncthreads();

    // ---- A-fragments of h' from LDS (full K) ----
    short8v af[4];
#pragma unroll
    for (int kb = 0; kb < 4; ++kb)
        af[kb] = *(const short8v*)&ldsu[lrowa * LDS_STRIDE + kb * 32 + quad * 8];

    // ---- GEMM2: h' @ Wf1 (OC=256; this wave: cts wv*4..wv*4+3) ----
    float4v acc2[4];
#pragma unroll
    for (int c = 0; c < 4; ++c) acc2[c] = (float4v){0.f, 0.f, 0.f, 0.f};
#pragma unroll
    for (int kb = 0; kb < 4; ++kb) {
#pragma unroll
        for (int c = 0; c < 4; ++c) {
            short8v b = *(const short8v*)(BF1 + (size_t)((wv * 4 + c) * 4 + kb) * 512 + lane * 8);
            acc2[c] = __builtin_amdgcn_mfma_f32_16x16x32_bf16(af[kb], b, acc2[c], 0, 0, 0);
        }
    }
    __syncthreads();

    // ---- T = relu(acc2 + bf1) -> LDS (this wave's 4 cts) ----
#pragma unroll
    for (int c = 0; c < 4; ++c) {
        float bi = bf1v[(wv * 4 + c) * 16 + col];
#pragma unroll
        for (int r = 0; r < 4; ++r) {
            float v = fmaxf(acc2[c][r] + bi, 0.f);
            ldsu[(lrowc + r) * LDS_STRIDE + (wv * 4 + c) * 16 + col] = f2bf(v);
        }
    }
    __syncthreads();

    // ---- GEMM3: T @ Wf2 (K=256; this wave: cts ct0..ct0+1) ----
    float4v acc3[2];
#pragma unroll
    for (int c = 0; c < 2; ++c) acc3[c] = (float4v){0.f, 0.f, 0.f, 0.f};
#pragma unroll
    for (int kb = 0; kb < 8; ++kb) {
        short8v a = *(const short8v*)&ldsu[lrowa * LDS_STRIDE + kb * 32 + quad * 8];
#pragma unroll
        for (int c = 0; c < 2; ++c) {
            short8v b = *(const short8v*)(BF2 + (size_t)((ct0 + c) * 8 + kb) * 512 + lane * 8);
            acc3[c] = __builtin_amdgcn_mfma_f32_16x16x32_bf16(a, b, acc3[c], 0, 0, 0);
        }
    }

    // ---- LN2 (+bias, +residual h'): partial stats + 4-way LDS exchange ----
    float s2[4] = {0.f, 0.f, 0.f, 0.f}, ss2[4] = {0.f, 0.f, 0.f, 0.f};
#pragma unroll
    for (int c = 0; c < 2; ++c) {
        float bi = bf2v[(ct0 + c) * 16 + col];
#pragma unroll
        for (int r = 0; r < 4; ++r) {
            float v = acc3[c][r] + bi + val[c][r];
            val[c][r] = v;
            s2[r] += v;
            ss2[r] += v * v;
        }
    }
#pragma unroll
    for (int mask = 1; mask < 16; mask <<= 1) {
#pragma unroll
        for (int r = 0; r < 4; ++r) {
            s2[r] += __shfl_xor(s2[r], mask, 64);
            ss2[r] += __shfl_xor(ss2[r], mask, 64);
        }
    }
    __syncthreads();   // GEMM3 reads of ldsu done; ldsf (alias) free after this point
    if (col == 0) {
#pragma unroll
        for (int r = 0; r < 4; ++r) {
            lnx[wv][lrowc + r][0] = s2[r];
            lnx[wv][lrowc + r][1] = ss2[r];
        }
    }
    __syncthreads();
#pragma unroll
    for (int r = 0; r < 4; ++r) {
        float fs = (lnx[0][lrowc + r][0] + lnx[1][lrowc + r][0]) +
                   (lnx[2][lrowc + r][0] + lnx[3][lrowc + r][0]);
        float fss = (lnx[0][lrowc + r][1] + lnx[1][lrowc + r][1]) +
                    (lnx[2][lrowc + r][1] + lnx[3][lrowc + r][1]);
        float mean = fs * (1.f / 128.f);
        float var = fss * (1.f / 128.f) - mean * mean;
        s2[r] = mean;
        ss2[r] = rsqrtf(var + LN_EPS);
    }
#pragma unroll
    for (int c = 0; c < 2; ++c) {
        float gg = g2v[(ct0 + c) * 16 + col], bb = be2v[(ct0 + c) * 16 + col];
#pragma unroll
        for (int r = 0; r < 4; ++r) {
            float o = (val[c][r] - s2[r]) * ss2[r] * gg + bb;
            ldsf[(lrowc + r) * LDS_FSTRIDE + (ct0 + c) * 16 + col] = o;
        }
    }
    __syncthreads();

    // ---- coalesced stores (256 threads): h as float4, hb as uint4 (8 bf16) ----
#pragma unroll
    for (int j = 0; j < 2; ++j) {
        int p = tid + j * 256;        // 0..511
        int row = p >> 5;
        int c4 = p & 31;
        float4 vv = *(const float4*)&ldsf[row * LDS_FSTRIDE + c4 * 4];
        *(float4*)&h[(size_t)(m0 + row) * 128 + c4 * 4] = vv;
    }
    {
        int p = tid;                  // 0..255
        int row = p >> 4;
        int c8 = p & 15;
        float4 va = *(const float4*)&ldsf[row * LDS_FSTRIDE + c8 * 8];
        float4 vb = *(const float4*)&ldsf[row * LDS_FSTRIDE + c8 * 8 + 4];
        uint4 ou;
        ou.x = (unsigned)f2bf(va.x) | ((unsigned)f2bf(va.y) << 16);
        ou.y = (unsigned)f2bf(va.z) | ((unsigned)f2bf(va.w) << 16);
        ou.z = (unsigned)f2bf(vb.x) | ((unsigned)f2bf(vb.y) << 16);
        ou.w = (unsigned)f2bf(vb.z) | ((unsigned)f2bf(vb.w) << 16);
        *(uint4*)&hb[(size_t)(m0 + row) * 128 + c8 * 8] = ou;
    }
}

// ---------------- attention aggregation --------------------------------------------
// One WAVE per dst node. 4 edge-groups x 16 lanes; lane covers 8 dims (sub = lane&15).
// Q bf16 [N,128]; K/V fp8-e4m3 packed [N,256B] -> ONE uint4 gather per edge per lane.
// Main loop batched 4-DEEP: avg degree 16 -> nfull ~4, so one batch covers a typical
// node's entire main loop -> one exposed gather latency instead of two.
// Log2-domain lazy-max online softmax (u/c1 pre-scaled by isq*log2e).
__global__ __launch_bounds__(64) void agg_kernel(
    const ushort_t* __restrict__ Q, const unsigned char* __restrict__ KV,
    const int* __restrict__ rowstart, const unsigned int* __restrict__ edges,
    const float* __restrict__ u, const float* __restrict__ c1,
    ushort_t* __restrict__ hout) {
    const int lane = threadIdx.x & 63;
    const int v = blockIdx.x;
    const int sub = lane & 15;
    const int grp = lane >> 4;

    // Q dims 8sub..+7 (uint4 = 8 bf16)
    uint4 qu = *(const uint4*)(Q + (size_t)v * 128 + sub * 8);
    float q0 = lo16(qu.x), q1 = hi16(qu.x), q2 = lo16(qu.y), q3 = hi16(qu.y);
    float q4 = lo16(qu.z), q5 = hi16(qu.z), q6 = lo16(qu.w), q7 = hi16(qu.w);
    float4 uva = *(const float4*)(u + sub * 8);
    float4 uvb = *(const float4*)(u + sub * 8 + 4);
    float4 cva = *(const float4*)(c1 + sub * 8);
    float4 cvb = *(const float4*)(c1 + sub * 8 + 4);

    float m = -1.0e38f;
    float sA[8] = {0.f, 0.f, 0.f, 0.f, 0.f, 0.f, 0.f, 0.f};
    float o[8] = {0.f, 0.f, 0.f, 0.f, 0.f, 0.f, 0.f, 0.f};

    const int start = rowstart[v];
    const int deg = rowstart[v + 1] - start;
    const int nfull = deg >> 2;
    const unsigned int* ep = edges + start + grp;

// compute body consuming a pre-loaded edge word + KV vector
#define AGG_COMPUTE(PE, KVv, MASKED, VALID)                                      \
    {                                                                            \
        float ef_ = __uint_as_float((PE) & 0xFFFF0000u);                         \
        float2v k01 = __builtin_amdgcn_cvt_pk_f32_fp8((KVv).x, false);           \
        float2v k23 = __builtin_amdgcn_cvt_pk_f32_fp8((KVv).x, true);            \
        float2v k45 = __builtin_amdgcn_cvt_pk_f32_fp8((KVv).y, false);           \
        float2v k67 = __builtin_amdgcn_cvt_pk_f32_fp8((KVv).y, true);            \
        float p_ = k01[0] * q0;                                                  \
        p_ = fmaf(k01[1], q1, p_);                                               \
        p_ = fmaf(k23[0], q2, p_);                                               \
        p_ = fmaf(k23[1], q3, p_);                                               \
        p_ = fmaf(k45[0], q4, p_);                                               \
        p_ = fmaf(k45[1], q5, p_);                                               \
        p_ = fmaf(k67[0], q6, p_);                                               \
        p_ = fmaf(k67[1], q7, p_);                                               \
        p_ += __shfl_xor(p_, 1, 64);                                             \
        p_ += __shfl_xor(p_, 2, 64);                                             \
        float x0 = p_ * fmaf(ef_, uva.x, cva.x);                                 \
        float x1 = p_ * fmaf(ef_, uva.y, cva.y);                                 \
        float x2 = p_ * fmaf(ef_, uva.z, cva.z);                                 \
        float x3 = p_ * fmaf(ef_, uva.w, cva.w);                                 \
        float x4 = p_ * fmaf(ef_, uvb.x, cvb.x);                                 \
        float x5 = p_ * fmaf(ef_, uvb.y, cvb.y);                                 \
        float x6 = p_ * fmaf(ef_, uvb.z, cvb.z);                                 \
        float x7 = p_ * fmaf(ef_, uvb.w, cvb.w);                                 \
        if (MASKED) {                                                            \
            x0 = (VALID) ? x0 : -1.0e38f; x1 = (VALID) ? x1 : -1.0e38f;          \
            x2 = (VALID) ? x2 : -1.0e38f; x3 = (VALID) ? x3 : -1.0e38f;          \
            x4 = (VALID) ? x4 : -1.0e38f; x5 = (VALID) ? x5 : -1.0e38f;          \
            x6 = (VALID) ? x6 : -1.0e38f; x7 = (VALID) ? x7 : -1.0e38f;          \
        }                                                                        \
        float xm = fmaxf(fmaxf(fmaxf(x0, x1), fmaxf(x2, x3)),                    \
                         fmaxf(fmaxf(x4, x5), fmaxf(x6, x7)));                   \
        if (xm > m) {                                                            \
            float nm = xm + 6.0f;                                                \
            float sc = EXP2(m - nm);                                             \
            sA[0] *= sc; sA[1] *= sc; sA[2] *= sc; sA[3] *= sc;                  \
            sA[4] *= sc; sA[5] *= sc; sA[6] *= sc; sA[7] *= sc;                  \
            o[0] *= sc; o[1] *= sc; o[2] *= sc; o[3] *= sc;                      \
            o[4] *= sc; o[5] *= sc; o[6] *= sc; o[7] *= sc;                      \
            m = nm;                                                              \
        }                                                                        \
        float e0 = EXP2(x0 - m), e1 = EXP2(x1 - m);                              \
        float e2 = EXP2(x2 - m), e3 = EXP2(x3 - m);                              \
        float e4 = EXP2(x4 - m), e5 = EXP2(x5 - m);                              \
        float e6 = EXP2(x6 - m), e7 = EXP2(x7 - m);                              \
        sA[0] += e0; sA[1] += e1; sA[2] += e2; sA[3] += e3;                      \
        sA[4] += e4; sA[5] += e5; sA[6] += e6; sA[7] += e7;                      \
        float2v v01 = __builtin_amdgcn_cvt_pk_f32_fp8((KVv).z, false);           \
        float2v v23 = __builtin_amdgcn_cvt_pk_f32_fp8((KVv).z, true);            \
        float2v v45 = __builtin_amdgcn_cvt_pk_f32_fp8((KVv).w, false);           \
        float2v v67 = __builtin_amdgcn_cvt_pk_f32_fp8((KVv).w, true);            \
        o[0] = fmaf(v01[0], e0, o[0]);                                           \
        o[1] = fmaf(v01[1], e1, o[1]);                                           \
        o[2] = fmaf(v23[0], e2, o[2]);                                           \
        o[3] = fmaf(v23[1], e3, o[3]);                                           \
        o[4] = fmaf(v45[0], e4, o[4]);                                           \
        o[5] = fmaf(v45[1], e5, o[5]);                                           \
        o[6] = fmaf(v67[0], e6, o[6]);                                           \
        o[7] = fmaf(v67[1], e7, o[7]);                                           \
    }

    int it = 0;
    for (; it + 4 <= nfull; it += 4) {
        // batch: issue all 4 edge words + all 4 KV gathers before any compute
        unsigned int pe0 = ep[4 * it];
        unsigned int pe1 = ep[4 * it + 4];
        unsigned int pe2 = ep[4 * it + 8];
        unsigned int pe3 = ep[4 * it + 12];
        uint4 kv0 = *(const uint4*)(KV + (size_t)(pe0 & 0xFFFFu) * 256 + sub * 16);
        uint4 kv1 = *(const uint4*)(KV + (size_t)(pe1 & 0xFFFFu) * 256 + sub * 16);
        uint4 kv2 = *(const uint4*)(KV + (size_t)(pe2 & 0xFFFFu) * 256 + sub * 16);
        uint4 kv3 = *(const uint4*)(KV + (size_t)(pe3 & 0xFFFFu) * 256 + sub * 16);
        AGG_COMPUTE(pe0, kv0, false, true)
        AGG_COMPUTE(pe1, kv1, false, true)
        AGG_COMPUTE(pe2, kv2, false, true)
        AGG_COMPUTE(pe3, kv3, false, true)
    }
    if (it + 2 <= nfull) {
        unsigned int pe0 = ep[4 * it];
        unsigned int pe1 = ep[4 * it + 4];
        uint4 kv0 = *(const uint4*)(KV + (size_t)(pe0 & 0xFFFFu) * 256 + sub * 16);
        uint4 kv1 = *(const uint4*)(KV + (size_t)(pe1 & 0xFFFFu) * 256 + sub * 16);
        AGG_COMPUTE(pe0, kv0, false, true)
        AGG_COMPUTE(pe1, kv1, false, true)
        it += 2;
    }
    if (it < nfull) {
        unsigned int pe0 = ep[4 * it];
        uint4 kv0 = *(const uint4*)(KV + (size_t)(pe0 & 0xFFFFu) * 256 + sub * 16);
        AGG_COMPUTE(pe0, kv0, false, true)
    }
    const int rem = deg & 3;
    if (rem) {
        bool valid = grp < rem;
        unsigned int pe = valid ? ep[4 * nfull] : edges[start];
        uint4 kv = *(const uint4*)(KV + (size_t)(pe & 0xFFFFu) * 256 + sub * 16);
        AGG_COMPUTE(pe, kv, true, valid)
    }
#undef AGG_COMPUTE

    // merge the 4 edge-groups (partners lane^16, lane^32 hold the same dims)
#pragma unroll
    for (int mask = 16; mask <= 32; mask <<= 1) {
        float mo = __shfl_xor(m, mask, 64);
        float mm = fmaxf(m, mo);
        float sca = EXP2(m - mm);
        float scb = EXP2(mo - mm);
#pragma unroll
        for (int j = 0; j < 8; ++j) {
            float t = __shfl_xor(sA[j], mask, 64);
            sA[j] = sA[j] * sca + t * scb;
            t = __shfl_xor(o[j], mask, 64);
            o[j] = o[j] * sca + t * scb;
        }
        m = mm;
    }

    if (grp == 0) {
        // ref: h_out = num / max(Z, 1e-6); ours scaled by 2^m; 1e-37 NaN guard
        float zc = 1e-6f * EXP2(-m);
        uint4 ou;
        unsigned int w0, w1;
        float z;
        z = fmaxf(fmaxf(sA[0], zc), 1e-37f); w0 = f2bf(o[0] / z);
        z = fmaxf(fmaxf(sA[1], zc), 1e-37f); w1 = f2bf(o[1] / z);
        ou.x = w0 | (w1 << 16);
        z = fmaxf(fmaxf(sA[2], zc), 1e-37f); w0 = f2bf(o[2] / z);
        z = fmaxf(fmaxf(sA[3], zc), 1e-37f); w1 = f2bf(o[3] / z);
        ou.y = w0 | (w1 << 16);
        z = fmaxf(fmaxf(sA[4], zc), 1e-37f); w0 = f2bf(o[4] / z);
        z = fmaxf(fmaxf(sA[5], zc), 1e-37f); w1 = f2bf(o[5] / z);
        ou.z = w0 | (w1 << 16);
        z = fmaxf(fmaxf(sA[6], zc), 1e-37f); w0 = f2bf(o[6] / z);
        z = fmaxf(fmaxf(sA[7], zc), 1e-37f); w1 = f2bf(o[7] / z);
        ou.w = w0 | (w1 << 16);
        *(uint4*)(hout + (size_t)v * 128 + sub * 8) = ou;
    }
}

// ---------------- mean over nodes ------------------------------------------------------
__global__ void mean_part_kernel(const float* __restrict__ h, float* __restrict__ macc) {
    __shared__ float s[256];
    int t = threadIdx.x;
    int col = t & 127;
    int half = t >> 7;
    int r0 = blockIdx.x * 256;
    float acc = 0.f;
    for (int r = half; r < 256; r += 2) acc += h[(size_t)(r0 + r) * 128 + col];
    s[t] = acc;
    __syncthreads();
    if (t < 128) atomicAdd(&macc[t], s[t] + s[t + 128]);
}

// ---------------- finalize -------------------------------------------------------------
__global__ void finalize_kernel(const float* __restrict__ macc, void* __restrict__ out,
                                const int* __restrict__ flag) {
    int t = threadIdx.x;
    float v = macc[t] * (1.f / (float)N_NODES);
    if (*flag)
        ((ushort_t*)out)[t] = f2bf(v);
    else
        ((float*)out)[t] = v;
}

// ---------------------------------------------------------------------------------------
extern "C" void kernel_launch(void* const* d_in, const int* in_sizes, int n_in,
                              void* d_out, int out_size, void* d_ws, size_t ws_size,
                              hipStream_t stream) {
    const int* src = (const int*)d_in[3];
    const int* dst = (const int*)d_in[4];

    char* w = (char*)d_ws;
    const size_t MB = 1u << 20;
    float* h        = (float*)(w);               // 16 MB [N,128] f32
    ushort_t* hb    = (ushort_t*)(w + 16 * MB);  //  8 MB [N,128] bf16 (also = HOUT)
    ushort_t* Qh    = (ushort_t*)(w + 24 * MB);  //  8 MB [N,128] bf16
    unsigned char* KVf8 = (unsigned char*)(w + 32 * MB);  // 8 MB [N,256B] fp8 K|V packed
    char* aux       = w + 48 * MB;
    int* deg        = (int*)(aux);               // 128 KB
    int* rowstart   = (int*)(aux + 0x40000);     // 128 KB + 4
    int* cursor     = (int*)(aux + 0x80000);     // 128 KB
    unsigned int* edges = (unsigned int*)(aux + 0xC0000);          // 2 MB
    float* ubuf     = (float*)(aux + 0xC0000 + 2 * MB);            // 3*128 f32
    float* cbuf     = ubuf + 3 * 128;
    float* macc     = cbuf + 3 * 128;            // 128 f32
    int* flag       = (int*)(macc + 128);
    float* conv     = (float*)(aux + 0xC0000 + 2 * MB + 4096);     // 40 KB f32
    ushort_t* swz   = (ushort_t*)((char*)conv + CONV_TOTAL * 4);   // 784 KB bf16

    detect_kernel<<<1, 256, 0, stream>>>((const unsigned int*)d_in[5], flag);

    ConvArgs ca;
    ca.src[0] = d_in[5];    // W_node
    ca.src[1] = d_in[6];    // b_node
    ca.src[2] = d_in[7];    // W_pos
    ca.src[3] = d_in[8];    // b_pos
    ca.src[4] = d_in[9];    // W_edge
    ca.src[5] = d_in[10];   // b_edge
    ca.src[6] = d_in[16];   // b_lin
    ca.src[7] = d_in[17];   // g1
    ca.src[8] = d_in[18];   // be1
    ca.src[9] = d_in[20];   // bf1
    ca.src[10] = d_in[22];  // bf2
    ca.src[11] = d_in[23];  // g2
    ca.src[12] = d_in[24];  // be2
    // convert also zeros deg (replaces hipMemsetAsync node)
    convert_kernel<<<(CONV_TOTAL + 255) / 256, 256, 0, stream>>>(ca, flag, conv, deg);

    // swz (192 blocks) + fused uc (3 blocks) + input-proj records (4 blocks)
    swz_kernel<<<192 + 3 + 4, 256, 0, stream>>>(
        d_in[11], d_in[12], d_in[13], d_in[15], d_in[19], d_in[21],
        d_in[14], d_in[9], d_in[10], d_in[5], d_in[7], flag, swz, ubuf, cbuf);

    // input projection via MFMA + fused degree histogram
    ip_gemm<<<N_NODES / 64, 256, 0, stream>>>(d_in[0], d_in[1], conv, flag, dst, deg,
                                              swz + (size_t)REC_WNP * 512, h, hb);
    // scan also zeros macc (replaces hipMemsetAsync node)
    scan_kernel<<<1, 1024, 0, stream>>>(deg, rowstart, cursor, macc);
    scatter_kernel<<<N_EDGES / 256, 256, 0, stream>>>(src, dst, d_in[2], flag, cursor,
                                                      edges);

    for (int i = 0; i < 3; ++i) {
        const ushort_t* swzQKV = swz + (size_t)REC_QKV(i) * 512;
        const ushort_t* swzWL  = swz + (size_t)REC_WLIN(i) * 512;
        const ushort_t* swzF1  = swz + (size_t)REC_WF1(i) * 512;
        const ushort_t* swzF2  = swz + (size_t)REC_WF2(i) * 512;

        // Q bf16 + K/V fp8 packed (3-segment, 4-wave blocks)
        qkv_gemm<4><<<dim3(N_NODES / 64, 3), 256, 0, stream>>>(hb, swzQKV, Qh, KVf8);

        // attention -> hb (= HOUT) [N,128] bf16 (4-deep batched gather main loop)
        agg_kernel<<<N_NODES, 64, 0, stream>>>(Qh, KVf8, rowstart, edges,
                                               ubuf + i * 128, cbuf + i * 128, hb);

        // fused layer tail, FOUR waves per 16-row tile (grid 2048 x 256 thr)
        ffn_kernel<<<N_NODES / 16, 256, 0, stream>>>(
            hb, swzWL, swzF1, swzF2,
            conv + OFF_BLIN + i * 128, conv + OFF_G1 + i * 128, conv + OFF_BE1 + i * 128,
            conv + OFF_BF1 + i * 256,
            conv + OFF_BF2 + i * 128, conv + OFF_G2 + i * 128, conv + OFF_BE2 + i * 128,
            h, hb);
    }

    mean_part_kernel<<<N_NODES / 256, 256, 0, stream>>>(h, macc);
    finalize_kernel<<<1, 128, 0, stream>>>(macc, d_out, flag);
}

// Round 11
// 428.889 us; speedup vs baseline: 1.3156x; 1.0237x over previous
//
#include <hip/hip_runtime.h>
#include <hip/hip_bf16.h>

#define N_NODES 32768
#define N_EDGES 524288
#define LN_EPS 1e-5f

typedef unsigned short ushort_t;
typedef __attribute__((ext_vector_type(8))) short short8v;
typedef __attribute__((ext_vector_type(4))) float float4v;
typedef __attribute__((ext_vector_type(2))) float float2v;

__device__ __forceinline__ float bf2f(ushort_t u) {
    return __uint_as_float(((unsigned int)u) << 16);
}
__device__ __forceinline__ ushort_t f2bf(float f) {
    unsigned int u = __float_as_uint(f);
    unsigned int r = (u + 0x7FFFu + ((u >> 16) & 1u)) >> 16;
    return (ushort_t)r;
}
__device__ __forceinline__ float lo16(unsigned int x) { return __uint_as_float(x << 16); }
__device__ __forceinline__ float hi16(unsigned int x) { return __uint_as_float(x & 0xFFFF0000u); }

#if __has_builtin(__builtin_amdgcn_exp2f)
#define EXP2(x) __builtin_amdgcn_exp2f(x)
#else
#define EXP2(x) exp2f(x)
#endif

// compact f32 conv region: only params consumed as f32 (biases, LN, input-proj weights)
#define OFF_WNODE 0
#define OFF_BNODE 5632
#define OFF_WPOS  5760
#define OFF_BPOS  6784
#define OFF_WEDGE 6912
#define OFF_BEDGE 7040
#define OFF_BLIN  7168
#define OFF_G1    7552
#define OFF_BE1   7936
#define OFF_BF1   8320
#define OFF_BF2   9088
#define OFF_G2    9472
#define OFF_BE2   9856
#define CONV_TOTAL 10240

// swizzled-B record bases (records of 512 ushorts = 64 lanes x 8 bf16)
#define REC_QKV(i)  ((i) * 96)          // 24 ct x 4 kb
#define REC_WLIN(i) (288 + (i) * 32)    // 8 ct x 4 kb
#define REC_WF1(i)  (384 + (i) * 64)    // 16 ct x 4 kb
#define REC_WF2(i)  (576 + (i) * 64)    // 8 ct x 8 kb
#define REC_WNP     768                 // input-proj [Wn;Wp;0] 8 ct x 2 kb
#define REC_TOTAL   784

#define LDS_STRIDE 264   // ushorts per LDS row (256 + 8 pad)
#define LDS_FSTRIDE 132  // floats per LDS row (same byte footprint)

// ---------------- dtype detection: bf16 data has exponent-like bits at [15:8] ---------
__global__ void detect_kernel(const unsigned int* __restrict__ wn, int* __restrict__ flag) {
    __shared__ int s[256];
    int t = threadIdx.x;
    int cnt = 0;
    for (int i = t; i < 2816; i += 256) {
        unsigned int b = (wn[i] >> 8) & 0x7F;
        cnt += (b >= 0x3A && b <= 0x40) ? 1 : 0;
    }
    s[t] = cnt;
    __syncthreads();
    for (int off = 128; off > 0; off >>= 1) {
        if (t < off) s[t] += s[t + off];
        __syncthreads();
    }
    if (t == 0) *flag = (s[0] > 1408) ? 1 : 0;   // 1 = bf16, 0 = f32
}

// ---------------- canonicalize small param buffers to f32 scratch ---------------------
// Also zeros the degree histogram (replaces a hipMemsetAsync dispatch node).
struct ConvArgs { const void* src[13]; };

__global__ void convert_kernel(ConvArgs a, const int* __restrict__ flag,
                               float* __restrict__ dst, int* __restrict__ deg) {
    int gid = blockIdx.x * 256 + threadIdx.x;
    for (int i = gid; i < N_NODES; i += CONV_TOTAL) deg[i] = 0;   // fused deg-zero
    if (gid >= CONV_TOTAL) return;
    const int off[14] = {OFF_WNODE, OFF_BNODE, OFF_WPOS, OFF_BPOS, OFF_WEDGE, OFF_BEDGE,
                         OFF_BLIN, OFF_G1, OFF_BE1, OFF_BF1, OFF_BF2, OFF_G2, OFF_BE2,
                         CONV_TOTAL};
    int s = 0;
#pragma unroll
    for (int i = 1; i < 13; ++i) s += (gid >= off[i]) ? 1 : 0;
    int local = gid - off[s];
    if (*flag)
        dst[gid] = bf2f(((const ushort_t*)a.src[s])[local]);
    else
        dst[gid] = ((const float*)a.src[s])[local];
}

// ---------------- swizzle GEMM weights into MFMA B-fragment records (raw sources) -----
// record(ct,kb): lane l holds W[kb*32 + (l>>4)*8 + j][ct*16 + (l&15)], j=0..7
// blocks 192..194 compute u/c1 (fused uc); blocks 195..198 build input-proj records.
__global__ void swz_kernel(const void* __restrict__ Wq, const void* __restrict__ Wk,
                           const void* __restrict__ Wv, const void* __restrict__ Wlin,
                           const void* __restrict__ Wf1, const void* __restrict__ Wf2,
                           const void* __restrict__ We, const void* __restrict__ wedge,
                           const void* __restrict__ bedge,
                           const void* __restrict__ Wn_, const void* __restrict__ Wp_,
                           const int* __restrict__ flag,
                           ushort_t* __restrict__ swz,
                           float* __restrict__ u, float* __restrict__ c1) {
    const bool isbf = (*flag != 0);
    if (blockIdx.x >= 195) {
        // input-proj B records: W[k][n], k = 0..43 Wn, 44..51 Wp, 52..63 zero pad
        int idx = (blockIdx.x - 195) * 256 + threadIdx.x;   // 0..1023
        int rec16 = idx >> 6;                               // 0..15
        int lane = idx & 63;
        int ct = rec16 >> 1, kb = rec16 & 1;
        int col = lane & 15, quad = lane >> 4;
        int n = ct * 16 + col;
        ushort_t v[8];
#pragma unroll
        for (int j = 0; j < 8; ++j) {
            int k = kb * 32 + quad * 8 + j;
            if (isbf) {
                v[j] = (k < 44) ? ((const ushort_t*)Wn_)[k * 128 + n]
                     : ((k < 52) ? ((const ushort_t*)Wp_)[(k - 44) * 128 + n]
                                 : (ushort_t)0);
            } else {
                float f = (k < 44) ? ((const float*)Wn_)[k * 128 + n]
                        : ((k < 52) ? ((const float*)Wp_)[(k - 44) * 128 + n] : 0.f);
                v[j] = f2bf(f);
            }
        }
        ushort_t* o = swz + (size_t)(REC_WNP + rec16) * 512 + lane * 8;
#pragma unroll
        for (int j = 0; j < 8; ++j) o[j] = v[j];
        return;
    }
    if (blockIdx.x >= 192) {
        // fused uc: pre-scaled by (1/sqrt(dk))*log2(e); agg works in log2 domain
        int l = blockIdx.x - 192;
        int d = threadIdx.x;
        if (d >= 128) return;
        float uu = 0.f, cc = 0.f;
        if (isbf) {
            const ushort_t* Wl = (const ushort_t*)We + (size_t)l * 16384;
            const ushort_t* we_ = (const ushort_t*)wedge;
            const ushort_t* be_ = (const ushort_t*)bedge;
#pragma unroll 4
            for (int k = 0; k < 128; ++k) {
                float w = bf2f(Wl[k * 128 + d]);
                uu = fmaf(bf2f(we_[k]), w, uu);
                cc = fmaf(bf2f(be_[k]), w, cc);
            }
        } else {
            const float* Wl = (const float*)We + (size_t)l * 16384;
            const float* we_ = (const float*)wedge;
            const float* be_ = (const float*)bedge;
#pragma unroll 4
            for (int k = 0; k < 128; ++k) {
                float w = Wl[k * 128 + d];
                uu = fmaf(we_[k], w, uu);
                cc = fmaf(be_[k], w, cc);
            }
        }
        const float scale = 0.17677669529663687f * 1.4426950408889634f;  // isq * log2(e)
        u[l * 128 + d] = uu * scale;
        c1[l * 128 + d] = (1.f + cc) * scale;
        return;
    }
    int gid = blockIdx.x * 256 + threadIdx.x;
    int lane = gid & 63;
    int rec = gid >> 6;
    int col = lane & 15, quad = lane >> 4;
    const void* src;
    size_t base;
    int ct, kb, OC;
    if (rec < 288) {                       // QKV: 3 layers x 24ct x 4kb
        int layer = rec / 96, r2 = rec % 96;
        ct = r2 >> 2; kb = r2 & 3;
        int seg = ct >> 3;                 // 0=Wq 1=Wk 2=Wv
        src = (seg == 0) ? Wq : ((seg == 1) ? Wk : Wv);
        base = (size_t)layer * 16384; OC = 128; ct &= 7;
    } else if (rec < 384) {                // W_lin
        int r = rec - 288, layer = r / 32, r2 = r % 32;
        ct = r2 >> 2; kb = r2 & 3;
        src = Wlin; base = (size_t)layer * 16384; OC = 128;
    } else if (rec < 576) {                // Wf1 (OC=256)
        int r = rec - 384, layer = r / 64, r2 = r % 64;
        ct = r2 >> 2; kb = r2 & 3;
        src = Wf1; base = (size_t)layer * 32768; OC = 256;
    } else {                               // Wf2 (K=256)
        int r = rec - 576, layer = r / 64, r2 = r % 64;
        ct = r2 >> 3; kb = r2 & 7;
        src = Wf2; base = (size_t)layer * 32768; OC = 128;
    }
    int n = ct * 16 + col;
    ushort_t v[8];
    if (isbf) {
        const ushort_t* s16 = (const ushort_t*)src + base;
#pragma unroll
        for (int j = 0; j < 8; ++j) v[j] = s16[(size_t)(kb * 32 + quad * 8 + j) * OC + n];
    } else {
        const float* s32 = (const float*)src + base;
#pragma unroll
        for (int j = 0; j < 8; ++j) v[j] = f2bf(s32[(size_t)(kb * 32 + quad * 8 + j) * OC + n]);
    }
    ushort_t* o = swz + (size_t)rec * 512 + lane * 8;
#pragma unroll
    for (int j = 0; j < 8; ++j) o[j] = v[j];
}

// ---------------- input projection via MFMA: h = [feats|lap|0] @ [Wn;Wp;0] + biases ---
// Grid N/64 blocks x 256 thr (4 waves); A tile staged bf16 in LDS; B from swz records.
// Fused degree histogram (4 strided passes). Outputs h f32 + hb bf16.
__global__ __launch_bounds__(256) void ip_gemm(
    const void* __restrict__ feats, const void* __restrict__ lap,
    const float* __restrict__ conv, const int* __restrict__ flag,
    const int* __restrict__ dstidx, int* __restrict__ deg,
    const ushort_t* __restrict__ Bswz,   // = swz + REC_WNP*512
    float* __restrict__ h, ushort_t* __restrict__ hb) {
    __shared__ __align__(16) ushort_t As[64 * 72];   // 64 rows x K=64, stride 72
    const int tid = threadIdx.x;

    // fused histogram: 512*256 threads x 4 edges
    for (int e = blockIdx.x * 256 + tid; e < N_EDGES; e += (N_NODES / 64) * 256)
        atomicAdd(&deg[dstidx[e]], 1);

    const bool isbf = (*flag != 0);
    const int r = tid >> 2;          // 0..63 (tile row)
    const int t4 = tid & 3;          // 16-col chunk
    const int m0g = blockIdx.x * 64;
    {
        const int row = m0g + r;
        ushort_t tmp[16];
        if (isbf) {
            const ushort_t* frow = (const ushort_t*)feats + (size_t)row * 44;
            const ushort_t* prow = (const ushort_t*)lap + (size_t)row * 8;
#pragma unroll
            for (int j = 0; j < 16; ++j) {
                int k = t4 * 16 + j;
                tmp[j] = (k < 44) ? frow[k]
                       : ((k < 52) ? prow[k - 44] : (ushort_t)0);
            }
        } else {
            const float* frow = (const float*)feats + (size_t)row * 44;
            const float* prow = (const float*)lap + (size_t)row * 8;
#pragma unroll
            for (int j = 0; j < 16; ++j) {
                int k = t4 * 16 + j;
                float v = (k < 44) ? frow[k] : ((k < 52) ? prow[k - 44] : 0.f);
                tmp[j] = f2bf(v);
            }
        }
#pragma unroll
        for (int j = 0; j < 16; ++j) As[r * 72 + t4 * 16 + j] = tmp[j];
    }
    __syncthreads();

    const int wv = tid >> 6, lane = tid & 63;
    const int col = lane & 15, quad = lane >> 4;
    const int m0 = wv * 16;
    short8v a0 = *(const short8v*)&As[(m0 + col) * 72 + quad * 8];
    short8v a1 = *(const short8v*)&As[(m0 + col) * 72 + 32 + quad * 8];

    float4v acc[8];
#pragma unroll
    for (int ct = 0; ct < 8; ++ct) {
        short8v b0 = *(const short8v*)(Bswz + (size_t)(ct * 2 + 0) * 512 + lane * 8);
        short8v b1 = *(const short8v*)(Bswz + (size_t)(ct * 2 + 1) * 512 + lane * 8);
        float4v a = (float4v){0.f, 0.f, 0.f, 0.f};
        a = __builtin_amdgcn_mfma_f32_16x16x32_bf16(a0, b0, a, 0, 0, 0);
        a = __builtin_amdgcn_mfma_f32_16x16x32_bf16(a1, b1, a, 0, 0, 0);
        acc[ct] = a;
    }

    const int rowb = m0g + m0 + quad * 4;
#pragma unroll
    for (int ct = 0; ct < 8; ++ct) {
        int j = ct * 16 + col;
        float bias = conv[OFF_BNODE + j] + conv[OFF_BPOS + j];
#pragma unroll
        for (int rr = 0; rr < 4; ++rr) {
            float o = acc[ct][rr] + bias;
            h[(size_t)(rowb + rr) * 128 + j] = o;
            hb[(size_t)(rowb + rr) * 128 + j] = f2bf(o);
        }
    }
}

// ---------------- CSR build ------------------------------------------------------------
// Also zeros macc (replaces a hipMemsetAsync dispatch node; mean_part runs much later).
__global__ void scan_kernel(const int* __restrict__ deg, int* __restrict__ rowstart,
                            int* __restrict__ cursor, float* __restrict__ macc) {
    __shared__ int lds[1024];
    int t = threadIdx.x;
    if (t < 128) macc[t] = 0.f;                 // fused macc-zero
    int base = t * 32;
    int v[32];
    int csum = 0;
#pragma unroll
    for (int j = 0; j < 8; ++j) {               // coalesced int4 loads
        int4 x = *(const int4*)(deg + base + j * 4);
        v[j * 4 + 0] = x.x; v[j * 4 + 1] = x.y;
        v[j * 4 + 2] = x.z; v[j * 4 + 3] = x.w;
        csum += x.x + x.y + x.z + x.w;
    }
    lds[t] = csum;
    __syncthreads();
    for (int off = 1; off < 1024; off <<= 1) {
        int x = (t >= off) ? lds[t - off] : 0;
        __syncthreads();
        lds[t] += x;
        __syncthreads();
    }
    int excl = lds[t] - csum;
    int running = excl;
#pragma unroll
    for (int j = 0; j < 8; ++j) {
        int4 w;
        w.x = running; running += v[j * 4 + 0];
        w.y = running; running += v[j * 4 + 1];
        w.z = running; running += v[j * 4 + 2];
        w.w = running; running += v[j * 4 + 3];
        *(int4*)(rowstart + base + j * 4) = w;
        *(int4*)(cursor + base + j * 4) = w;
    }
    if (t == 1023) rowstart[N_NODES] = running;
}

__global__ void scatter_kernel(const int* __restrict__ src, const int* __restrict__ dst,
                               const void* __restrict__ ef, const int* __restrict__ flag,
                               int* __restrict__ cursor,
                               unsigned int* __restrict__ edges) {
    int e = blockIdx.x * 256 + threadIdx.x;
    if (e < N_EDGES) {
        ushort_t efb = (*flag != 0) ? ((const ushort_t*)ef)[e]
                                    : f2bf(((const float*)ef)[e]);
        int d = dst[e];
        int p = atomicAdd(&cursor[d], 1);
        edges[p] = (unsigned int)src[e] | ((unsigned int)efb << 16);
    }
}

// ---------------- MFMA GEMM (QKV): seg 0 -> Q bf16 [N,128];
//                  segs 1/2 -> K/V packed fp8-e4m3 into KV [N,256B]
//                  (per 8-dim block b: bytes 16b..16b+7 = K dims, +8..+15 = V dims).
// Block: 256 thr = 4 waves; wave = 16 rows x 128 cols; grid = (M/64, 3 segs).
template <int KB>
__global__ __launch_bounds__(256) void qkv_gemm(
    const ushort_t* __restrict__ A,
    const ushort_t* __restrict__ Bswz,
    ushort_t* __restrict__ outQ,
    unsigned char* __restrict__ outKV) {
    const int K = KB * 32;
    const int tid = threadIdx.x;
    const int wv = tid >> 6, lane = tid & 63;
    const int col = lane & 15, quad = lane >> 4;
    const int m0 = blockIdx.x * 64 + wv * 16;
    const int ct0 = blockIdx.y * 8;

    float4v acc[8];
#pragma unroll
    for (int ct = 0; ct < 8; ++ct) acc[ct] = (float4v){0.f, 0.f, 0.f, 0.f};

    const ushort_t* Ap = A + (size_t)(m0 + col) * K + quad * 8;
    const ushort_t* Bp = Bswz + (size_t)ct0 * KB * 512 + lane * 8;

#pragma unroll
    for (int kb = 0; kb < KB; ++kb) {
        short8v a = *(const short8v*)(Ap + kb * 32);
#pragma unroll
        for (int ct = 0; ct < 8; ++ct) {
            short8v b = *(const short8v*)(Bp + (size_t)(ct * KB + kb) * 512);
            acc[ct] = __builtin_amdgcn_mfma_f32_16x16x32_bf16(a, b, acc[ct], 0, 0, 0);
        }
    }

    const int rowb = m0 + quad * 4;
    const int seg = blockIdx.y;
    if (seg == 0) {
#pragma unroll
        for (int ct = 0; ct < 8; ++ct) {
            int j = ct * 16 + col;
#pragma unroll
            for (int r = 0; r < 4; ++r)
                outQ[(size_t)(rowb + r) * 128 + j] = f2bf(acc[ct][r]);
        }
    } else {
        const int vofs = (seg == 2) ? 8 : 0;
#pragma unroll
        for (int ct = 0; ct < 8; ++ct) {
            int j = ct * 16 + col;
            int off = ((j >> 3) * 16) + (j & 7) + vofs;
#pragma unroll
            for (int r = 0; r < 4; ++r) {
                float a = acc[ct][r];
                float b = __shfl_xor(a, 1, 64);   // partner col (j^1) same ct,r
                if ((col & 1) == 0) {
                    unsigned short pk = (unsigned short)
                        __builtin_amdgcn_cvt_pk_fp8_f32(a, b, 0, false);
                    *(ushort_t*)(outKV + (size_t)(rowb + r) * 256 + off) = pk;
                }
            }
        }
    }
}

// ---------------- fused layer tail: h = LN2(h' + relu(h'@Wf1+b)@Wf2+b2),
//                  h' = LN1(h + HOUT@WL+bl). FOUR waves per 16-row tile (grid N/16,
//                  256 thr): wave wv owns a quarter of the output columns of each
//                  GEMM; LN row-stats completed via a 4-way LDS exchange. Same total
//                  work as the 1-wave version, 4x resident waves (grid-limited).
__global__ __launch_bounds__(256, 2) void ffn_kernel(
    const ushort_t* __restrict__ HOUT,   // [N,128] bf16 (= hb, attention out)
    const ushort_t* __restrict__ BWL,    // swz W_lin  (8ct x 4kb)
    const ushort_t* __restrict__ BF1,    // swz Wf1    (16ct x 4kb)
    const ushort_t* __restrict__ BF2,    // swz Wf2    (8ct x 8kb)
    const float* __restrict__ bl,
    const float* __restrict__ g1v, const float* __restrict__ be1v,
    const float* __restrict__ bf1v,
    const float* __restrict__ bf2v,
    const float* __restrict__ g2v, const float* __restrict__ be2v,
    float* __restrict__ h,               // [N,128] f32 in-out (residual -> final)
    ushort_t* __restrict__ hb) {         // [N,128] bf16 out
    __shared__ __align__(16) char ldsraw[16 * 528];   // 8448 B, dual-view
    __shared__ float lnx[4][16][2];      // cross-wave LN partials [wave][row][sum,sumsq]
    ushort_t* ldsu = (ushort_t*)ldsraw;  // stride LDS_STRIDE (264)
    float* ldsf = (float*)ldsraw;        // stride LDS_FSTRIDE (132)
    const int tid = threadIdx.x;
    const int wv = tid >> 6;             // 0..3 (column-quarter owner)
    const int lane = tid & 63;
    const int col = lane & 15, quad = lane >> 4;
    const int m0 = blockIdx.x * 16;
    const int rowb = m0 + quad * 4;          // global row base (C-layout)
    const int lrowc = quad * 4;              // LDS row base for C-layout stores
    const int lrowa = col;                   // LDS row for A-fragment reads
    const int ct0 = wv * 2;                  // GEMM1/GEMM3 ct base (2 of 8)

    // ---- GEMM1: HOUT @ W_lin (this wave: cts ct0..ct0+1) ----
    float4v acc[2];
#pragma unroll
    for (int c = 0; c < 2; ++c) acc[c] = (float4v){0.f, 0.f, 0.f, 0.f};
    const ushort_t* Ap = HOUT + (size_t)(m0 + col) * 128 + quad * 8;
#pragma unroll
    for (int kb = 0; kb < 4; ++kb) {
        short8v a = *(const short8v*)(Ap + kb * 32);
#pragma unroll
        for (int c = 0; c < 2; ++c) {
            short8v b = *(const short8v*)(BWL + (size_t)((ct0 + c) * 4 + kb) * 512 + lane * 8);
            acc[c] = __builtin_amdgcn_mfma_f32_16x16x32_bf16(a, b, acc[c], 0, 0, 0);
        }
    }

    // ---- LN1 (+bias, +residual h): wave-partial stats then 4-way LDS exchange ----
    float val[2][4], s[4] = {0.f, 0.f, 0.f, 0.f}, ss[4] = {0.f, 0.f, 0.f, 0.f};
#pragma unroll
    for (int c = 0; c < 2; ++c) {
        float bi = bl[(ct0 + c) * 16 + col];
#pragma unroll
        for (int r = 0; r < 4; ++r) {
            float v = acc[c][r] + bi + h[(size_t)(rowb + r) * 128 + (ct0 + c) * 16 + col];
            val[c][r] = v;
            s[r] += v;
            ss[r] += v * v;
        }
    }
#pragma unroll
    for (int mask = 1; mask < 16; mask <<= 1) {
#pragma unroll
        for (int r = 0; r < 4; ++r) {
            s[r] += __shfl_xor(s[r], mask, 64);
            ss[r] += __shfl_xor(ss[r], mask, 64);
        }
    }
    if (col == 0) {
#pragma unroll
        for (int r = 0; r < 4; ++r) {
            lnx[wv][lrowc + r][0] = s[r];
            lnx[wv][lrowc + r][1] = ss[r];
        }
    }
    __syncthreads();
#pragma unroll
    for (int r = 0; r < 4; ++r) {
        float fs = (lnx[0][lrowc + r][0] + lnx[1][lrowc + r][0]) +
                   (lnx[2][lrowc + r][0] + lnx[3][lrowc + r][0]);
        float fss = (lnx[0][lrowc + r][1] + lnx[1][lrowc + r][1]) +
                    (lnx[2][lrowc + r][1] + lnx[3][lrowc + r][1]);
        float mean = fs * (1.f / 128.f);
        float var = fss * (1.f / 128.f) - mean * mean;
        s[r] = mean;
        ss[r] = rsqrtf(var + LN_EPS);
    }
#pragma unroll
    for (int c = 0; c < 2; ++c) {
        float gg = g1v[(ct0 + c) * 16 + col], bb = be1v[(ct0 + c) * 16 + col];
#pragma unroll
        for (int r = 0; r < 4; ++r) {
            float o = (val[c][r] - s[r]) * ss[r] * gg + bb;
            val[c][r] = o;                                       // residual for LN2
            ldsu[(lrowc + r) * LDS_STRIDE + (ct0 + c) * 16 + col] = f2bf(o);
        }
    }
    __syncthreads();

    // ---- A-fragments of h' from LDS (full K) ----
    short8v af[4];
#pragma unroll
    for (int kb = 0; kb < 4; ++kb)
        af[kb] = *(const short8v*)&ldsu[lrowa * LDS_STRIDE + kb * 32 + quad * 8];

    // ---- GEMM2: h' @ Wf1 (OC=256; this wave: cts wv*4..wv*4+3) ----
    float4v acc2[4];
#pragma unroll
    for (int c = 0; c < 4; ++c) acc2[c] = (float4v){0.f, 0.f, 0.f, 0.f};
#pragma unroll
    for (int kb = 0; kb < 4; ++kb) {
#pragma unroll
        for (int c = 0; c < 4; ++c) {
            short8v b = *(const short8v*)(BF1 + (size_t)((wv * 4 + c) * 4 + kb) * 512 + lane * 8);
            acc2[c] = __builtin_amdgcn_mfma_f32_16x16x32_bf16(af[kb], b, acc2[c], 0, 0, 0);
        }
    }
    __syncthreads();

    // ---- T = relu(acc2 + bf1) -> LDS (this wave's 4 cts) ----
#pragma unroll
    for (int c = 0; c < 4; ++c) {
        float bi = bf1v[(wv * 4 + c) * 16 + col];
#pragma unroll
        for (int r = 0; r < 4; ++r) {
            float v = fmaxf(acc2[c][r] + bi, 0.f);
            ldsu[(lrowc + r) * LDS_STRIDE + (wv * 4 + c) * 16 + col] = f2bf(v);
        }
    }
    __syncthreads();

    // ---- GEMM3: T @ Wf2 (K=256; this wave: cts ct0..ct0+1) ----
    float4v acc3[2];
#pragma unroll
    for (int c = 0; c < 2; ++c) acc3[c] = (float4v){0.f, 0.f, 0.f, 0.f};
#pragma unroll
    for (int kb = 0; kb < 8; ++kb) {
        short8v a = *(const short8v*)&ldsu[lrowa * LDS_STRIDE + kb * 32 + quad * 8];
#pragma unroll
        for (int c = 0; c < 2; ++c) {
            short8v b = *(const short8v*)(BF2 + (size_t)((ct0 + c) * 8 + kb) * 512 + lane * 8);
            acc3[c] = __builtin_amdgcn_mfma_f32_16x16x32_bf16(a, b, acc3[c], 0, 0, 0);
        }
    }

    // ---- LN2 (+bias, +residual h'): partial stats + 4-way LDS exchange ----
    float s2[4] = {0.f, 0.f, 0.f, 0.f}, ss2[4] = {0.f, 0.f, 0.f, 0.f};
#pragma unroll
    for (int c = 0; c < 2; ++c) {
        float bi = bf2v[(ct0 + c) * 16 + col];
#pragma unroll
        for (int r = 0; r < 4; ++r) {
            float v = acc3[c][r] + bi + val[c][r];
            val[c][r] = v;
            s2[r] += v;
            ss2[r] += v * v;
        }
    }
#pragma unroll
    for (int mask = 1; mask < 16; mask <<= 1) {
#pragma unroll
        for (int r = 0; r < 4; ++r) {
            s2[r] += __shfl_xor(s2[r], mask, 64);
            ss2[r] += __shfl_xor(ss2[r], mask, 64);
        }
    }
    __syncthreads();   // GEMM3 reads of ldsu done; ldsf (alias) free after this point
    if (col == 0) {
#pragma unroll
        for (int r = 0; r < 4; ++r) {
            lnx[wv][lrowc + r][0] = s2[r];
            lnx[wv][lrowc + r][1] = ss2[r];
        }
    }
    __syncthreads();
#pragma unroll
    for (int r = 0; r < 4; ++r) {
        float fs = (lnx[0][lrowc + r][0] + lnx[1][lrowc + r][0]) +
                   (lnx[2][lrowc + r][0] + lnx[3][lrowc + r][0]);
        float fss = (lnx[0][lrowc + r][1] + lnx[1][lrowc + r][1]) +
                    (lnx[2][lrowc + r][1] + lnx[3][lrowc + r][1]);
        float mean = fs * (1.f / 128.f);
        float var = fss * (1.f / 128.f) - mean * mean;
        s2[r] = mean;
        ss2[r] = rsqrtf(var + LN_EPS);
    }
#pragma unroll
    for (int c = 0; c < 2; ++c) {
        float gg = g2v[(ct0 + c) * 16 + col], bb = be2v[(ct0 + c) * 16 + col];
#pragma unroll
        for (int r = 0; r < 4; ++r) {
            float o = (val[c][r] - s2[r]) * ss2[r] * gg + bb;
            ldsf[(lrowc + r) * LDS_FSTRIDE + (ct0 + c) * 16 + col] = o;
        }
    }
    __syncthreads();

    // ---- coalesced stores (256 threads): h as float4, hb as uint4 (8 bf16) ----
#pragma unroll
    for (int j = 0; j < 2; ++j) {
        int p = tid + j * 256;        // 0..511
        int row = p >> 5;
        int c4 = p & 31;
        float4 vv = *(const float4*)&ldsf[row * LDS_FSTRIDE + c4 * 4];
        *(float4*)&h[(size_t)(m0 + row) * 128 + c4 * 4] = vv;
    }
    {
        int p = tid;                  // 0..255
        int row = p >> 4;
        int c8 = p & 15;
        float4 va = *(const float4*)&ldsf[row * LDS_FSTRIDE + c8 * 8];
        float4 vb = *(const float4*)&ldsf[row * LDS_FSTRIDE + c8 * 8 + 4];
        uint4 ou;
        ou.x = (unsigned)f2bf(va.x) | ((unsigned)f2bf(va.y) << 16);
        ou.y = (unsigned)f2bf(va.z) | ((unsigned)f2bf(va.w) << 16);
        ou.z = (unsigned)f2bf(vb.x) | ((unsigned)f2bf(vb.y) << 16);
        ou.w = (unsigned)f2bf(vb.z) | ((unsigned)f2bf(vb.w) << 16);
        *(uint4*)&hb[(size_t)(m0 + row) * 128 + c8 * 8] = ou;
    }
}

// ---------------- attention aggregation --------------------------------------------
// One WAVE per dst node. 4 edge-groups x 16 lanes; lane covers 8 dims (sub = lane&15).
// Q bf16 [N,128]; K/V fp8-e4m3 packed [N,256B] -> ONE uint4 gather per edge per lane.
// Main loop batched 4-DEEP. DIRECT exp2 (no online max) — matches the reference,
// which computes alpha = exp(score) with no max subtraction; removes the fmax tree,
// compare/rescale branch, and max-merge (kernel was VALU-bound at 77% busy).
// u/c1 pre-scaled by isq*log2e so exp2 is usable directly.
__global__ __launch_bounds__(64) void agg_kernel(
    const ushort_t* __restrict__ Q, const unsigned char* __restrict__ KV,
    const int* __restrict__ rowstart, const unsigned int* __restrict__ edges,
    const float* __restrict__ u, const float* __restrict__ c1,
    ushort_t* __restrict__ hout) {
    const int lane = threadIdx.x & 63;
    const int v = blockIdx.x;
    const int sub = lane & 15;
    const int grp = lane >> 4;

    // Q dims 8sub..+7 (uint4 = 8 bf16)
    uint4 qu = *(const uint4*)(Q + (size_t)v * 128 + sub * 8);
    float q0 = lo16(qu.x), q1 = hi16(qu.x), q2 = lo16(qu.y), q3 = hi16(qu.y);
    float q4 = lo16(qu.z), q5 = hi16(qu.z), q6 = lo16(qu.w), q7 = hi16(qu.w);
    float4 uva = *(const float4*)(u + sub * 8);
    float4 uvb = *(const float4*)(u + sub * 8 + 4);
    float4 cva = *(const float4*)(c1 + sub * 8);
    float4 cvb = *(const float4*)(c1 + sub * 8 + 4);

    float sA[8] = {0.f, 0.f, 0.f, 0.f, 0.f, 0.f, 0.f, 0.f};
    float o[8] = {0.f, 0.f, 0.f, 0.f, 0.f, 0.f, 0.f, 0.f};

    const int start = rowstart[v];
    const int deg = rowstart[v + 1] - start;
    const int nfull = deg >> 2;
    const unsigned int* ep = edges + start + grp;

// compute body consuming a pre-loaded edge word + KV vector (no max tracking)
#define AGG_COMPUTE(PE, KVv, MASKED, VALID)                                      \
    {                                                                            \
        float ef_ = __uint_as_float((PE) & 0xFFFF0000u);                         \
        float2v k01 = __builtin_amdgcn_cvt_pk_f32_fp8((KVv).x, false);           \
        float2v k23 = __builtin_amdgcn_cvt_pk_f32_fp8((KVv).x, true);            \
        float2v k45 = __builtin_amdgcn_cvt_pk_f32_fp8((KVv).y, false);           \
        float2v k67 = __builtin_amdgcn_cvt_pk_f32_fp8((KVv).y, true);            \
        float p_ = k01[0] * q0;                                                  \
        p_ = fmaf(k01[1], q1, p_);                                               \
        p_ = fmaf(k23[0], q2, p_);                                               \
        p_ = fmaf(k23[1], q3, p_);                                               \
        p_ = fmaf(k45[0], q4, p_);                                               \
        p_ = fmaf(k45[1], q5, p_);                                               \
        p_ = fmaf(k67[0], q6, p_);                                               \
        p_ = fmaf(k67[1], q7, p_);                                               \
        p_ += __shfl_xor(p_, 1, 64);                                             \
        p_ += __shfl_xor(p_, 2, 64);                                             \
        float x0 = p_ * fmaf(ef_, uva.x, cva.x);                                 \
        float x1 = p_ * fmaf(ef_, uva.y, cva.y);                                 \
        float x2 = p_ * fmaf(ef_, uva.z, cva.z);                                 \
        float x3 = p_ * fmaf(ef_, uva.w, cva.w);                                 \
        float x4 = p_ * fmaf(ef_, uvb.x, cvb.x);                                 \
        float x5 = p_ * fmaf(ef_, uvb.y, cvb.y);                                 \
        float x6 = p_ * fmaf(ef_, uvb.z, cvb.z);                                 \
        float x7 = p_ * fmaf(ef_, uvb.w, cvb.w);                                 \
        if (MASKED) {                                                            \
            x0 = (VALID) ? x0 : -1.0e38f; x1 = (VALID) ? x1 : -1.0e38f;          \
            x2 = (VALID) ? x2 : -1.0e38f; x3 = (VALID) ? x3 : -1.0e38f;          \
            x4 = (VALID) ? x4 : -1.0e38f; x5 = (VALID) ? x5 : -1.0e38f;          \
            x6 = (VALID) ? x6 : -1.0e38f; x7 = (VALID) ? x7 : -1.0e38f;          \
        }                                                                        \
        float e0 = EXP2(x0), e1 = EXP2(x1);                                      \
        float e2 = EXP2(x2), e3 = EXP2(x3);                                      \
        float e4 = EXP2(x4), e5 = EXP2(x5);                                      \
        float e6 = EXP2(x6), e7 = EXP2(x7);                                      \
        sA[0] += e0; sA[1] += e1; sA[2] += e2; sA[3] += e3;                      \
        sA[4] += e4; sA[5] += e5; sA[6] += e6; sA[7] += e7;                      \
        float2v v01 = __builtin_amdgcn_cvt_pk_f32_fp8((KVv).z, false);           \
        float2v v23 = __builtin_amdgcn_cvt_pk_f32_fp8((KVv).z, true);            \
        float2v v45 = __builtin_amdgcn_cvt_pk_f32_fp8((KVv).w, false);           \
        float2v v67 = __builtin_amdgcn_cvt_pk_f32_fp8((KVv).w, true);            \
        o[0] = fmaf(v01[0], e0, o[0]);                                           \
        o[1] = fmaf(v01[1], e1, o[1]);                                           \
        o[2] = fmaf(v23[0], e2, o[2]);                                           \
        o[3] = fmaf(v23[1], e3, o[3]);                                           \
        o[4] = fmaf(v45[0], e4, o[4]);                                           \
        o[5] = fmaf(v45[1], e5, o[5]);                                           \
        o[6] = fmaf(v67[0], e6, o[6]);                                           \
        o[7] = fmaf(v67[1], e7, o[7]);                                           \
    }

    int it = 0;
    for (; it + 4 <= nfull; it += 4) {
        // batch: issue all 4 edge words + all 4 KV gathers before any compute
        unsigned int pe0 = ep[4 * it];
        unsigned int pe1 = ep[4 * it + 4];
        unsigned int pe2 = ep[4 * it + 8];
        unsigned int pe3 = ep[4 * it + 12];
        uint4 kv0 = *(const uint4*)(KV + (size_t)(pe0 & 0xFFFFu) * 256 + sub * 16);
        uint4 kv1 = *(const uint4*)(KV + (size_t)(pe1 & 0xFFFFu) * 256 + sub * 16);
        uint4 kv2 = *(const uint4*)(KV + (size_t)(pe2 & 0xFFFFu) * 256 + sub * 16);
        uint4 kv3 = *(const uint4*)(KV + (size_t)(pe3 & 0xFFFFu) * 256 + sub * 16);
        AGG_COMPUTE(pe0, kv0, false, true)
        AGG_COMPUTE(pe1, kv1, false, true)
        AGG_COMPUTE(pe2, kv2, false, true)
        AGG_COMPUTE(pe3, kv3, false, true)
    }
    if (it + 2 <= nfull) {
        unsigned int pe0 = ep[4 * it];
        unsigned int pe1 = ep[4 * it + 4];
        uint4 kv0 = *(const uint4*)(KV + (size_t)(pe0 & 0xFFFFu) * 256 + sub * 16);
        uint4 kv1 = *(const uint4*)(KV + (size_t)(pe1 & 0xFFFFu) * 256 + sub * 16);
        AGG_COMPUTE(pe0, kv0, false, true)
        AGG_COMPUTE(pe1, kv1, false, true)
        it += 2;
    }
    if (it < nfull) {
        unsigned int pe0 = ep[4 * it];
        uint4 kv0 = *(const uint4*)(KV + (size_t)(pe0 & 0xFFFFu) * 256 + sub * 16);
        AGG_COMPUTE(pe0, kv0, false, true)
    }
    const int rem = deg & 3;
    if (rem) {
        bool valid = grp < rem;
        unsigned int pe = valid ? ep[4 * nfull] : edges[start];
        uint4 kv = *(const uint4*)(KV + (size_t)(pe & 0xFFFFu) * 256 + sub * 16);
        AGG_COMPUTE(pe, kv, true, valid)
    }
#undef AGG_COMPUTE

    // merge the 4 edge-groups (partners lane^16, lane^32 hold the same dims)
#pragma unroll
    for (int mask = 16; mask <= 32; mask <<= 1) {
#pragma unroll
        for (int j = 0; j < 8; ++j) {
            sA[j] += __shfl_xor(sA[j], mask, 64);
            o[j] += __shfl_xor(o[j], mask, 64);
        }
    }

    if (grp == 0) {
        // ref: h_out = num / max(Z, 1e-6)
        uint4 ou;
        unsigned int w0, w1;
        float z;
        z = fmaxf(sA[0], 1e-6f); w0 = f2bf(o[0] / z);
        z = fmaxf(sA[1], 1e-6f); w1 = f2bf(o[1] / z);
        ou.x = w0 | (w1 << 16);
        z = fmaxf(sA[2], 1e-6f); w0 = f2bf(o[2] / z);
        z = fmaxf(sA[3], 1e-6f); w1 = f2bf(o[3] / z);
        ou.y = w0 | (w1 << 16);
        z = fmaxf(sA[4], 1e-6f); w0 = f2bf(o[4] / z);
        z = fmaxf(sA[5], 1e-6f); w1 = f2bf(o[5] / z);
        ou.z = w0 | (w1 << 16);
        z = fmaxf(sA[6], 1e-6f); w0 = f2bf(o[6] / z);
        z = fmaxf(sA[7], 1e-6f); w1 = f2bf(o[7] / z);
        ou.w = w0 | (w1 << 16);
        *(uint4*)(hout + (size_t)v * 128 + sub * 8) = ou;
    }
}

// ---------------- mean over nodes ------------------------------------------------------
__global__ void mean_part_kernel(const float* __restrict__ h, float* __restrict__ macc) {
    __shared__ float s[256];
    int t = threadIdx.x;
    int col = t & 127;
    int half = t >> 7;
    int r0 = blockIdx.x * 256;
    float acc = 0.f;
    for (int r = half; r < 256; r += 2) acc += h[(size_t)(r0 + r) * 128 + col];
    s[t] = acc;
    __syncthreads();
    if (t < 128) atomicAdd(&macc[t], s[t] + s[t + 128]);
}

// ---------------- finalize -------------------------------------------------------------
__global__ void finalize_kernel(const float* __restrict__ macc, void* __restrict__ out,
                                const int* __restrict__ flag) {
    int t = threadIdx.x;
    float v = macc[t] * (1.f / (float)N_NODES);
    if (*flag)
        ((ushort_t*)out)[t] = f2bf(v);
    else
        ((float*)out)[t] = v;
}

// ---------------------------------------------------------------------------------------
extern "C" void kernel_launch(void* const* d_in, const int* in_sizes, int n_in,
                              void* d_out, int out_size, void* d_ws, size_t ws_size,
                              hipStream_t stream) {
    const int* src = (const int*)d_in[3];
    const int* dst = (const int*)d_in[4];

    char* w = (char*)d_ws;
    const size_t MB = 1u << 20;
    float* h        = (float*)(w);               // 16 MB [N,128] f32
    ushort_t* hb    = (ushort_t*)(w + 16 * MB);  //  8 MB [N,128] bf16 (also = HOUT)
    ushort_t* Qh    = (ushort_t*)(w + 24 * MB);  //  8 MB [N,128] bf16
    unsigned char* KVf8 = (unsigned char*)(w + 32 * MB);  // 8 MB [N,256B] fp8 K|V packed
    char* aux       = w + 48 * MB;
    int* deg        = (int*)(aux);               // 128 KB
    int* rowstart   = (int*)(aux + 0x40000);     // 128 KB + 4
    int* cursor     = (int*)(aux + 0x80000);     // 128 KB
    unsigned int* edges = (unsigned int*)(aux + 0xC0000);          // 2 MB
    float* ubuf     = (float*)(aux + 0xC0000 + 2 * MB);            // 3*128 f32
    float* cbuf     = ubuf + 3 * 128;
    float* macc     = cbuf + 3 * 128;            // 128 f32
    int* flag       = (int*)(macc + 128);
    float* conv     = (float*)(aux + 0xC0000 + 2 * MB + 4096);     // 40 KB f32
    ushort_t* swz   = (ushort_t*)((char*)conv + CONV_TOTAL * 4);   // 784 KB bf16

    detect_kernel<<<1, 256, 0, stream>>>((const unsigned int*)d_in[5], flag);

    ConvArgs ca;
    ca.src[0] = d_in[5];    // W_node
    ca.src[1] = d_in[6];    // b_node
    ca.src[2] = d_in[7];    // W_pos
    ca.src[3] = d_in[8];    // b_pos
    ca.src[4] = d_in[9];    // W_edge
    ca.src[5] = d_in[10];   // b_edge
    ca.src[6] = d_in[16];   // b_lin
    ca.src[7] = d_in[17];   // g1
    ca.src[8] = d_in[18];   // be1
    ca.src[9] = d_in[20];   // bf1
    ca.src[10] = d_in[22];  // bf2
    ca.src[11] = d_in[23];  // g2
    ca.src[12] = d_in[24];  // be2
    // convert also zeros deg (replaces hipMemsetAsync node)
    convert_kernel<<<(CONV_TOTAL + 255) / 256, 256, 0, stream>>>(ca, flag, conv, deg);

    // swz (192 blocks) + fused uc (3 blocks) + input-proj records (4 blocks)
    swz_kernel<<<192 + 3 + 4, 256, 0, stream>>>(
        d_in[11], d_in[12], d_in[13], d_in[15], d_in[19], d_in[21],
        d_in[14], d_in[9], d_in[10], d_in[5], d_in[7], flag, swz, ubuf, cbuf);

    // input projection via MFMA + fused degree histogram
    ip_gemm<<<N_NODES / 64, 256, 0, stream>>>(d_in[0], d_in[1], conv, flag, dst, deg,
                                              swz + (size_t)REC_WNP * 512, h, hb);
    // scan also zeros macc (replaces hipMemsetAsync node)
    scan_kernel<<<1, 1024, 0, stream>>>(deg, rowstart, cursor, macc);
    scatter_kernel<<<N_EDGES / 256, 256, 0, stream>>>(src, dst, d_in[2], flag, cursor,
                                                      edges);

    for (int i = 0; i < 3; ++i) {
        const ushort_t* swzQKV = swz + (size_t)REC_QKV(i) * 512;
        const ushort_t* swzWL  = swz + (size_t)REC_WLIN(i) * 512;
        const ushort_t* swzF1  = swz + (size_t)REC_WF1(i) * 512;
        const ushort_t* swzF2  = swz + (size_t)REC_WF2(i) * 512;

        // Q bf16 + K/V fp8 packed (3-segment, 4-wave blocks)
        qkv_gemm<4><<<dim3(N_NODES / 64, 3), 256, 0, stream>>>(hb, swzQKV, Qh, KVf8);

        // attention -> hb (= HOUT) [N,128] bf16 (direct-exp2, 4-deep batched gathers)
        agg_kernel<<<N_NODES, 64, 0, stream>>>(Qh, KVf8, rowstart, edges,
                                               ubuf + i * 128, cbuf + i * 128, hb);

        // fused layer tail, FOUR waves per 16-row tile (grid 2048 x 256 thr)
        ffn_kernel<<<N_NODES / 16, 256, 0, stream>>>(
            hb, swzWL, swzF1, swzF2,
            conv + OFF_BLIN + i * 128, conv + OFF_G1 + i * 128, conv + OFF_BE1 + i * 128,
            conv + OFF_BF1 + i * 256,
            conv + OFF_BF2 + i * 128, conv + OFF_G2 + i * 128, conv + OFF_BE2 + i * 128,
            h, hb);
    }

    mean_part_kernel<<<N_NODES / 256, 256, 0, stream>>>(h, macc);
    finalize_kernel<<<1, 128, 0, stream>>>(macc, d_out, flag);
}

// Round 12
// 428.759 us; speedup vs baseline: 1.3160x; 1.0003x over previous
//
#include <hip/hip_runtime.h>
#include <hip/hip_bf16.h>

#define N_NODES 32768
#define N_EDGES 524288
#define LN_EPS 1e-5f

typedef unsigned short ushort_t;
typedef __attribute__((ext_vector_type(8))) short short8v;
typedef __attribute__((ext_vector_type(4))) float float4v;
typedef __attribute__((ext_vector_type(2))) float float2v;

__device__ __forceinline__ float bf2f(ushort_t u) {
    return __uint_as_float(((unsigned int)u) << 16);
}
__device__ __forceinline__ ushort_t f2bf(float f) {
    unsigned int u = __float_as_uint(f);
    unsigned int r = (u + 0x7FFFu + ((u >> 16) & 1u)) >> 16;
    return (ushort_t)r;
}
__device__ __forceinline__ float lo16(unsigned int x) { return __uint_as_float(x << 16); }
__device__ __forceinline__ float hi16(unsigned int x) { return __uint_as_float(x & 0xFFFF0000u); }

#if __has_builtin(__builtin_amdgcn_exp2f)
#define EXP2(x) __builtin_amdgcn_exp2f(x)
#else
#define EXP2(x) exp2f(x)
#endif

// compact f32 conv region: only params consumed as f32 (biases, LN, input-proj weights)
#define OFF_WNODE 0
#define OFF_BNODE 5632
#define OFF_WPOS  5760
#define OFF_BPOS  6784
#define OFF_WEDGE 6912
#define OFF_BEDGE 7040
#define OFF_BLIN  7168
#define OFF_G1    7552
#define OFF_BE1   7936
#define OFF_BF1   8320
#define OFF_BF2   9088
#define OFF_G2    9472
#define OFF_BE2   9856
#define CONV_TOTAL 10240

// swizzled-B record bases (records of 512 ushorts = 64 lanes x 8 bf16)
#define REC_QKV(i)  ((i) * 96)          // 24 ct x 4 kb
#define REC_WLIN(i) (288 + (i) * 32)    // 8 ct x 4 kb
#define REC_WF1(i)  (384 + (i) * 64)    // 16 ct x 4 kb
#define REC_WF2(i)  (576 + (i) * 64)    // 8 ct x 8 kb
#define REC_WNP     768                 // input-proj [Wn;Wp;0] 8 ct x 2 kb
#define REC_TOTAL   784

#define LDS_STRIDE 264   // ushorts per LDS row (256 + 8 pad)
#define LDS_FSTRIDE 132  // floats per LDS row (same byte footprint)

// ---------------- dtype detection: bf16 data has exponent-like bits at [15:8] ---------
__global__ void detect_kernel(const unsigned int* __restrict__ wn, int* __restrict__ flag) {
    __shared__ int s[256];
    int t = threadIdx.x;
    int cnt = 0;
    for (int i = t; i < 2816; i += 256) {
        unsigned int b = (wn[i] >> 8) & 0x7F;
        cnt += (b >= 0x3A && b <= 0x40) ? 1 : 0;
    }
    s[t] = cnt;
    __syncthreads();
    for (int off = 128; off > 0; off >>= 1) {
        if (t < off) s[t] += s[t + off];
        __syncthreads();
    }
    if (t == 0) *flag = (s[0] > 1408) ? 1 : 0;   // 1 = bf16, 0 = f32
}

// ---------------- canonicalize small param buffers to f32 scratch ---------------------
// Also zeros the degree histogram (replaces a hipMemsetAsync dispatch node).
struct ConvArgs { const void* src[13]; };

__global__ void convert_kernel(ConvArgs a, const int* __restrict__ flag,
                               float* __restrict__ dst, int* __restrict__ deg) {
    int gid = blockIdx.x * 256 + threadIdx.x;
    for (int i = gid; i < N_NODES; i += CONV_TOTAL) deg[i] = 0;   // fused deg-zero
    if (gid >= CONV_TOTAL) return;
    const int off[14] = {OFF_WNODE, OFF_BNODE, OFF_WPOS, OFF_BPOS, OFF_WEDGE, OFF_BEDGE,
                         OFF_BLIN, OFF_G1, OFF_BE1, OFF_BF1, OFF_BF2, OFF_G2, OFF_BE2,
                         CONV_TOTAL};
    int s = 0;
#pragma unroll
    for (int i = 1; i < 13; ++i) s += (gid >= off[i]) ? 1 : 0;
    int local = gid - off[s];
    if (*flag)
        dst[gid] = bf2f(((const ushort_t*)a.src[s])[local]);
    else
        dst[gid] = ((const float*)a.src[s])[local];
}

// ---------------- swizzle GEMM weights into MFMA B-fragment records (raw sources) -----
// record(ct,kb): lane l holds W[kb*32 + (l>>4)*8 + j][ct*16 + (l&15)], j=0..7
// blocks 192..194 compute u/c1 (fused uc); blocks 195..198 build input-proj records.
__global__ void swz_kernel(const void* __restrict__ Wq, const void* __restrict__ Wk,
                           const void* __restrict__ Wv, const void* __restrict__ Wlin,
                           const void* __restrict__ Wf1, const void* __restrict__ Wf2,
                           const void* __restrict__ We, const void* __restrict__ wedge,
                           const void* __restrict__ bedge,
                           const void* __restrict__ Wn_, const void* __restrict__ Wp_,
                           const int* __restrict__ flag,
                           ushort_t* __restrict__ swz,
                           float* __restrict__ u, float* __restrict__ c1) {
    const bool isbf = (*flag != 0);
    if (blockIdx.x >= 195) {
        // input-proj B records: W[k][n], k = 0..43 Wn, 44..51 Wp, 52..63 zero pad
        int idx = (blockIdx.x - 195) * 256 + threadIdx.x;   // 0..1023
        int rec16 = idx >> 6;                               // 0..15
        int lane = idx & 63;
        int ct = rec16 >> 1, kb = rec16 & 1;
        int col = lane & 15, quad = lane >> 4;
        int n = ct * 16 + col;
        ushort_t v[8];
#pragma unroll
        for (int j = 0; j < 8; ++j) {
            int k = kb * 32 + quad * 8 + j;
            if (isbf) {
                v[j] = (k < 44) ? ((const ushort_t*)Wn_)[k * 128 + n]
                     : ((k < 52) ? ((const ushort_t*)Wp_)[(k - 44) * 128 + n]
                                 : (ushort_t)0);
            } else {
                float f = (k < 44) ? ((const float*)Wn_)[k * 128 + n]
                        : ((k < 52) ? ((const float*)Wp_)[(k - 44) * 128 + n] : 0.f);
                v[j] = f2bf(f);
            }
        }
        ushort_t* o = swz + (size_t)(REC_WNP + rec16) * 512 + lane * 8;
#pragma unroll
        for (int j = 0; j < 8; ++j) o[j] = v[j];
        return;
    }
    if (blockIdx.x >= 192) {
        // fused uc: pre-scaled by (1/sqrt(dk))*log2(e); agg works in log2 domain
        int l = blockIdx.x - 192;
        int d = threadIdx.x;
        if (d >= 128) return;
        float uu = 0.f, cc = 0.f;
        if (isbf) {
            const ushort_t* Wl = (const ushort_t*)We + (size_t)l * 16384;
            const ushort_t* we_ = (const ushort_t*)wedge;
            const ushort_t* be_ = (const ushort_t*)bedge;
#pragma unroll 4
            for (int k = 0; k < 128; ++k) {
                float w = bf2f(Wl[k * 128 + d]);
                uu = fmaf(bf2f(we_[k]), w, uu);
                cc = fmaf(bf2f(be_[k]), w, cc);
            }
        } else {
            const float* Wl = (const float*)We + (size_t)l * 16384;
            const float* we_ = (const float*)wedge;
            const float* be_ = (const float*)bedge;
#pragma unroll 4
            for (int k = 0; k < 128; ++k) {
                float w = Wl[k * 128 + d];
                uu = fmaf(we_[k], w, uu);
                cc = fmaf(be_[k], w, cc);
            }
        }
        const float scale = 0.17677669529663687f * 1.4426950408889634f;  // isq * log2(e)
        u[l * 128 + d] = uu * scale;
        c1[l * 128 + d] = (1.f + cc) * scale;
        return;
    }
    int gid = blockIdx.x * 256 + threadIdx.x;
    int lane = gid & 63;
    int rec = gid >> 6;
    int col = lane & 15, quad = lane >> 4;
    const void* src;
    size_t base;
    int ct, kb, OC;
    if (rec < 288) {                       // QKV: 3 layers x 24ct x 4kb
        int layer = rec / 96, r2 = rec % 96;
        ct = r2 >> 2; kb = r2 & 3;
        int seg = ct >> 3;                 // 0=Wq 1=Wk 2=Wv
        src = (seg == 0) ? Wq : ((seg == 1) ? Wk : Wv);
        base = (size_t)layer * 16384; OC = 128; ct &= 7;
    } else if (rec < 384) {                // W_lin
        int r = rec - 288, layer = r / 32, r2 = r % 32;
        ct = r2 >> 2; kb = r2 & 3;
        src = Wlin; base = (size_t)layer * 16384; OC = 128;
    } else if (rec < 576) {                // Wf1 (OC=256)
        int r = rec - 384, layer = r / 64, r2 = r % 64;
        ct = r2 >> 2; kb = r2 & 3;
        src = Wf1; base = (size_t)layer * 32768; OC = 256;
    } else {                               // Wf2 (K=256)
        int r = rec - 576, layer = r / 64, r2 = r % 64;
        ct = r2 >> 3; kb = r2 & 7;
        src = Wf2; base = (size_t)layer * 32768; OC = 128;
    }
    int n = ct * 16 + col;
    ushort_t v[8];
    if (isbf) {
        const ushort_t* s16 = (const ushort_t*)src + base;
#pragma unroll
        for (int j = 0; j < 8; ++j) v[j] = s16[(size_t)(kb * 32 + quad * 8 + j) * OC + n];
    } else {
        const float* s32 = (const float*)src + base;
#pragma unroll
        for (int j = 0; j < 8; ++j) v[j] = f2bf(s32[(size_t)(kb * 32 + quad * 8 + j) * OC + n]);
    }
    ushort_t* o = swz + (size_t)rec * 512 + lane * 8;
#pragma unroll
    for (int j = 0; j < 8; ++j) o[j] = v[j];
}

// ---------------- input projection via MFMA: h = [feats|lap|0] @ [Wn;Wp;0] + biases ---
// Grid N/64 blocks x 256 thr (4 waves); A tile staged bf16 in LDS; B from swz records.
// Fused degree histogram (4 strided passes). Outputs h f32 + hb bf16.
__global__ __launch_bounds__(256) void ip_gemm(
    const void* __restrict__ feats, const void* __restrict__ lap,
    const float* __restrict__ conv, const int* __restrict__ flag,
    const int* __restrict__ dstidx, int* __restrict__ deg,
    const ushort_t* __restrict__ Bswz,   // = swz + REC_WNP*512
    float* __restrict__ h, ushort_t* __restrict__ hb) {
    __shared__ __align__(16) ushort_t As[64 * 72];   // 64 rows x K=64, stride 72
    const int tid = threadIdx.x;

    // fused histogram: 512*256 threads x 4 edges
    for (int e = blockIdx.x * 256 + tid; e < N_EDGES; e += (N_NODES / 64) * 256)
        atomicAdd(&deg[dstidx[e]], 1);

    const bool isbf = (*flag != 0);
    const int r = tid >> 2;          // 0..63 (tile row)
    const int t4 = tid & 3;          // 16-col chunk
    const int m0g = blockIdx.x * 64;
    {
        const int row = m0g + r;
        ushort_t tmp[16];
        if (isbf) {
            const ushort_t* frow = (const ushort_t*)feats + (size_t)row * 44;
            const ushort_t* prow = (const ushort_t*)lap + (size_t)row * 8;
#pragma unroll
            for (int j = 0; j < 16; ++j) {
                int k = t4 * 16 + j;
                tmp[j] = (k < 44) ? frow[k]
                       : ((k < 52) ? prow[k - 44] : (ushort_t)0);
            }
        } else {
            const float* frow = (const float*)feats + (size_t)row * 44;
            const float* prow = (const float*)lap + (size_t)row * 8;
#pragma unroll
            for (int j = 0; j < 16; ++j) {
                int k = t4 * 16 + j;
                float v = (k < 44) ? frow[k] : ((k < 52) ? prow[k - 44] : 0.f);
                tmp[j] = f2bf(v);
            }
        }
#pragma unroll
        for (int j = 0; j < 16; ++j) As[r * 72 + t4 * 16 + j] = tmp[j];
    }
    __syncthreads();

    const int wv = tid >> 6, lane = tid & 63;
    const int col = lane & 15, quad = lane >> 4;
    const int m0 = wv * 16;
    short8v a0 = *(const short8v*)&As[(m0 + col) * 72 + quad * 8];
    short8v a1 = *(const short8v*)&As[(m0 + col) * 72 + 32 + quad * 8];

    float4v acc[8];
#pragma unroll
    for (int ct = 0; ct < 8; ++ct) {
        short8v b0 = *(const short8v*)(Bswz + (size_t)(ct * 2 + 0) * 512 + lane * 8);
        short8v b1 = *(const short8v*)(Bswz + (size_t)(ct * 2 + 1) * 512 + lane * 8);
        float4v a = (float4v){0.f, 0.f, 0.f, 0.f};
        a = __builtin_amdgcn_mfma_f32_16x16x32_bf16(a0, b0, a, 0, 0, 0);
        a = __builtin_amdgcn_mfma_f32_16x16x32_bf16(a1, b1, a, 0, 0, 0);
        acc[ct] = a;
    }

    const int rowb = m0g + m0 + quad * 4;
#pragma unroll
    for (int ct = 0; ct < 8; ++ct) {
        int j = ct * 16 + col;
        float bias = conv[OFF_BNODE + j] + conv[OFF_BPOS + j];
#pragma unroll
        for (int rr = 0; rr < 4; ++rr) {
            float o = acc[ct][rr] + bias;
            h[(size_t)(rowb + rr) * 128 + j] = o;
            hb[(size_t)(rowb + rr) * 128 + j] = f2bf(o);
        }
    }
}

// ---------------- CSR build ------------------------------------------------------------
// Also zeros macc (replaces a hipMemsetAsync dispatch node; mean_part runs much later).
__global__ void scan_kernel(const int* __restrict__ deg, int* __restrict__ rowstart,
                            int* __restrict__ cursor, float* __restrict__ macc) {
    __shared__ int lds[1024];
    int t = threadIdx.x;
    if (t < 128) macc[t] = 0.f;                 // fused macc-zero
    int base = t * 32;
    int v[32];
    int csum = 0;
#pragma unroll
    for (int j = 0; j < 8; ++j) {               // coalesced int4 loads
        int4 x = *(const int4*)(deg + base + j * 4);
        v[j * 4 + 0] = x.x; v[j * 4 + 1] = x.y;
        v[j * 4 + 2] = x.z; v[j * 4 + 3] = x.w;
        csum += x.x + x.y + x.z + x.w;
    }
    lds[t] = csum;
    __syncthreads();
    for (int off = 1; off < 1024; off <<= 1) {
        int x = (t >= off) ? lds[t - off] : 0;
        __syncthreads();
        lds[t] += x;
        __syncthreads();
    }
    int excl = lds[t] - csum;
    int running = excl;
#pragma unroll
    for (int j = 0; j < 8; ++j) {
        int4 w;
        w.x = running; running += v[j * 4 + 0];
        w.y = running; running += v[j * 4 + 1];
        w.z = running; running += v[j * 4 + 2];
        w.w = running; running += v[j * 4 + 3];
        *(int4*)(rowstart + base + j * 4) = w;
        *(int4*)(cursor + base + j * 4) = w;
    }
    if (t == 1023) rowstart[N_NODES] = running;
}

__global__ void scatter_kernel(const int* __restrict__ src, const int* __restrict__ dst,
                               const void* __restrict__ ef, const int* __restrict__ flag,
                               int* __restrict__ cursor,
                               unsigned int* __restrict__ edges) {
    int e = blockIdx.x * 256 + threadIdx.x;
    if (e < N_EDGES) {
        ushort_t efb = (*flag != 0) ? ((const ushort_t*)ef)[e]
                                    : f2bf(((const float*)ef)[e]);
        int d = dst[e];
        int p = atomicAdd(&cursor[d], 1);
        edges[p] = (unsigned int)src[e] | ((unsigned int)efb << 16);
    }
}

// ---------------- MFMA GEMM (QKV): seg 0 -> Q bf16 [N,128];
//                  segs 1/2 -> K/V packed fp8-e4m3 into KV [N,256B]
//                  (per 8-dim block b: bytes 16b..16b+7 = K dims, +8..+15 = V dims).
// Block: 256 thr = 4 waves; wave = 16 rows x 128 cols; grid = (M/64, 3 segs).
template <int KB>
__global__ __launch_bounds__(256) void qkv_gemm(
    const ushort_t* __restrict__ A,
    const ushort_t* __restrict__ Bswz,
    ushort_t* __restrict__ outQ,
    unsigned char* __restrict__ outKV) {
    const int K = KB * 32;
    const int tid = threadIdx.x;
    const int wv = tid >> 6, lane = tid & 63;
    const int col = lane & 15, quad = lane >> 4;
    const int m0 = blockIdx.x * 64 + wv * 16;
    const int ct0 = blockIdx.y * 8;

    float4v acc[8];
#pragma unroll
    for (int ct = 0; ct < 8; ++ct) acc[ct] = (float4v){0.f, 0.f, 0.f, 0.f};

    const ushort_t* Ap = A + (size_t)(m0 + col) * K + quad * 8;
    const ushort_t* Bp = Bswz + (size_t)ct0 * KB * 512 + lane * 8;

#pragma unroll
    for (int kb = 0; kb < KB; ++kb) {
        short8v a = *(const short8v*)(Ap + kb * 32);
#pragma unroll
        for (int ct = 0; ct < 8; ++ct) {
            short8v b = *(const short8v*)(Bp + (size_t)(ct * KB + kb) * 512);
            acc[ct] = __builtin_amdgcn_mfma_f32_16x16x32_bf16(a, b, acc[ct], 0, 0, 0);
        }
    }

    const int rowb = m0 + quad * 4;
    const int seg = blockIdx.y;
    if (seg == 0) {
#pragma unroll
        for (int ct = 0; ct < 8; ++ct) {
            int j = ct * 16 + col;
#pragma unroll
            for (int r = 0; r < 4; ++r)
                outQ[(size_t)(rowb + r) * 128 + j] = f2bf(acc[ct][r]);
        }
    } else {
        const int vofs = (seg == 2) ? 8 : 0;
#pragma unroll
        for (int ct = 0; ct < 8; ++ct) {
            int j = ct * 16 + col;
            int off = ((j >> 3) * 16) + (j & 7) + vofs;
#pragma unroll
            for (int r = 0; r < 4; ++r) {
                float a = acc[ct][r];
                float b = __shfl_xor(a, 1, 64);   // partner col (j^1) same ct,r
                if ((col & 1) == 0) {
                    unsigned short pk = (unsigned short)
                        __builtin_amdgcn_cvt_pk_fp8_f32(a, b, 0, false);
                    *(ushort_t*)(outKV + (size_t)(rowb + r) * 256 + off) = pk;
                }
            }
        }
    }
}

// ---------------- fused layer tail: h = LN2(h' + relu(h'@Wf1+b)@Wf2+b2),
//                  h' = LN1(h + HOUT@WL+bl). FOUR waves per 16-row tile (grid N/16,
//                  256 thr): wave wv owns a quarter of the output columns of each
//                  GEMM; LN row-stats completed via a 4-way LDS exchange. Same total
//                  work as the 1-wave version, 4x resident waves (grid-limited).
__global__ __launch_bounds__(256, 2) void ffn_kernel(
    const ushort_t* __restrict__ HOUT,   // [N,128] bf16 (= hb, attention out)
    const ushort_t* __restrict__ BWL,    // swz W_lin  (8ct x 4kb)
    const ushort_t* __restrict__ BF1,    // swz Wf1    (16ct x 4kb)
    const ushort_t* __restrict__ BF2,    // swz Wf2    (8ct x 8kb)
    const float* __restrict__ bl,
    const float* __restrict__ g1v, const float* __restrict__ be1v,
    const float* __restrict__ bf1v,
    const float* __restrict__ bf2v,
    const float* __restrict__ g2v, const float* __restrict__ be2v,
    float* __restrict__ h,               // [N,128] f32 in-out (residual -> final)
    ushort_t* __restrict__ hb) {         // [N,128] bf16 out
    __shared__ __align__(16) char ldsraw[16 * 528];   // 8448 B, dual-view
    __shared__ float lnx[4][16][2];      // cross-wave LN partials [wave][row][sum,sumsq]
    ushort_t* ldsu = (ushort_t*)ldsraw;  // stride LDS_STRIDE (264)
    float* ldsf = (float*)ldsraw;        // stride LDS_FSTRIDE (132)
    const int tid = threadIdx.x;
    const int wv = tid >> 6;             // 0..3 (column-quarter owner)
    const int lane = tid & 63;
    const int col = lane & 15, quad = lane >> 4;
    const int m0 = blockIdx.x * 16;
    const int rowb = m0 + quad * 4;          // global row base (C-layout)
    const int lrowc = quad * 4;              // LDS row base for C-layout stores
    const int lrowa = col;                   // LDS row for A-fragment reads
    const int ct0 = wv * 2;                  // GEMM1/GEMM3 ct base (2 of 8)

    // ---- GEMM1: HOUT @ W_lin (this wave: cts ct0..ct0+1) ----
    float4v acc[2];
#pragma unroll
    for (int c = 0; c < 2; ++c) acc[c] = (float4v){0.f, 0.f, 0.f, 0.f};
    const ushort_t* Ap = HOUT + (size_t)(m0 + col) * 128 + quad * 8;
#pragma unroll
    for (int kb = 0; kb < 4; ++kb) {
        short8v a = *(const short8v*)(Ap + kb * 32);
#pragma unroll
        for (int c = 0; c < 2; ++c) {
            short8v b = *(const short8v*)(BWL + (size_t)((ct0 + c) * 4 + kb) * 512 + lane * 8);
            acc[c] = __builtin_amdgcn_mfma_f32_16x16x32_bf16(a, b, acc[c], 0, 0, 0);
        }
    }

    // ---- LN1 (+bias, +residual h): wave-partial stats then 4-way LDS exchange ----
    float val[2][4], s[4] = {0.f, 0.f, 0.f, 0.f}, ss[4] = {0.f, 0.f, 0.f, 0.f};
#pragma unroll
    for (int c = 0; c < 2; ++c) {
        float bi = bl[(ct0 + c) * 16 + col];
#pragma unroll
        for (int r = 0; r < 4; ++r) {
            float v = acc[c][r] + bi + h[(size_t)(rowb + r) * 128 + (ct0 + c) * 16 + col];
            val[c][r] = v;
            s[r] += v;
            ss[r] += v * v;
        }
    }
#pragma unroll
    for (int mask = 1; mask < 16; mask <<= 1) {
#pragma unroll
        for (int r = 0; r < 4; ++r) {
            s[r] += __shfl_xor(s[r], mask, 64);
            ss[r] += __shfl_xor(ss[r], mask, 64);
        }
    }
    if (col == 0) {
#pragma unroll
        for (int r = 0; r < 4; ++r) {
            lnx[wv][lrowc + r][0] = s[r];
            lnx[wv][lrowc + r][1] = ss[r];
        }
    }
    __syncthreads();
#pragma unroll
    for (int r = 0; r < 4; ++r) {
        float fs = (lnx[0][lrowc + r][0] + lnx[1][lrowc + r][0]) +
                   (lnx[2][lrowc + r][0] + lnx[3][lrowc + r][0]);
        float fss = (lnx[0][lrowc + r][1] + lnx[1][lrowc + r][1]) +
                    (lnx[2][lrowc + r][1] + lnx[3][lrowc + r][1]);
        float mean = fs * (1.f / 128.f);
        float var = fss * (1.f / 128.f) - mean * mean;
        s[r] = mean;
        ss[r] = rsqrtf(var + LN_EPS);
    }
#pragma unroll
    for (int c = 0; c < 2; ++c) {
        float gg = g1v[(ct0 + c) * 16 + col], bb = be1v[(ct0 + c) * 16 + col];
#pragma unroll
        for (int r = 0; r < 4; ++r) {
            float o = (val[c][r] - s[r]) * ss[r] * gg + bb;
            val[c][r] = o;                                       // residual for LN2
            ldsu[(lrowc + r) * LDS_STRIDE + (ct0 + c) * 16 + col] = f2bf(o);
        }
    }
    __syncthreads();

    // ---- A-fragments of h' from LDS (full K) ----
    short8v af[4];
#pragma unroll
    for (int kb = 0; kb < 4; ++kb)
        af[kb] = *(const short8v*)&ldsu[lrowa * LDS_STRIDE + kb * 32 + quad * 8];

    // ---- GEMM2: h' @ Wf1 (OC=256; this wave: cts wv*4..wv*4+3) ----
    float4v acc2[4];
#pragma unroll
    for (int c = 0; c < 4; ++c) acc2[c] = (float4v){0.f, 0.f, 0.f, 0.f};
#pragma unroll
    for (int kb = 0; kb < 4; ++kb) {
#pragma unroll
        for (int c = 0; c < 4; ++c) {
            short8v b = *(const short8v*)(BF1 + (size_t)((wv * 4 + c) * 4 + kb) * 512 + lane * 8);
            acc2[c] = __builtin_amdgcn_mfma_f32_16x16x32_bf16(af[kb], b, acc2[c], 0, 0, 0);
        }
    }
    __syncthreads();

    // ---- T = relu(acc2 + bf1) -> LDS (this wave's 4 cts) ----
#pragma unroll
    for (int c = 0; c < 4; ++c) {
        float bi = bf1v[(wv * 4 + c) * 16 + col];
#pragma unroll
        for (int r = 0; r < 4; ++r) {
            float v = fmaxf(acc2[c][r] + bi, 0.f);
            ldsu[(lrowc + r) * LDS_STRIDE + (wv * 4 + c) * 16 + col] = f2bf(v);
        }
    }
    __syncthreads();

    // ---- GEMM3: T @ Wf2 (K=256; this wave: cts ct0..ct0+1) ----
    float4v acc3[2];
#pragma unroll
    for (int c = 0; c < 2; ++c) acc3[c] = (float4v){0.f, 0.f, 0.f, 0.f};
#pragma unroll
    for (int kb = 0; kb < 8; ++kb) {
        short8v a = *(const short8v*)&ldsu[lrowa * LDS_STRIDE + kb * 32 + quad * 8];
#pragma unroll
        for (int c = 0; c < 2; ++c) {
            short8v b = *(const short8v*)(BF2 + (size_t)((ct0 + c) * 8 + kb) * 512 + lane * 8);
            acc3[c] = __builtin_amdgcn_mfma_f32_16x16x32_bf16(a, b, acc3[c], 0, 0, 0);
        }
    }

    // ---- LN2 (+bias, +residual h'): partial stats + 4-way LDS exchange ----
    float s2[4] = {0.f, 0.f, 0.f, 0.f}, ss2[4] = {0.f, 0.f, 0.f, 0.f};
#pragma unroll
    for (int c = 0; c < 2; ++c) {
        float bi = bf2v[(ct0 + c) * 16 + col];
#pragma unroll
        for (int r = 0; r < 4; ++r) {
            float v = acc3[c][r] + bi + val[c][r];
            val[c][r] = v;
            s2[r] += v;
            ss2[r] += v * v;
        }
    }
#pragma unroll
    for (int mask = 1; mask < 16; mask <<= 1) {
#pragma unroll
        for (int r = 0; r < 4; ++r) {
            s2[r] += __shfl_xor(s2[r], mask, 64);
            ss2[r] += __shfl_xor(ss2[r], mask, 64);
        }
    }
    __syncthreads();   // GEMM3 reads of ldsu done; ldsf (alias) free after this point
    if (col == 0) {
#pragma unroll
        for (int r = 0; r < 4; ++r) {
            lnx[wv][lrowc + r][0] = s2[r];
            lnx[wv][lrowc + r][1] = ss2[r];
        }
    }
    __syncthreads();
#pragma unroll
    for (int r = 0; r < 4; ++r) {
        float fs = (lnx[0][lrowc + r][0] + lnx[1][lrowc + r][0]) +
                   (lnx[2][lrowc + r][0] + lnx[3][lrowc + r][0]);
        float fss = (lnx[0][lrowc + r][1] + lnx[1][lrowc + r][1]) +
                    (lnx[2][lrowc + r][1] + lnx[3][lrowc + r][1]);
        float mean = fs * (1.f / 128.f);
        float var = fss * (1.f / 128.f) - mean * mean;
        s2[r] = mean;
        ss2[r] = rsqrtf(var + LN_EPS);
    }
#pragma unroll
    for (int c = 0; c < 2; ++c) {
        float gg = g2v[(ct0 + c) * 16 + col], bb = be2v[(ct0 + c) * 16 + col];
#pragma unroll
        for (int r = 0; r < 4; ++r) {
            float o = (val[c][r] - s2[r]) * ss2[r] * gg + bb;
            ldsf[(lrowc + r) * LDS_FSTRIDE + (ct0 + c) * 16 + col] = o;
        }
    }
    __syncthreads();

    // ---- coalesced stores (256 threads): h as float4, hb as uint4 (8 bf16) ----
#pragma unroll
    for (int j = 0; j < 2; ++j) {
        int p = tid + j * 256;        // 0..511
        int row = p >> 5;
        int c4 = p & 31;
        float4 vv = *(const float4*)&ldsf[row * LDS_FSTRIDE + c4 * 4];
        *(float4*)&h[(size_t)(m0 + row) * 128 + c4 * 4] = vv;
    }
    {
        int p = tid;                  // 0..255
        int row = p >> 4;
        int c8 = p & 15;
        float4 va = *(const float4*)&ldsf[row * LDS_FSTRIDE + c8 * 8];
        float4 vb = *(const float4*)&ldsf[row * LDS_FSTRIDE + c8 * 8 + 4];
        uint4 ou;
        ou.x = (unsigned)f2bf(va.x) | ((unsigned)f2bf(va.y) << 16);
        ou.y = (unsigned)f2bf(va.z) | ((unsigned)f2bf(va.w) << 16);
        ou.z = (unsigned)f2bf(vb.x) | ((unsigned)f2bf(vb.y) << 16);
        ou.w = (unsigned)f2bf(vb.z) | ((unsigned)f2bf(vb.w) << 16);
        *(uint4*)&hb[(size_t)(m0 + row) * 128 + c8 * 8] = ou;
    }
}

// ---------------- attention aggregation --------------------------------------------
// One WAVE per dst node. 4 edge-groups x 16 lanes; lane covers 8 dims (sub = lane&15).
// Q bf16 [N,128]; K/V fp8-e4m3 packed [N,256B] -> ONE uint4 gather per edge per lane.
// Direct exp2 (no online max, matches reference). PACKED-F32 inner loop: all fma/mul/
// add expressed as float2v so the compiler can emit VOP3P v_pk_* (2 f32 ops/instr) —
// kernel is VALU-throughput-bound (77% VALUBusy @ 41% occupancy). exp2 stays scalar
// (no packed transcendental). Per-component arithmetic is bit-identical to scalar.
__global__ __launch_bounds__(64) void agg_kernel(
    const ushort_t* __restrict__ Q, const unsigned char* __restrict__ KV,
    const int* __restrict__ rowstart, const unsigned int* __restrict__ edges,
    const float* __restrict__ u, const float* __restrict__ c1,
    ushort_t* __restrict__ hout) {
    const int lane = threadIdx.x & 63;
    const int v = blockIdx.x;
    const int sub = lane & 15;
    const int grp = lane >> 4;

    // Q dims 8sub..+7 (uint4 = 8 bf16) as float2 pairs
    uint4 qu = *(const uint4*)(Q + (size_t)v * 128 + sub * 8);
    float2v q01 = {lo16(qu.x), hi16(qu.x)};
    float2v q23 = {lo16(qu.y), hi16(qu.y)};
    float2v q45 = {lo16(qu.z), hi16(qu.z)};
    float2v q67 = {lo16(qu.w), hi16(qu.w)};
    float4 uva = *(const float4*)(u + sub * 8);
    float4 uvb = *(const float4*)(u + sub * 8 + 4);
    float4 cva = *(const float4*)(c1 + sub * 8);
    float4 cvb = *(const float4*)(c1 + sub * 8 + 4);
    float2v u01 = {uva.x, uva.y}, u23 = {uva.z, uva.w};
    float2v u45 = {uvb.x, uvb.y}, u67 = {uvb.z, uvb.w};
    float2v c01 = {cva.x, cva.y}, c23 = {cva.z, cva.w};
    float2v c45 = {cvb.x, cvb.y}, c67 = {cvb.z, cvb.w};

    float2v sA2[4], o2[4];
#pragma unroll
    for (int j = 0; j < 4; ++j) {
        sA2[j] = (float2v){0.f, 0.f};
        o2[j] = (float2v){0.f, 0.f};
    }

    const int start = rowstart[v];
    const int deg = rowstart[v + 1] - start;
    const int nfull = deg >> 2;
    const unsigned int* ep = edges + start + grp;

// compute body consuming a pre-loaded edge word + KV vector (packed f32, no max)
#define AGG_COMPUTE(PE, KVv, MASKED, VALID)                                      \
    {                                                                            \
        float ef_ = __uint_as_float((PE) & 0xFFFF0000u);                         \
        float2v ef2 = {ef_, ef_};                                                \
        float2v k01 = __builtin_amdgcn_cvt_pk_f32_fp8((KVv).x, false);           \
        float2v k23 = __builtin_amdgcn_cvt_pk_f32_fp8((KVv).x, true);            \
        float2v k45 = __builtin_amdgcn_cvt_pk_f32_fp8((KVv).y, false);           \
        float2v k67 = __builtin_amdgcn_cvt_pk_f32_fp8((KVv).y, true);            \
        float2v p2 = k01 * q01;                                                  \
        p2 = k23 * q23 + p2;                                                     \
        p2 = k45 * q45 + p2;                                                     \
        p2 = k67 * q67 + p2;                                                     \
        float p_ = p2[0] + p2[1];                                                \
        p_ += __shfl_xor(p_, 1, 64);                                             \
        p_ += __shfl_xor(p_, 2, 64);                                             \
        float2v pv = {p_, p_};                                                   \
        float2v x01 = pv * (ef2 * u01 + c01);                                    \
        float2v x23 = pv * (ef2 * u23 + c23);                                    \
        float2v x45 = pv * (ef2 * u45 + c45);                                    \
        float2v x67 = pv * (ef2 * u67 + c67);                                    \
        if (MASKED) {                                                            \
            float2v neg = {-1.0e38f, -1.0e38f};                                  \
            x01 = (VALID) ? x01 : neg; x23 = (VALID) ? x23 : neg;                \
            x45 = (VALID) ? x45 : neg; x67 = (VALID) ? x67 : neg;                \
        }                                                                        \
        float2v e01 = {EXP2(x01[0]), EXP2(x01[1])};                              \
        float2v e23 = {EXP2(x23[0]), EXP2(x23[1])};                              \
        float2v e45 = {EXP2(x45[0]), EXP2(x45[1])};                              \
        float2v e67 = {EXP2(x67[0]), EXP2(x67[1])};                              \
        sA2[0] += e01; sA2[1] += e23; sA2[2] += e45; sA2[3] += e67;              \
        float2v v01 = __builtin_amdgcn_cvt_pk_f32_fp8((KVv).z, false);           \
        float2v v23 = __builtin_amdgcn_cvt_pk_f32_fp8((KVv).z, true);            \
        float2v v45 = __builtin_amdgcn_cvt_pk_f32_fp8((KVv).w, false);           \
        float2v v67 = __builtin_amdgcn_cvt_pk_f32_fp8((KVv).w, true);            \
        o2[0] = v01 * e01 + o2[0];                                               \
        o2[1] = v23 * e23 + o2[1];                                               \
        o2[2] = v45 * e45 + o2[2];                                               \
        o2[3] = v67 * e67 + o2[3];                                               \
    }

    int it = 0;
    for (; it + 4 <= nfull; it += 4) {
        // batch: issue all 4 edge words + all 4 KV gathers before any compute
        unsigned int pe0 = ep[4 * it];
        unsigned int pe1 = ep[4 * it + 4];
        unsigned int pe2 = ep[4 * it + 8];
        unsigned int pe3 = ep[4 * it + 12];
        uint4 kv0 = *(const uint4*)(KV + (size_t)(pe0 & 0xFFFFu) * 256 + sub * 16);
        uint4 kv1 = *(const uint4*)(KV + (size_t)(pe1 & 0xFFFFu) * 256 + sub * 16);
        uint4 kv2 = *(const uint4*)(KV + (size_t)(pe2 & 0xFFFFu) * 256 + sub * 16);
        uint4 kv3 = *(const uint4*)(KV + (size_t)(pe3 & 0xFFFFu) * 256 + sub * 16);
        AGG_COMPUTE(pe0, kv0, false, true)
        AGG_COMPUTE(pe1, kv1, false, true)
        AGG_COMPUTE(pe2, kv2, false, true)
        AGG_COMPUTE(pe3, kv3, false, true)
    }
    if (it + 2 <= nfull) {
        unsigned int pe0 = ep[4 * it];
        unsigned int pe1 = ep[4 * it + 4];
        uint4 kv0 = *(const uint4*)(KV + (size_t)(pe0 & 0xFFFFu) * 256 + sub * 16);
        uint4 kv1 = *(const uint4*)(KV + (size_t)(pe1 & 0xFFFFu) * 256 + sub * 16);
        AGG_COMPUTE(pe0, kv0, false, true)
        AGG_COMPUTE(pe1, kv1, false, true)
        it += 2;
    }
    if (it < nfull) {
        unsigned int pe0 = ep[4 * it];
        uint4 kv0 = *(const uint4*)(KV + (size_t)(pe0 & 0xFFFFu) * 256 + sub * 16);
        AGG_COMPUTE(pe0, kv0, false, true)
    }
    const int rem = deg & 3;
    if (rem) {
        bool valid = grp < rem;
        unsigned int pe = valid ? ep[4 * nfull] : edges[start];
        uint4 kv = *(const uint4*)(KV + (size_t)(pe & 0xFFFFu) * 256 + sub * 16);
        AGG_COMPUTE(pe, kv, true, valid)
    }
#undef AGG_COMPUTE

    // merge the 4 edge-groups (partners lane^16, lane^32 hold the same dims)
#pragma unroll
    for (int mask = 16; mask <= 32; mask <<= 1) {
#pragma unroll
        for (int j = 0; j < 4; ++j) {
            sA2[j][0] += __shfl_xor(sA2[j][0], mask, 64);
            sA2[j][1] += __shfl_xor(sA2[j][1], mask, 64);
            o2[j][0] += __shfl_xor(o2[j][0], mask, 64);
            o2[j][1] += __shfl_xor(o2[j][1], mask, 64);
        }
    }

    if (grp == 0) {
        // ref: h_out = num / max(Z, 1e-6)
        uint4 ou;
        unsigned int w0, w1;
        float z;
        z = fmaxf(sA2[0][0], 1e-6f); w0 = f2bf(o2[0][0] / z);
        z = fmaxf(sA2[0][1], 1e-6f); w1 = f2bf(o2[0][1] / z);
        ou.x = w0 | (w1 << 16);
        z = fmaxf(sA2[1][0], 1e-6f); w0 = f2bf(o2[1][0] / z);
        z = fmaxf(sA2[1][1], 1e-6f); w1 = f2bf(o2[1][1] / z);
        ou.y = w0 | (w1 << 16);
        z = fmaxf(sA2[2][0], 1e-6f); w0 = f2bf(o2[2][0] / z);
        z = fmaxf(sA2[2][1], 1e-6f); w1 = f2bf(o2[2][1] / z);
        ou.z = w0 | (w1 << 16);
        z = fmaxf(sA2[3][0], 1e-6f); w0 = f2bf(o2[3][0] / z);
        z = fmaxf(sA2[3][1], 1e-6f); w1 = f2bf(o2[3][1] / z);
        ou.w = w0 | (w1 << 16);
        *(uint4*)(hout + (size_t)v * 128 + sub * 8) = ou;
    }
}

// ---------------- mean over nodes ------------------------------------------------------
__global__ void mean_part_kernel(const float* __restrict__ h, float* __restrict__ macc) {
    __shared__ float s[256];
    int t = threadIdx.x;
    int col = t & 127;
    int half = t >> 7;
    int r0 = blockIdx.x * 256;
    float acc = 0.f;
    for (int r = half; r < 256; r += 2) acc += h[(size_t)(r0 + r) * 128 + col];
    s[t] = acc;
    __syncthreads();
    if (t < 128) atomicAdd(&macc[t], s[t] + s[t + 128]);
}

// ---------------- finalize -------------------------------------------------------------
__global__ void finalize_kernel(const float* __restrict__ macc, void* __restrict__ out,
                                const int* __restrict__ flag) {
    int t = threadIdx.x;
    float v = macc[t] * (1.f / (float)N_NODES);
    if (*flag)
        ((ushort_t*)out)[t] = f2bf(v);
    else
        ((float*)out)[t] = v;
}

// ---------------------------------------------------------------------------------------
extern "C" void kernel_launch(void* const* d_in, const int* in_sizes, int n_in,
                              void* d_out, int out_size, void* d_ws, size_t ws_size,
                              hipStream_t stream) {
    const int* src = (const int*)d_in[3];
    const int* dst = (const int*)d_in[4];

    char* w = (char*)d_ws;
    const size_t MB = 1u << 20;
    float* h        = (float*)(w);               // 16 MB [N,128] f32
    ushort_t* hb    = (ushort_t*)(w + 16 * MB);  //  8 MB [N,128] bf16 (also = HOUT)
    ushort_t* Qh    = (ushort_t*)(w + 24 * MB);  //  8 MB [N,128] bf16
    unsigned char* KVf8 = (unsigned char*)(w + 32 * MB);  // 8 MB [N,256B] fp8 K|V packed
    char* aux       = w + 48 * MB;
    int* deg        = (int*)(aux);               // 128 KB
    int* rowstart   = (int*)(aux + 0x40000);     // 128 KB + 4
    int* cursor     = (int*)(aux + 0x80000);     // 128 KB
    unsigned int* edges = (unsigned int*)(aux + 0xC0000);          // 2 MB
    float* ubuf     = (float*)(aux + 0xC0000 + 2 * MB);            // 3*128 f32
    float* cbuf     = ubuf + 3 * 128;
    float* macc     = cbuf + 3 * 128;            // 128 f32
    int* flag       = (int*)(macc + 128);
    float* conv     = (float*)(aux + 0xC0000 + 2 * MB + 4096);     // 40 KB f32
    ushort_t* swz   = (ushort_t*)((char*)conv + CONV_TOTAL * 4);   // 784 KB bf16

    detect_kernel<<<1, 256, 0, stream>>>((const unsigned int*)d_in[5], flag);

    ConvArgs ca;
    ca.src[0] = d_in[5];    // W_node
    ca.src[1] = d_in[6];    // b_node
    ca.src[2] = d_in[7];    // W_pos
    ca.src[3] = d_in[8];    // b_pos
    ca.src[4] = d_in[9];    // W_edge
    ca.src[5] = d_in[10];   // b_edge
    ca.src[6] = d_in[16];   // b_lin
    ca.src[7] = d_in[17];   // g1
    ca.src[8] = d_in[18];   // be1
    ca.src[9] = d_in[20];   // bf1
    ca.src[10] = d_in[22];  // bf2
    ca.src[11] = d_in[23];  // g2
    ca.src[12] = d_in[24];  // be2
    // convert also zeros deg (replaces hipMemsetAsync node)
    convert_kernel<<<(CONV_TOTAL + 255) / 256, 256, 0, stream>>>(ca, flag, conv, deg);

    // swz (192 blocks) + fused uc (3 blocks) + input-proj records (4 blocks)
    swz_kernel<<<192 + 3 + 4, 256, 0, stream>>>(
        d_in[11], d_in[12], d_in[13], d_in[15], d_in[19], d_in[21],
        d_in[14], d_in[9], d_in[10], d_in[5], d_in[7], flag, swz, ubuf, cbuf);

    // input projection via MFMA + fused degree histogram
    ip_gemm<<<N_NODES / 64, 256, 0, stream>>>(d_in[0], d_in[1], conv, flag, dst, deg,
                                              swz + (size_t)REC_WNP * 512, h, hb);
    // scan also zeros macc (replaces hipMemsetAsync node)
    scan_kernel<<<1, 1024, 0, stream>>>(deg, rowstart, cursor, macc);
    scatter_kernel<<<N_EDGES / 256, 256, 0, stream>>>(src, dst, d_in[2], flag, cursor,
                                                      edges);

    for (int i = 0; i < 3; ++i) {
        const ushort_t* swzQKV = swz + (size_t)REC_QKV(i) * 512;
        const ushort_t* swzWL  = swz + (size_t)REC_WLIN(i) * 512;
        const ushort_t* swzF1  = swz + (size_t)REC_WF1(i) * 512;
        const ushort_t* swzF2  = swz + (size_t)REC_WF2(i) * 512;

        // Q bf16 + K/V fp8 packed (3-segment, 4-wave blocks)
        qkv_gemm<4><<<dim3(N_NODES / 64, 3), 256, 0, stream>>>(hb, swzQKV, Qh, KVf8);

        // attention -> hb (= HOUT) [N,128] bf16 (packed-f32 direct-exp2 main loop)
        agg_kernel<<<N_NODES, 64, 0, stream>>>(Qh, KVf8, rowstart, edges,
                                               ubuf + i * 128, cbuf + i * 128, hb);

        // fused layer tail, FOUR waves per 16-row tile (grid 2048 x 256 thr)
        ffn_kernel<<<N_NODES / 16, 256, 0, stream>>>(
            hb, swzWL, swzF1, swzF2,
            conv + OFF_BLIN + i * 128, conv + OFF_G1 + i * 128, conv + OFF_BE1 + i * 128,
            conv + OFF_BF1 + i * 256,
            conv + OFF_BF2 + i * 128, conv + OFF_G2 + i * 128, conv + OFF_BE2 + i * 128,
            h, hb);
    }

    mean_part_kernel<<<N_NODES / 256, 256, 0, stream>>>(h, macc);
    finalize_kernel<<<1, 128, 0, stream>>>(macc, d_out, flag);
}